// Round 2
// baseline (776.878 us; speedup 1.0000x reference)
//
#include <hip/hip_runtime.h>
#include <hip/hip_bf16.h>

typedef __hip_bfloat16 bf16;
#define BF2F(x) __bfloat162float(x)

// Load a float element from an array whose storage dtype is bf16 (BF=1) or fp32 (BF=0).
template<int BF>
__device__ __forceinline__ float ldf(const void* p, size_t i) {
    return BF ? __bfloat162float(((const bf16*)p)[i]) : ((const float*)p)[i];
}

// projection[0][0] == 64.0f exactly. fp32 little-endian 0x42800000 -> first ushort 0x0000.
// bf16 storage -> first ushort 0x4280. Write mode flag (1 = bf16) into ws.
__global__ void detect_dtype_kernel(const void* __restrict__ proj, int* __restrict__ flag) {
    const unsigned short* u = (const unsigned short*)proj;
    *flag = (u[0] == 0x4280) ? 1 : 0;
}

// -------------------------------------------------------------------------
// Kernel 1: 1x1 conv  (Wk|Wv)[1024,256] @ img[256,4096] -> buf[pixel][1024] (bf16)
// pixel-major output so the sampler reads contiguous channels per head/tap.
// -------------------------------------------------------------------------
template<int BF>
__global__ __launch_bounds__(256) void conv1x1_kernel(
    const void* __restrict__ img, const void* __restrict__ Wk,
    const void* __restrict__ Wv, bf16* __restrict__ buf,
    const int* __restrict__ flag)
{
    if (*flag != BF) return;   // wrong-dtype instantiation: uniform early exit
    __shared__ float simg[16][64];   // [c_local][pix]
    __shared__ float sW[16][17];     // [o_local][c_local], padded
    const int tid = threadIdx.x;
    const int p0  = blockIdx.x * 64;   // pixel base (row-contiguous)
    const int o0  = blockIdx.y * 16;   // out-channel base (0..1023)
    const int pix = tid & 63, og = tid >> 6;   // og in 0..3, 4 outs each
    float acc0 = 0.f, acc1 = 0.f, acc2 = 0.f, acc3 = 0.f;
    const void* W = (o0 < 512) ? Wk : Wv;
    const size_t wbase = (size_t)((o0 < 512) ? o0 : (o0 - 512)) * 256;
    for (int c0 = 0; c0 < 256; c0 += 16) {
#pragma unroll
        for (int i = 0; i < 4; i++) {
            int e = tid + i * 256; int cl = e >> 6, pp = e & 63;
            simg[cl][pp] = ldf<BF>(img, (size_t)(c0 + cl) * 4096 + p0 + pp);
        }
        { int ol = tid >> 4, cl = tid & 15;
          sW[ol][cl] = ldf<BF>(W, wbase + (size_t)ol * 256 + c0 + cl); }
        __syncthreads();
#pragma unroll
        for (int cl = 0; cl < 16; cl++) {
            float im = simg[cl][pix];
            acc0 += sW[og * 4 + 0][cl] * im;
            acc1 += sW[og * 4 + 1][cl] * im;
            acc2 += sW[og * 4 + 2][cl] * im;
            acc3 += sW[og * 4 + 3][cl] * im;
        }
        __syncthreads();
    }
    size_t base = (size_t)(p0 + pix) * 1024 + o0 + og * 4;
    buf[base + 0] = __float2bfloat16(acc0);
    buf[base + 1] = __float2bfloat16(acc1);
    buf[base + 2] = __float2bfloat16(acc2);
    buf[base + 3] = __float2bfloat16(acc3);
}

// -------------------------------------------------------------------------
// Kernel 2: per-gaussian fused deformable attention. 1 block = 1 gaussian.
// -------------------------------------------------------------------------
template<int BF>
__global__ __launch_bounds__(256) void deform_attn_kernel(
    const void* __restrict__ means, const void* __restrict__ scales,
    const void* __restrict__ rot,   const void* __restrict__ features,
    const void* __restrict__ transforms, const void* __restrict__ projection,
    const void* __restrict__ Wq,    const void* __restrict__ W_off,
    const void* __restrict__ b_off, const void* __restrict__ Wout,
    const void* __restrict__ b_out, const bf16* __restrict__ buf,
    void* __restrict__ out, const int* __restrict__ flag)
{
    if (*flag != BF) return;   // wrong-dtype instantiation: uniform early exit
    __shared__ float feat[96];       // features[g][3][32]
    __shared__ float qf[1536];       // q_full [t][512]; later reused as out_attn
    __shared__ float qm[512];        // q_mean [h*64+d]
    __shared__ float mw[3], sc3[3], Rt[9], pr[12];
    __shared__ float lrn[144];       // sigmoid offsets - 0.5, [h][18]
    __shared__ float sxy[192];       // sample pixel coords [96][2]
    __shared__ float ks[96 * 64];    // sampled keys   [p][d]
    __shared__ float vs[96 * 64];    // sampled values [p][d]
    __shared__ float att[288];       // scores/attn [(h*3+t)*12+k]

    const int g = blockIdx.x, tid = threadIdx.x;

    // ---- stage 0: tiny loads + per-gaussian geometry ----
    if (tid < 96) {
        feat[tid] = ldf<BF>(features, (size_t)g * 96 + tid);
    } else if (tid < 99) {
        sc3[tid - 96] = ldf<BF>(scales, (size_t)g * 3 + (tid - 96));
    } else if (tid >= 100 && tid < 112) {
        pr[tid - 100] = ldf<BF>(projection, tid - 100);   // rows 0..2 of 4x4
    } else if (tid == 112) {
        float w = ldf<BF>(rot, (size_t)g * 4),     x = ldf<BF>(rot, (size_t)g * 4 + 1);
        float y = ldf<BF>(rot, (size_t)g * 4 + 2), z = ldf<BF>(rot, (size_t)g * 4 + 3);
        float n = rsqrtf(w * w + x * x + y * y + z * z);
        w *= n; x *= n; y *= n; z *= n;
        float R00 = 1 - 2 * (y * y + z * z), R01 = 2 * (x * y - w * z), R02 = 2 * (x * z + w * y);
        float R10 = 2 * (x * y + w * z), R11 = 1 - 2 * (x * x + z * z), R12 = 2 * (y * z - w * x);
        float R20 = 2 * (x * z - w * y), R21 = 2 * (y * z + w * x), R22 = 1 - 2 * (x * x + y * y);
        // Rt = R^T
        Rt[0] = R00; Rt[1] = R10; Rt[2] = R20;
        Rt[3] = R01; Rt[4] = R11; Rt[5] = R21;
        Rt[6] = R02; Rt[7] = R12; Rt[8] = R22;
    } else if (tid >= 116 && tid < 119) {
        int i = tid - 116;
        float m0 = ldf<BF>(means, (size_t)g * 3);
        float m1 = ldf<BF>(means, (size_t)g * 3 + 1);
        float m2 = ldf<BF>(means, (size_t)g * 3 + 2);
        size_t tb = (size_t)g * 16 + i * 4;
        mw[i] = ldf<BF>(transforms, tb) * m0 + ldf<BF>(transforms, tb + 1) * m1
              + ldf<BF>(transforms, tb + 2) * m2 + ldf<BF>(transforms, tb + 3);
    }
    __syncthreads();

    // ---- stage 1: q_full = features @ Wq   [3][512] ----
#pragma unroll
    for (int i = 0; i < 6; i++) {
        int e = tid + i * 256;
        int t = e >> 9, a = e & 511;
        float s = 0.f;
        const float* fp = feat + t * 32;
#pragma unroll
        for (int f = 0; f < 32; f++) s += fp[f] * ldf<BF>(Wq, (size_t)f * 512 + a);
        qf[e] = s;
    }
    __syncthreads();

    // ---- stage 2: q_mean over the 3 tokens ----
    qm[tid]       = (qf[tid]       + qf[tid + 512] + qf[tid + 1024]) * (1.f / 3.f);
    qm[tid + 256] = (qf[tid + 256] + qf[tid + 768] + qf[tid + 1280]) * (1.f / 3.f);
    __syncthreads();

    // ---- stage 3: OffsetNet  (67 -> 18 per head, sigmoid - 0.5) ----
    if (tid < 144) {
        int h = tid / 18, l = tid % 18;
        float s = ldf<BF>(b_off, l);
#pragma unroll
        for (int i = 0; i < 3; i++) s += mw[i] * ldf<BF>(W_off, i * 18 + l);
        for (int d = 0; d < 64; d++) s += qm[h * 64 + d] * ldf<BF>(W_off, (size_t)(3 + d) * 18 + l);
        s = fminf(fmaxf(s, -9.21f), 9.21f);
        lrn[tid] = 1.f / (1.f + expf(-s)) - 0.5f;
    }
    __syncthreads();

    // ---- stage 4: 96 sample-point pixel coordinates ----
    if (tid < 96) {
        int h = tid / 12, k = tid % 12;
        float s0, s1, s2;
        if (k < 6) {
            const float FSx[6] = {0.f, 1.f, 0.f, 0.f, -1.f, 0.f};
            const float FSy[6] = {0.f, 0.f, 1.f, 0.f, 0.f, -1.f};
            const float FSz[6] = {0.f, 0.f, 0.f, 1.f, 0.f, 0.f};
            s0 = FSx[k]; s1 = FSy[k]; s2 = FSz[k];
        } else {
            int b = h * 18 + (k - 6) * 3;
            s0 = lrn[b]; s1 = lrn[b + 1]; s2 = lrn[b + 2];
        }
        float o0 = s0 * sc3[0], o1 = s1 * sc3[1], o2 = s2 * sc3[2];
        float wx = Rt[0] * o0 + Rt[1] * o1 + Rt[2] * o2 + mw[0];
        float wy = Rt[3] * o0 + Rt[4] * o1 + Rt[5] * o2 + mw[1];
        float wz = Rt[6] * o0 + Rt[7] * o1 + Rt[8] * o2 + mw[2];
        float px = pr[0] * wx + pr[1] * wy + pr[2]  * wz + pr[3];
        float py = pr[4] * wx + pr[5] * wy + pr[6]  * wz + pr[7];
        float pz = pr[8] * wx + pr[9] * wy + pr[10] * wz + pr[11];
        pz = fmaxf(pz, 1e-5f);
        float gx = fminf(fmaxf(px / pz * (1.f / 64.f), 0.f), 0.9999f);
        float gy = fminf(fmaxf(py / pz * (1.f / 64.f), 0.f), 0.9999f);
        // x = (2*gx-1+1)*(W/2)-0.5 = gx*64-0.5
        sxy[tid * 2]     = gx * 64.f - 0.5f;
        sxy[tid * 2 + 1] = gy * 64.f - 0.5f;
    }
    __syncthreads();

    // ---- stage 5: bilinear sampling of k/v (contiguous channels per tap) ----
    {
        const int d = tid & 63, pg = tid >> 6;
        for (int it = 0; it < 24; it++) {
            int p = it * 4 + pg;
            int h = p / 12;
            float x = sxy[p * 2], y = sxy[p * 2 + 1];
            float fx = floorf(x), fy = floorf(y);
            int x0 = (int)fx, y0 = (int)fy;
            float wx1 = x - fx, wx0 = 1.f - wx1;
            float wy1 = y - fy, wy0 = 1.f - wy1;
            int x1 = x0 + 1, y1 = y0 + 1;
            bool vx0 = (x0 >= 0) & (x0 < 64), vx1 = (x1 >= 0) & (x1 < 64);
            bool vy0 = (y0 >= 0) & (y0 < 64), vy1 = (y1 >= 0) & (y1 < 64);
            int xc0 = min(max(x0, 0), 63), xc1 = min(max(x1, 0), 63);
            int yc0 = min(max(y0, 0), 63), yc1 = min(max(y1, 0), 63);
            int a = h * 64 + d;
            float ka = 0.f, va = 0.f;
            if (vx0 & vy0) { const bf16* pp = buf + (size_t)(yc0 * 64 + xc0) * 1024 + a;
                             float w = wx0 * wy0; ka += w * BF2F(pp[0]); va += w * BF2F(pp[512]); }
            if (vx1 & vy0) { const bf16* pp = buf + (size_t)(yc0 * 64 + xc1) * 1024 + a;
                             float w = wx1 * wy0; ka += w * BF2F(pp[0]); va += w * BF2F(pp[512]); }
            if (vx0 & vy1) { const bf16* pp = buf + (size_t)(yc1 * 64 + xc0) * 1024 + a;
                             float w = wx0 * wy1; ka += w * BF2F(pp[0]); va += w * BF2F(pp[512]); }
            if (vx1 & vy1) { const bf16* pp = buf + (size_t)(yc1 * 64 + xc1) * 1024 + a;
                             float w = wx1 * wy1; ka += w * BF2F(pp[0]); va += w * BF2F(pp[512]); }
            ks[p * 64 + d] = ka;
            vs[p * 64 + d] = va;
        }
    }
    __syncthreads();

    // ---- stage 6: scores = q . k_s * HD^-0.5   [8][3][12] ----
    for (int e = tid; e < 288; e += 256) {
        int h = e / 36, r = e % 36, t = r / 12, k = r % 12;
        const float* qp = qf + t * 512 + h * 64;
        const float* kp = ks + (h * 12 + k) * 64;
        float s = 0.f;
#pragma unroll
        for (int dd = 0; dd < 64; dd++) s += qp[dd] * kp[dd];
        att[(h * 3 + t) * 12 + k] = s * 0.125f;   // 64^-0.5
    }
    __syncthreads();

    // ---- stage 7: softmax over K=12 ----
    if (tid < 24) {
        float* row = att + tid * 12;
        float m = row[0];
#pragma unroll
        for (int k = 1; k < 12; k++) m = fmaxf(m, row[k]);
        float e_[12]; float ssum = 0.f;
#pragma unroll
        for (int k = 0; k < 12; k++) { e_[k] = expf(row[k] - m); ssum += e_[k]; }
        float inv = 1.f / ssum;
#pragma unroll
        for (int k = 0; k < 12; k++) row[k] = e_[k] * inv;
    }
    __syncthreads();

    // ---- stage 8: out_attn = attn @ v_s  -> reuse qf as [t][512] ----
    float* oa = qf;   // q_full is dead after stage 6
#pragma unroll
    for (int i = 0; i < 6; i++) {
        int e = tid + i * 256;
        int t = e >> 9, a = e & 511, h = a >> 6, dd = a & 63;
        const float* ar = att + (h * 3 + t) * 12;
        const float* vp = vs + (h * 12) * 64 + dd;
        float s = 0.f;
#pragma unroll
        for (int k = 0; k < 12; k++) s += ar[k] * vp[k * 64];
        oa[e] = s;
    }
    __syncthreads();

    // ---- stage 9: out = out_attn @ Wout + b_out + features ----
    if (tid < 96) {
        int t = tid / 32, c = tid % 32;
        float acc = ldf<BF>(b_out, c) + feat[t * 32 + c];
        const float* op = oa + t * 512;
        for (int a = 0; a < 512; a++) acc += op[a] * ldf<BF>(Wout, (size_t)a * 32 + c);
        size_t oi = (size_t)g * 96 + tid;
        if (BF) ((bf16*)out)[oi] = __float2bfloat16(acc);
        else    ((float*)out)[oi] = acc;
    }
}

extern "C" void kernel_launch(void* const* d_in, const int* in_sizes, int n_in,
                              void* d_out, int out_size, void* d_ws, size_t ws_size,
                              hipStream_t stream) {
    const void* means      = d_in[0];
    const void* scales     = d_in[1];
    const void* rot        = d_in[2];
    const void* features   = d_in[3];
    const void* transforms = d_in[4];
    const void* projection = d_in[5];
    const void* img        = d_in[6];
    const void* Wq         = d_in[7];
    const void* Wk         = d_in[8];
    const void* Wv         = d_in[9];
    const void* W_off      = d_in[10];
    const void* b_off      = d_in[11];
    const void* Wout       = d_in[12];
    const void* b_out      = d_in[13];

    int*  flag = (int*)d_ws;
    bf16* buf  = (bf16*)((char*)d_ws + 64);   // 4096 px x 1024 ch bf16 = 8 MiB

    detect_dtype_kernel<<<1, 1, 0, stream>>>(projection, flag);

    dim3 grid1(64, 64);
    conv1x1_kernel<1><<<grid1, 256, 0, stream>>>(img, Wk, Wv, buf, flag);
    conv1x1_kernel<0><<<grid1, 256, 0, stream>>>(img, Wk, Wv, buf, flag);
    deform_attn_kernel<1><<<8192, 256, 0, stream>>>(
        means, scales, rot, features, transforms, projection,
        Wq, W_off, b_off, Wout, b_out, buf, d_out, flag);
    deform_attn_kernel<0><<<8192, 256, 0, stream>>>(
        means, scales, rot, features, transforms, projection,
        Wq, W_off, b_off, Wout, b_out, buf, d_out, flag);
}

// Round 3
// 317.586 us; speedup vs baseline: 2.4462x; 2.4462x over previous
//
#include <hip/hip_runtime.h>
#include <hip/hip_bf16.h>

typedef __hip_bfloat16 bf16;
#define BF2F(x) __bfloat162float(x)

template<int BF>
__device__ __forceinline__ float ldf(const void* p, size_t i) {
    return BF ? __bfloat162float(((const bf16*)p)[i]) : ((const float*)p)[i];
}

// load elements i, i+1 (i even) as floats
template<int BF>
__device__ __forceinline__ float2 ld2f(const void* p, size_t i) {
    if (BF) {
        unsigned u = *(const unsigned*)((const unsigned short*)p + i);
        return make_float2(__uint_as_float(u << 16), __uint_as_float(u & 0xffff0000u));
    } else {
        return *(const float2*)((const float*)p + i);
    }
}

// unpack 8 bf16 (16B aligned) to 8 floats
__device__ __forceinline__ void ld8bf(const bf16* p, float* f) {
    uint4 u = *(const uint4*)p;
    f[0] = __uint_as_float(u.x << 16); f[1] = __uint_as_float(u.x & 0xffff0000u);
    f[2] = __uint_as_float(u.y << 16); f[3] = __uint_as_float(u.y & 0xffff0000u);
    f[4] = __uint_as_float(u.z << 16); f[5] = __uint_as_float(u.z & 0xffff0000u);
    f[6] = __uint_as_float(u.w << 16); f[7] = __uint_as_float(u.w & 0xffff0000u);
}

// projection[0][0] == 64.0f exactly -> first ushort 0x4280 iff bf16 storage.
__global__ void detect_dtype_kernel(const void* __restrict__ proj, int* __restrict__ flag) {
    const unsigned short* u = (const unsigned short*)proj;
    *flag = (u[0] == 0x4280) ? 1 : 0;
}

// -------------------------------------------------------------------------
// Kernel 1: 1x1 conv  (Wk|Wv)[1024,256] @ img[256,4096] -> buf[pixel][1024] bf16
// -------------------------------------------------------------------------
template<int BF>
__global__ __launch_bounds__(256) void conv1x1_kernel(
    const void* __restrict__ img, const void* __restrict__ Wk,
    const void* __restrict__ Wv, bf16* __restrict__ buf,
    const int* __restrict__ flag)
{
    if (*flag != BF) return;
    __shared__ float simg[16][64];   // [c_local][pix]
    __shared__ float sW[16][17];     // [o_local][c_local], padded
    const int tid = threadIdx.x;
    const int p0  = blockIdx.x * 64;
    const int o0  = blockIdx.y * 16;
    const int pix = tid & 63, og = tid >> 6;
    float acc0 = 0.f, acc1 = 0.f, acc2 = 0.f, acc3 = 0.f;
    const void* W = (o0 < 512) ? Wk : Wv;
    const size_t wbase = (size_t)((o0 < 512) ? o0 : (o0 - 512)) * 256;
    for (int c0 = 0; c0 < 256; c0 += 16) {
        { // vectorized image stage: 16 rows x 64 pix, 4 elems/thread
            int cl = tid >> 4, pp = (tid & 15) * 4;
            size_t idx = (size_t)(c0 + cl) * 4096 + p0 + pp;
            if (BF) {
                ushort4 u = *(const ushort4*)((const unsigned short*)img + idx);
                simg[cl][pp + 0] = __uint_as_float((unsigned)u.x << 16);
                simg[cl][pp + 1] = __uint_as_float((unsigned)u.y << 16);
                simg[cl][pp + 2] = __uint_as_float((unsigned)u.z << 16);
                simg[cl][pp + 3] = __uint_as_float((unsigned)u.w << 16);
            } else {
                float4 v = *(const float4*)((const float*)img + idx);
                simg[cl][pp + 0] = v.x; simg[cl][pp + 1] = v.y;
                simg[cl][pp + 2] = v.z; simg[cl][pp + 3] = v.w;
            }
        }
        { int ol = tid >> 4, cl = tid & 15;
          sW[ol][cl] = ldf<BF>(W, wbase + (size_t)ol * 256 + c0 + cl); }
        __syncthreads();
#pragma unroll
        for (int cl = 0; cl < 16; cl++) {
            float im = simg[cl][pix];
            acc0 += sW[og * 4 + 0][cl] * im;
            acc1 += sW[og * 4 + 1][cl] * im;
            acc2 += sW[og * 4 + 2][cl] * im;
            acc3 += sW[og * 4 + 3][cl] * im;
        }
        __syncthreads();
    }
    size_t base = (size_t)(p0 + pix) * 1024 + o0 + og * 4;
    buf[base + 0] = __float2bfloat16(acc0);
    buf[base + 1] = __float2bfloat16(acc1);
    buf[base + 2] = __float2bfloat16(acc2);
    buf[base + 3] = __float2bfloat16(acc3);
}

// -------------------------------------------------------------------------
// Kernel 2: per-gaussian fused deformable attention. 1 block = 1 gaussian.
// -------------------------------------------------------------------------
template<int BF>
__global__ __launch_bounds__(256, 4) void deform_attn_kernel(
    const void* __restrict__ means, const void* __restrict__ scales,
    const void* __restrict__ rot,   const void* __restrict__ features,
    const void* __restrict__ transforms, const void* __restrict__ projection,
    const void* __restrict__ Wq,    const void* __restrict__ W_off,
    const void* __restrict__ b_off, const void* __restrict__ Wout,
    const void* __restrict__ b_out, const bf16* __restrict__ buf,
    void* __restrict__ out, const int* __restrict__ flag)
{
    if (*flag != BF) return;
    __shared__ float feat[96];                              // features[g][3][32]
    __shared__ __attribute__((aligned(16))) float qf[1536]; // q_full [t][512]; later out_attn
    __shared__ float qm[512];                               // q_mean [h*64+d]
    __shared__ float mw[3], sc3[3], Rt[9], pr[12];
    __shared__ float lrn[144];                              // sigmoid-0.5, [h][18]
    __shared__ float sxy[192];                              // sample coords [96][2]
    __shared__ __attribute__((aligned(16))) float vs[6144]; // sampled values [p][64]; later red
    __shared__ float att[288];                              // scores/attn [(h*3+t)*12+k]

    const int g = blockIdx.x, tid = threadIdx.x;

    // ---- stage 0: tiny loads + per-gaussian geometry ----
    if (tid < 96) {
        feat[tid] = ldf<BF>(features, (size_t)g * 96 + tid);
    } else if (tid < 99) {
        sc3[tid - 96] = ldf<BF>(scales, (size_t)g * 3 + (tid - 96));
    } else if (tid >= 100 && tid < 112) {
        pr[tid - 100] = ldf<BF>(projection, tid - 100);
    } else if (tid == 112) {
        float w = ldf<BF>(rot, (size_t)g * 4),     x = ldf<BF>(rot, (size_t)g * 4 + 1);
        float y = ldf<BF>(rot, (size_t)g * 4 + 2), z = ldf<BF>(rot, (size_t)g * 4 + 3);
        float n = rsqrtf(w * w + x * x + y * y + z * z);
        w *= n; x *= n; y *= n; z *= n;
        float R00 = 1 - 2 * (y * y + z * z), R01 = 2 * (x * y - w * z), R02 = 2 * (x * z + w * y);
        float R10 = 2 * (x * y + w * z), R11 = 1 - 2 * (x * x + z * z), R12 = 2 * (y * z - w * x);
        float R20 = 2 * (x * z - w * y), R21 = 2 * (y * z + w * x), R22 = 1 - 2 * (x * x + y * y);
        Rt[0] = R00; Rt[1] = R10; Rt[2] = R20;
        Rt[3] = R01; Rt[4] = R11; Rt[5] = R21;
        Rt[6] = R02; Rt[7] = R12; Rt[8] = R22;
    } else if (tid >= 116 && tid < 119) {
        int i = tid - 116;
        float m0 = ldf<BF>(means, (size_t)g * 3);
        float m1 = ldf<BF>(means, (size_t)g * 3 + 1);
        float m2 = ldf<BF>(means, (size_t)g * 3 + 2);
        size_t tb = (size_t)g * 16 + i * 4;
        mw[i] = ldf<BF>(transforms, tb) * m0 + ldf<BF>(transforms, tb + 1) * m1
              + ldf<BF>(transforms, tb + 2) * m2 + ldf<BF>(transforms, tb + 3);
    }
    __syncthreads();

    // ---- stage 1: q_full = features @ Wq  (thread = 2 adjacent cols x 3 tokens) ----
    {
        const int a0 = tid * 2;
        float s00 = 0.f, s01 = 0.f, s10 = 0.f, s11 = 0.f, s20 = 0.f, s21 = 0.f;
#pragma unroll
        for (int f = 0; f < 32; f++) {
            float2 w2 = ld2f<BF>(Wq, (size_t)f * 512 + a0);
            float f0 = feat[f], f1 = feat[32 + f], f2 = feat[64 + f];
            s00 += f0 * w2.x; s01 += f0 * w2.y;
            s10 += f1 * w2.x; s11 += f1 * w2.y;
            s20 += f2 * w2.x; s21 += f2 * w2.y;
        }
        *(float2*)(qf + a0)        = make_float2(s00, s01);
        *(float2*)(qf + 512 + a0)  = make_float2(s10, s11);
        *(float2*)(qf + 1024 + a0) = make_float2(s20, s21);
    }
    __syncthreads();

    // ---- stage 2: q_mean over the 3 tokens ----
    qm[tid]       = (qf[tid]       + qf[tid + 512] + qf[tid + 1024]) * (1.f / 3.f);
    qm[tid + 256] = (qf[tid + 256] + qf[tid + 768] + qf[tid + 1280]) * (1.f / 3.f);
    __syncthreads();

    // ---- stage 3: OffsetNet  (67 -> 18 per head, sigmoid - 0.5) ----
    if (tid < 144) {
        int h = tid / 18, l = tid % 18;
        float s = ldf<BF>(b_off, l);
#pragma unroll
        for (int i = 0; i < 3; i++) s += mw[i] * ldf<BF>(W_off, i * 18 + l);
        for (int d = 0; d < 64; d++) s += qm[h * 64 + d] * ldf<BF>(W_off, (size_t)(3 + d) * 18 + l);
        s = fminf(fmaxf(s, -9.21f), 9.21f);
        lrn[tid] = 1.f / (1.f + expf(-s)) - 0.5f;
    }
    __syncthreads();

    // ---- stage 4: 96 sample-point pixel coordinates ----
    if (tid < 96) {
        int h = tid / 12, k = tid % 12;
        float s0, s1, s2;
        if (k < 6) {
            const float FSx[6] = {0.f, 1.f, 0.f, 0.f, -1.f, 0.f};
            const float FSy[6] = {0.f, 0.f, 1.f, 0.f, 0.f, -1.f};
            const float FSz[6] = {0.f, 0.f, 0.f, 1.f, 0.f, 0.f};
            s0 = FSx[k]; s1 = FSy[k]; s2 = FSz[k];
        } else {
            int b = h * 18 + (k - 6) * 3;
            s0 = lrn[b]; s1 = lrn[b + 1]; s2 = lrn[b + 2];
        }
        float o0 = s0 * sc3[0], o1 = s1 * sc3[1], o2 = s2 * sc3[2];
        float wx = Rt[0] * o0 + Rt[1] * o1 + Rt[2] * o2 + mw[0];
        float wy = Rt[3] * o0 + Rt[4] * o1 + Rt[5] * o2 + mw[1];
        float wz = Rt[6] * o0 + Rt[7] * o1 + Rt[8] * o2 + mw[2];
        float px = pr[0] * wx + pr[1] * wy + pr[2]  * wz + pr[3];
        float py = pr[4] * wx + pr[5] * wy + pr[6]  * wz + pr[7];
        float pz = pr[8] * wx + pr[9] * wy + pr[10] * wz + pr[11];
        pz = fmaxf(pz, 1e-5f);
        float gx = fminf(fmaxf(px / pz * (1.f / 64.f), 0.f), 0.9999f);
        float gy = fminf(fmaxf(py / pz * (1.f / 64.f), 0.f), 0.9999f);
        sxy[tid * 2]     = gx * 64.f - 0.5f;
        sxy[tid * 2 + 1] = gy * 64.f - 0.5f;
    }
    __syncthreads();

    // ---- stage 5: sample k/v (8 threads x 8 ch per point) + fused q.k scores ----
    {
        const int slice = tid & 7, d0 = slice * 8, grp = tid >> 3;   // 32 point-groups
        for (int it = 0; it < 3; it++) {
            const int p = it * 32 + grp;
            const int h = p / 12, k = p - h * 12;
            float x = sxy[p * 2], y = sxy[p * 2 + 1];
            float fx = floorf(x), fy = floorf(y);
            int x0 = (int)fx, y0 = (int)fy;
            float wx1 = x - fx, wx0 = 1.f - wx1;
            float wy1 = y - fy, wy0 = 1.f - wy1;
            int x1 = x0 + 1, y1 = y0 + 1;
            bool vx0 = (x0 >= 0) & (x0 < 64), vx1 = (x1 >= 0) & (x1 < 64);
            bool vy0 = (y0 >= 0) & (y0 < 64), vy1 = (y1 >= 0) & (y1 < 64);
            int xc0 = min(max(x0, 0), 63), xc1 = min(max(x1, 0), 63);
            int yc0 = min(max(y0, 0), 63), yc1 = min(max(y1, 0), 63);
            const int a = h * 64 + d0;
            float ka[8] = {0,0,0,0,0,0,0,0}, va[8] = {0,0,0,0,0,0,0,0}, t8[8];
#define CORNER(vx, vy, yy, xx, wgt)                                              \
            if ((vx) & (vy)) {                                                   \
                const bf16* pp = buf + (size_t)((yy) * 64 + (xx)) * 1024 + a;    \
                float w = (wgt);                                                 \
                ld8bf(pp, t8);                                                   \
                for (int j = 0; j < 8; j++) ka[j] += w * t8[j];                  \
                ld8bf(pp + 512, t8);                                             \
                for (int j = 0; j < 8; j++) va[j] += w * t8[j];                  \
            }
            CORNER(vx0, vy0, yc0, xc0, wx0 * wy0)
            CORNER(vx1, vy0, yc0, xc1, wx1 * wy0)
            CORNER(vx0, vy1, yc1, xc0, wx0 * wy1)
            CORNER(vx1, vy1, yc1, xc1, wx1 * wy1)
#undef CORNER
            *(float4*)(vs + p * 64 + d0)     = make_float4(va[0], va[1], va[2], va[3]);
            *(float4*)(vs + p * 64 + d0 + 4) = make_float4(va[4], va[5], va[6], va[7]);
            // fused partial scores for the 3 tokens
            float sp[3];
#pragma unroll
            for (int t = 0; t < 3; t++) {
                const float* qp = qf + t * 512 + a;
                float s = 0.f;
#pragma unroll
                for (int j = 0; j < 8; j++) s += qp[j] * ka[j];
                sp[t] = s;
            }
#pragma unroll
            for (int m = 1; m < 8; m <<= 1) {
#pragma unroll
                for (int t = 0; t < 3; t++) sp[t] += __shfl_xor(sp[t], m);
            }
            if (slice == 0) {
#pragma unroll
                for (int t = 0; t < 3; t++) att[(h * 3 + t) * 12 + k] = sp[t] * 0.125f;
            }
        }
    }
    __syncthreads();

    // ---- stage 7: softmax over K=12 ----
    if (tid < 24) {
        float* row = att + tid * 12;
        float m = row[0];
#pragma unroll
        for (int k = 1; k < 12; k++) m = fmaxf(m, row[k]);
        float e_[12]; float ssum = 0.f;
#pragma unroll
        for (int k = 0; k < 12; k++) { e_[k] = expf(row[k] - m); ssum += e_[k]; }
        float inv = 1.f / ssum;
#pragma unroll
        for (int k = 0; k < 12; k++) row[k] = e_[k] * inv;
    }
    __syncthreads();

    // ---- stage 8: out_attn = attn @ v_s  -> reuse qf as [t][512] ----
#pragma unroll
    for (int i = 0; i < 6; i++) {
        int e = tid + i * 256;
        int t = e >> 9, a = e & 511, h = a >> 6, dd = a & 63;
        const float* ar = att + (h * 3 + t) * 12;
        const float* vp = vs + (h * 12) * 64 + dd;
        float s = 0.f;
#pragma unroll
        for (int k = 0; k < 12; k++) s += ar[k] * vp[k * 64];
        // qf row t is fully consumed as soon as... (qf reads done in stage 5; safe)
        qf[e] = s;
    }
    __syncthreads();

    // ---- stage 9: out = oa @ Wout + b_out + feat; split-K over 16 slices ----
    {
        float* red = vs;   // vs dead now; need 16*3*32 = 1536 floats
        const int c0 = (tid & 15) * 2, slice = tid >> 4;   // 16 slices x 32 a's
        const int abase = slice * 32;
        float a00 = 0.f, a01 = 0.f, a10 = 0.f, a11 = 0.f, a20 = 0.f, a21 = 0.f;
#pragma unroll
        for (int i = 0; i < 32; i++) {
            int a = abase + i;
            float2 w2 = ld2f<BF>(Wout, (size_t)a * 32 + c0);
            float o0 = qf[a], o1 = qf[512 + a], o2 = qf[1024 + a];
            a00 += o0 * w2.x; a01 += o0 * w2.y;
            a10 += o1 * w2.x; a11 += o1 * w2.y;
            a20 += o2 * w2.x; a21 += o2 * w2.y;
        }
        red[(slice * 3 + 0) * 32 + c0] = a00; red[(slice * 3 + 0) * 32 + c0 + 1] = a01;
        red[(slice * 3 + 1) * 32 + c0] = a10; red[(slice * 3 + 1) * 32 + c0 + 1] = a11;
        red[(slice * 3 + 2) * 32 + c0] = a20; red[(slice * 3 + 2) * 32 + c0 + 1] = a21;
        __syncthreads();
        if (tid < 96) {
            int t = tid >> 5, c = tid & 31;
            float acc = ldf<BF>(b_out, c) + feat[tid];
#pragma unroll
            for (int s = 0; s < 16; s++) acc += red[(s * 3 + t) * 32 + c];
            size_t oi = (size_t)g * 96 + tid;
            if (BF) ((bf16*)out)[oi] = __float2bfloat16(acc);
            else    ((float*)out)[oi] = acc;
        }
    }
}

extern "C" void kernel_launch(void* const* d_in, const int* in_sizes, int n_in,
                              void* d_out, int out_size, void* d_ws, size_t ws_size,
                              hipStream_t stream) {
    const void* means      = d_in[0];
    const void* scales     = d_in[1];
    const void* rot        = d_in[2];
    const void* features   = d_in[3];
    const void* transforms = d_in[4];
    const void* projection = d_in[5];
    const void* img        = d_in[6];
    const void* Wq         = d_in[7];
    const void* Wk         = d_in[8];
    const void* Wv         = d_in[9];
    const void* W_off      = d_in[10];
    const void* b_off      = d_in[11];
    const void* Wout       = d_in[12];
    const void* b_out      = d_in[13];

    int*  flag = (int*)d_ws;
    bf16* buf  = (bf16*)((char*)d_ws + 64);   // 4096 px x 1024 ch bf16 = 8 MiB

    detect_dtype_kernel<<<1, 1, 0, stream>>>(projection, flag);

    dim3 grid1(64, 64);
    conv1x1_kernel<1><<<grid1, 256, 0, stream>>>(img, Wk, Wv, buf, flag);
    conv1x1_kernel<0><<<grid1, 256, 0, stream>>>(img, Wk, Wv, buf, flag);
    deform_attn_kernel<1><<<8192, 256, 0, stream>>>(
        means, scales, rot, features, transforms, projection,
        Wq, W_off, b_off, Wout, b_out, buf, d_out, flag);
    deform_attn_kernel<0><<<8192, 256, 0, stream>>>(
        means, scales, rot, features, transforms, projection,
        Wq, W_off, b_off, Wout, b_out, buf, d_out, flag);
}

// Round 4
// 244.744 us; speedup vs baseline: 3.1742x; 1.2976x over previous
//
#include <hip/hip_runtime.h>
#include <hip/hip_bf16.h>

typedef __hip_bfloat16 bf16;
typedef __attribute__((ext_vector_type(8))) short short8;
typedef __attribute__((ext_vector_type(4))) float float4v;
#define BF2F(x) __bfloat162float(x)

template<int BF>
__device__ __forceinline__ float ldf(const void* p, size_t i) {
    return BF ? __bfloat162float(((const bf16*)p)[i]) : ((const float*)p)[i];
}

// load elements i, i+1 (i even) as floats
template<int BF>
__device__ __forceinline__ float2 ld2f(const void* p, size_t i) {
    if (BF) {
        unsigned u = *(const unsigned*)((const unsigned short*)p + i);
        return make_float2(__uint_as_float(u << 16), __uint_as_float(u & 0xffff0000u));
    } else {
        return *(const float2*)((const float*)p + i);
    }
}

// unpack 8 bf16 (16B aligned) to 8 floats
__device__ __forceinline__ void ld8bf(const bf16* p, float* f) {
    uint4 u = *(const uint4*)p;
    f[0] = __uint_as_float(u.x << 16); f[1] = __uint_as_float(u.x & 0xffff0000u);
    f[2] = __uint_as_float(u.y << 16); f[3] = __uint_as_float(u.y & 0xffff0000u);
    f[4] = __uint_as_float(u.z << 16); f[5] = __uint_as_float(u.z & 0xffff0000u);
    f[6] = __uint_as_float(u.w << 16); f[7] = __uint_as_float(u.w & 0xffff0000u);
}

__device__ __forceinline__ unsigned short f2bfu(float f) {
    bf16 b = __float2bfloat16(f);
    return *(unsigned short*)&b;
}
__device__ __forceinline__ unsigned packbf(float lo, float hi) {
    return (unsigned)f2bfu(lo) | ((unsigned)f2bfu(hi) << 16);
}

// projection[0][0] == 64.0f exactly -> first ushort 0x4280 iff bf16 storage.
__global__ void detect_dtype_kernel(const void* __restrict__ proj, int* __restrict__ flag) {
    const unsigned short* u = (const unsigned short*)proj;
    *flag = (u[0] == 0x4280) ? 1 : 0;
}

// -------------------------------------------------------------------------
// Kernel 1: MFMA 1x1 conv.  buf[px][1024] = img^T[px][256k] @ (Wk|Wv)^T[256k][1024]
// Block: 64 px x 64 out, 4 waves (wave = 16 px x 64 out), K=256 staged in LDS.
// -------------------------------------------------------------------------
template<int BF>
__global__ __launch_bounds__(256) void conv_mfma_kernel(
    const void* __restrict__ img, const void* __restrict__ Wk,
    const void* __restrict__ Wv, bf16* __restrict__ buf,
    const int* __restrict__ flag)
{
    if (*flag != BF) return;
    __shared__ __attribute__((aligned(16))) unsigned short Bt[64][264]; // [px][k], +8 pad
    const int tid = threadIdx.x;
    const int p0 = blockIdx.x * 64;        // pixel base (one image row)
    const int o0 = blockIdx.y * 64;        // out-channel base

    // ---- stage img tile transposed: Bt[px][k] (k-pairs packed as dwords) ----
#pragma unroll
    for (int i = 0; i < 4; i++) {
        int chunk = i * 256 + tid;          // 1024 chunks = 128 kpairs x 8 px-groups
        int kp  = chunk >> 3;               // k-pair index (k = 2*kp, 2*kp+1)
        int pxg = (chunk & 7) * 8;          // px group base (8 px)
        unsigned lo[8], hi[8];
        if (BF) {
            const unsigned short* ip = (const unsigned short*)img;
            uint4 r0 = *(const uint4*)(ip + (size_t)(2 * kp) * 4096 + p0 + pxg);
            uint4 r1 = *(const uint4*)(ip + (size_t)(2 * kp + 1) * 4096 + p0 + pxg);
            lo[0] = r0.x & 0xffffu; lo[1] = r0.x >> 16; lo[2] = r0.y & 0xffffu; lo[3] = r0.y >> 16;
            lo[4] = r0.z & 0xffffu; lo[5] = r0.z >> 16; lo[6] = r0.w & 0xffffu; lo[7] = r0.w >> 16;
            hi[0] = r1.x & 0xffffu; hi[1] = r1.x >> 16; hi[2] = r1.y & 0xffffu; hi[3] = r1.y >> 16;
            hi[4] = r1.z & 0xffffu; hi[5] = r1.z >> 16; hi[6] = r1.w & 0xffffu; hi[7] = r1.w >> 16;
        } else {
            const float* ip = (const float*)img;
            const float* r0 = ip + (size_t)(2 * kp) * 4096 + p0 + pxg;
            const float* r1 = ip + (size_t)(2 * kp + 1) * 4096 + p0 + pxg;
            float4 a0 = *(const float4*)r0, a1 = *(const float4*)(r0 + 4);
            float4 b0 = *(const float4*)r1, b1 = *(const float4*)(r1 + 4);
            lo[0] = f2bfu(a0.x); lo[1] = f2bfu(a0.y); lo[2] = f2bfu(a0.z); lo[3] = f2bfu(a0.w);
            lo[4] = f2bfu(a1.x); lo[5] = f2bfu(a1.y); lo[6] = f2bfu(a1.z); lo[7] = f2bfu(a1.w);
            hi[0] = f2bfu(b0.x); hi[1] = f2bfu(b0.y); hi[2] = f2bfu(b0.z); hi[3] = f2bfu(b0.w);
            hi[4] = f2bfu(b1.x); hi[5] = f2bfu(b1.y); hi[6] = f2bfu(b1.z); hi[7] = f2bfu(b1.w);
        }
#pragma unroll
        for (int j = 0; j < 8; j++)
            *(unsigned*)&Bt[pxg + j][2 * kp] = lo[j] | (hi[j] << 16);
    }
    __syncthreads();

    // ---- MFMA main: wave w -> px sub-tile w*16, all 64 out ----
    const int w = tid >> 6, l = tid & 63;
    const int m = l & 15, quad = l >> 4;
    const int mrow = w * 16 + m;
    const void* Wsel = (o0 < 512) ? Wk : Wv;
    const int obase = (o0 < 512) ? o0 : (o0 - 512);

    float4v acc[4] = {{0,0,0,0},{0,0,0,0},{0,0,0,0},{0,0,0,0}};
#pragma unroll
    for (int kk = 0; kk < 8; kk++) {
        const int kofs = kk * 32 + quad * 8;
        short8 af = *(const short8*)&Bt[mrow][kofs];
#pragma unroll
        for (int nt = 0; nt < 4; nt++) {
            const int row = obase + nt * 16 + m;
            short8 b8;
            if (BF) {
                b8 = *(const short8*)((const unsigned short*)Wsel + (size_t)row * 256 + kofs);
            } else {
                const float* wp = (const float*)Wsel + (size_t)row * 256 + kofs;
                float4 w0 = *(const float4*)wp, w1 = *(const float4*)(wp + 4);
                b8[0] = (short)f2bfu(w0.x); b8[1] = (short)f2bfu(w0.y);
                b8[2] = (short)f2bfu(w0.z); b8[3] = (short)f2bfu(w0.w);
                b8[4] = (short)f2bfu(w1.x); b8[5] = (short)f2bfu(w1.y);
                b8[6] = (short)f2bfu(w1.z); b8[7] = (short)f2bfu(w1.w);
            }
            acc[nt] = __builtin_amdgcn_mfma_f32_16x16x32_bf16(af, b8, acc[nt], 0, 0, 0);
        }
    }
    // ---- store: D col = lane&15 = out offset, row = quad*4+reg = px offset ----
#pragma unroll
    for (int nt = 0; nt < 4; nt++) {
#pragma unroll
        for (int r = 0; r < 4; r++) {
            size_t px = p0 + w * 16 + quad * 4 + r;
            buf[px * 1024 + o0 + nt * 16 + m] = __float2bfloat16(acc[nt][r]);
        }
    }
}

// -------------------------------------------------------------------------
// Kernel 2: per-gaussian fused deformable attention. 1 block = 1 gaussian.
// -------------------------------------------------------------------------
template<int BF>
__global__ __launch_bounds__(256, 6) void deform_attn_kernel(
    const void* __restrict__ means, const void* __restrict__ scales,
    const void* __restrict__ rot,   const void* __restrict__ features,
    const void* __restrict__ transforms, const void* __restrict__ projection,
    const void* __restrict__ Wq,    const void* __restrict__ W_off,
    const void* __restrict__ b_off, const void* __restrict__ Wout,
    const void* __restrict__ b_out, const bf16* __restrict__ buf,
    void* __restrict__ out, const int* __restrict__ flag)
{
    if (*flag != BF) return;
    __shared__ float feat[96];                              // features[g][3][32]
    __shared__ __attribute__((aligned(16))) float qf[1536]; // q_full [t][512]; later out_attn
    __shared__ float qm[512];                               // q_mean [h*64+d]
    __shared__ float mw[3], sc3[3], Rt[9], pr[12];
    __shared__ float lrn[144];                              // sigmoid-0.5, [h][18]
    __shared__ int   coff[96][4];                           // corner element offsets
    __shared__ float cwt[96][4];                            // corner weights (0 if invalid)
    __shared__ __attribute__((aligned(16))) char pool[12288]; // vs bf16 [96][64] / stage9 red
    __shared__ float att[288];                              // scores/attn [(h*3+t)*12+k]

    unsigned short* vsh = (unsigned short*)pool;
    const int g = blockIdx.x, tid = threadIdx.x;

    // ---- stage 0: tiny loads + per-gaussian geometry ----
    if (tid < 96) {
        feat[tid] = ldf<BF>(features, (size_t)g * 96 + tid);
    } else if (tid < 99) {
        sc3[tid - 96] = ldf<BF>(scales, (size_t)g * 3 + (tid - 96));
    } else if (tid >= 100 && tid < 112) {
        pr[tid - 100] = ldf<BF>(projection, tid - 100);
    } else if (tid == 112) {
        float w = ldf<BF>(rot, (size_t)g * 4),     x = ldf<BF>(rot, (size_t)g * 4 + 1);
        float y = ldf<BF>(rot, (size_t)g * 4 + 2), z = ldf<BF>(rot, (size_t)g * 4 + 3);
        float n = rsqrtf(w * w + x * x + y * y + z * z);
        w *= n; x *= n; y *= n; z *= n;
        float R00 = 1 - 2 * (y * y + z * z), R01 = 2 * (x * y - w * z), R02 = 2 * (x * z + w * y);
        float R10 = 2 * (x * y + w * z), R11 = 1 - 2 * (x * x + z * z), R12 = 2 * (y * z - w * x);
        float R20 = 2 * (x * z - w * y), R21 = 2 * (y * z + w * x), R22 = 1 - 2 * (x * x + y * y);
        Rt[0] = R00; Rt[1] = R10; Rt[2] = R20;
        Rt[3] = R01; Rt[4] = R11; Rt[5] = R21;
        Rt[6] = R02; Rt[7] = R12; Rt[8] = R22;
    } else if (tid >= 116 && tid < 119) {
        int i = tid - 116;
        float m0 = ldf<BF>(means, (size_t)g * 3);
        float m1 = ldf<BF>(means, (size_t)g * 3 + 1);
        float m2 = ldf<BF>(means, (size_t)g * 3 + 2);
        size_t tb = (size_t)g * 16 + i * 4;
        mw[i] = ldf<BF>(transforms, tb) * m0 + ldf<BF>(transforms, tb + 1) * m1
              + ldf<BF>(transforms, tb + 2) * m2 + ldf<BF>(transforms, tb + 3);
    }
    __syncthreads();

    // ---- stage 1: q_full = features @ Wq  (thread = 2 adjacent cols x 3 tokens) ----
    {
        const int a0 = tid * 2;
        float s00 = 0.f, s01 = 0.f, s10 = 0.f, s11 = 0.f, s20 = 0.f, s21 = 0.f;
#pragma unroll
        for (int f = 0; f < 32; f++) {
            float2 w2 = ld2f<BF>(Wq, (size_t)f * 512 + a0);
            float f0 = feat[f], f1 = feat[32 + f], f2 = feat[64 + f];
            s00 += f0 * w2.x; s01 += f0 * w2.y;
            s10 += f1 * w2.x; s11 += f1 * w2.y;
            s20 += f2 * w2.x; s21 += f2 * w2.y;
        }
        *(float2*)(qf + a0)        = make_float2(s00, s01);
        *(float2*)(qf + 512 + a0)  = make_float2(s10, s11);
        *(float2*)(qf + 1024 + a0) = make_float2(s20, s21);
    }
    __syncthreads();

    // ---- stage 2: q_mean over the 3 tokens ----
    qm[tid]       = (qf[tid]       + qf[tid + 512] + qf[tid + 1024]) * (1.f / 3.f);
    qm[tid + 256] = (qf[tid + 256] + qf[tid + 768] + qf[tid + 1280]) * (1.f / 3.f);
    __syncthreads();

    // ---- stage 3: OffsetNet  (67 -> 18 per head, sigmoid - 0.5) ----
    if (tid < 144) {
        int h = tid / 18, l = tid % 18;
        float s = ldf<BF>(b_off, l);
#pragma unroll
        for (int i = 0; i < 3; i++) s += mw[i] * ldf<BF>(W_off, i * 18 + l);
        for (int d = 0; d < 64; d++) s += qm[h * 64 + d] * ldf<BF>(W_off, (size_t)(3 + d) * 18 + l);
        s = fminf(fmaxf(s, -9.21f), 9.21f);
        lrn[tid] = 1.f / (1.f + expf(-s)) - 0.5f;
    }
    __syncthreads();

    // ---- stage 4: 96 sample points -> corner offsets + weights ----
    if (tid < 96) {
        int h = tid / 12, k = tid % 12;
        float s0, s1, s2;
        if (k < 6) {
            const float FSx[6] = {0.f, 1.f, 0.f, 0.f, -1.f, 0.f};
            const float FSy[6] = {0.f, 0.f, 1.f, 0.f, 0.f, -1.f};
            const float FSz[6] = {0.f, 0.f, 0.f, 1.f, 0.f, 0.f};
            s0 = FSx[k]; s1 = FSy[k]; s2 = FSz[k];
        } else {
            int b = h * 18 + (k - 6) * 3;
            s0 = lrn[b]; s1 = lrn[b + 1]; s2 = lrn[b + 2];
        }
        float o0 = s0 * sc3[0], o1 = s1 * sc3[1], o2 = s2 * sc3[2];
        float wx = Rt[0] * o0 + Rt[1] * o1 + Rt[2] * o2 + mw[0];
        float wy = Rt[3] * o0 + Rt[4] * o1 + Rt[5] * o2 + mw[1];
        float wz = Rt[6] * o0 + Rt[7] * o1 + Rt[8] * o2 + mw[2];
        float px = pr[0] * wx + pr[1] * wy + pr[2]  * wz + pr[3];
        float py = pr[4] * wx + pr[5] * wy + pr[6]  * wz + pr[7];
        float pz = pr[8] * wx + pr[9] * wy + pr[10] * wz + pr[11];
        pz = fmaxf(pz, 1e-5f);
        float gx = fminf(fmaxf(px / pz * (1.f / 64.f), 0.f), 0.9999f);
        float gy = fminf(fmaxf(py / pz * (1.f / 64.f), 0.f), 0.9999f);
        float x = gx * 64.f - 0.5f, y = gy * 64.f - 0.5f;
        float fx = floorf(x), fy = floorf(y);
        int x0 = (int)fx, y0 = (int)fy;
        float wx1 = x - fx, wx0c = 1.f - wx1;
        float wy1 = y - fy, wy0c = 1.f - wy1;
        int xs[2] = {x0, x0 + 1}, ys[2] = {y0, y0 + 1};
        float wxs[2] = {wx0c, wx1}, wys[2] = {wy0c, wy1};
#pragma unroll
        for (int c = 0; c < 4; c++) {
            int dx = c & 1, dy = c >> 1;
            int xi = xs[dx], yi = ys[dy];
            bool v = (xi >= 0) & (xi < 64) & (yi >= 0) & (yi < 64);
            int xc = min(max(xi, 0), 63), yc = min(max(yi, 0), 63);
            coff[tid][c] = (yc * 64 + xc) * 1024;
            cwt[tid][c]  = v ? wxs[dx] * wys[dy] : 0.f;
        }
    }
    __syncthreads();

    // ---- stage 5: branchless sample k/v (8 thr x 8 ch / point) + fused q.k ----
    {
        const int slice = tid & 7, d0 = slice * 8, grp = tid >> 3;
#pragma unroll
        for (int it = 0; it < 3; it++) {
            const int p = it * 32 + grp;
            const int h = p / 12, k = p - h * 12;
            const int a = h * 64 + d0;
            const bf16* bp = buf + a;
            float ka[8] = {0,0,0,0,0,0,0,0}, va[8] = {0,0,0,0,0,0,0,0}, t8[8];
#pragma unroll
            for (int c = 0; c < 4; c++) {
                const int   o = coff[p][c];
                const float w = cwt[p][c];
                ld8bf(bp + o, t8);
#pragma unroll
                for (int j = 0; j < 8; j++) ka[j] += w * t8[j];
                ld8bf(bp + o + 512, t8);
#pragma unroll
                for (int j = 0; j < 8; j++) va[j] += w * t8[j];
            }
            uint4 pv;
            pv.x = packbf(va[0], va[1]); pv.y = packbf(va[2], va[3]);
            pv.z = packbf(va[4], va[5]); pv.w = packbf(va[6], va[7]);
            *(uint4*)(vsh + p * 64 + d0) = pv;
            float sp[3];
#pragma unroll
            for (int t = 0; t < 3; t++) {
                const float* qp = qf + t * 512 + a;
                float s = 0.f;
#pragma unroll
                for (int j = 0; j < 8; j++) s += qp[j] * ka[j];
                sp[t] = s;
            }
#pragma unroll
            for (int msk = 1; msk < 8; msk <<= 1) {
#pragma unroll
                for (int t = 0; t < 3; t++) sp[t] += __shfl_xor(sp[t], msk);
            }
            if (slice == 0) {
#pragma unroll
                for (int t = 0; t < 3; t++) att[(h * 3 + t) * 12 + k] = sp[t] * 0.125f;
            }
        }
    }
    __syncthreads();

    // ---- stage 7: softmax over K=12 ----
    if (tid < 24) {
        float* row = att + tid * 12;
        float m = row[0];
#pragma unroll
        for (int k = 1; k < 12; k++) m = fmaxf(m, row[k]);
        float e_[12]; float ssum = 0.f;
#pragma unroll
        for (int k = 0; k < 12; k++) { e_[k] = expf(row[k] - m); ssum += e_[k]; }
        float inv = 1.f / ssum;
#pragma unroll
        for (int k = 0; k < 12; k++) row[k] = e_[k] * inv;
    }
    __syncthreads();

    // ---- stage 8: out_attn = attn @ v_s  -> reuse qf as [t][512] ----
#pragma unroll
    for (int i = 0; i < 6; i++) {
        int e = tid + i * 256;
        int t = e >> 9, a = e & 511, h = a >> 6, dd = a & 63;
        const float* ar = att + (h * 3 + t) * 12;
        const unsigned short* vp = vsh + (h * 12) * 64 + dd;
        float s = 0.f;
#pragma unroll
        for (int k = 0; k < 12; k++)
            s += ar[k] * __uint_as_float((unsigned)vp[k * 64] << 16);
        qf[e] = s;
    }
    __syncthreads();

    // ---- stage 9: out = oa @ Wout + b_out + feat; split-K over 16 slices ----
    {
        float* red = (float*)pool;   // vs dead; need 16*3*32 = 1536 floats
        const int c0 = (tid & 15) * 2, slice = tid >> 4;
        const int abase = slice * 32;
        float a00 = 0.f, a01 = 0.f, a10 = 0.f, a11 = 0.f, a20 = 0.f, a21 = 0.f;
#pragma unroll
        for (int i = 0; i < 32; i++) {
            int a = abase + i;
            float2 w2 = ld2f<BF>(Wout, (size_t)a * 32 + c0);
            float o0 = qf[a], o1 = qf[512 + a], o2 = qf[1024 + a];
            a00 += o0 * w2.x; a01 += o0 * w2.y;
            a10 += o1 * w2.x; a11 += o1 * w2.y;
            a20 += o2 * w2.x; a21 += o2 * w2.y;
        }
        __syncthreads();   // vsh reads (stage 8) complete before pool reuse
        red[(slice * 3 + 0) * 32 + c0] = a00; red[(slice * 3 + 0) * 32 + c0 + 1] = a01;
        red[(slice * 3 + 1) * 32 + c0] = a10; red[(slice * 3 + 1) * 32 + c0 + 1] = a11;
        red[(slice * 3 + 2) * 32 + c0] = a20; red[(slice * 3 + 2) * 32 + c0 + 1] = a21;
        __syncthreads();
        if (tid < 96) {
            int t = tid >> 5, c = tid & 31;
            float acc = ldf<BF>(b_out, c) + feat[tid];
#pragma unroll
            for (int s = 0; s < 16; s++) acc += red[(s * 3 + t) * 32 + c];
            size_t oi = (size_t)g * 96 + tid;
            if (BF) ((bf16*)out)[oi] = __float2bfloat16(acc);
            else    ((float*)out)[oi] = acc;
        }
    }
}

extern "C" void kernel_launch(void* const* d_in, const int* in_sizes, int n_in,
                              void* d_out, int out_size, void* d_ws, size_t ws_size,
                              hipStream_t stream) {
    const void* means      = d_in[0];
    const void* scales     = d_in[1];
    const void* rot        = d_in[2];
    const void* features   = d_in[3];
    const void* transforms = d_in[4];
    const void* projection = d_in[5];
    const void* img        = d_in[6];
    const void* Wq         = d_in[7];
    const void* Wk         = d_in[8];
    const void* Wv         = d_in[9];
    const void* W_off      = d_in[10];
    const void* b_off      = d_in[11];
    const void* Wout       = d_in[12];
    const void* b_out      = d_in[13];

    int*  flag = (int*)d_ws;
    bf16* buf  = (bf16*)((char*)d_ws + 64);   // 4096 px x 1024 ch bf16 = 8 MiB

    detect_dtype_kernel<<<1, 1, 0, stream>>>(projection, flag);

    dim3 grid1(64, 16);
    conv_mfma_kernel<1><<<grid1, 256, 0, stream>>>(img, Wk, Wv, buf, flag);
    conv_mfma_kernel<0><<<grid1, 256, 0, stream>>>(img, Wk, Wv, buf, flag);
    deform_attn_kernel<1><<<8192, 256, 0, stream>>>(
        means, scales, rot, features, transforms, projection,
        Wq, W_off, b_off, Wout, b_out, buf, d_out, flag);
    deform_attn_kernel<0><<<8192, 256, 0, stream>>>(
        means, scales, rot, features, transforms, projection,
        Wq, W_off, b_off, Wout, b_out, buf, d_out, flag);
}

// Round 6
// 211.450 us; speedup vs baseline: 3.6740x; 1.1575x over previous
//
#include <hip/hip_runtime.h>
#include <hip/hip_bf16.h>

typedef __hip_bfloat16 bf16;
typedef __attribute__((ext_vector_type(8))) short short8;
typedef __attribute__((ext_vector_type(4))) float float4v;

// ---- helpers: inputs are fp32; MFMA operands / intermediates are bf16 ----
__device__ __forceinline__ unsigned short f2bfu(float f) {
    bf16 b = __float2bfloat16(f);
    return *(unsigned short*)&b;
}
// unpack 8 bf16 (16B aligned) to 8 floats
__device__ __forceinline__ void ld8bf(const bf16* p, float* f) {
    uint4 u = *(const uint4*)p;
    f[0] = __uint_as_float(u.x << 16); f[1] = __uint_as_float(u.x & 0xffff0000u);
    f[2] = __uint_as_float(u.y << 16); f[3] = __uint_as_float(u.y & 0xffff0000u);
    f[4] = __uint_as_float(u.z << 16); f[5] = __uint_as_float(u.z & 0xffff0000u);
    f[6] = __uint_as_float(u.w << 16); f[7] = __uint_as_float(u.w & 0xffff0000u);
}
__device__ __forceinline__ unsigned packbf(float lo, float hi) {
    return (unsigned)f2bfu(lo) | ((unsigned)f2bfu(hi) << 16);
}

// -------------------------------------------------------------------------
// Kernel 1: MFMA 1x1 conv.  buf[px][1024](bf16) = img^T[px][256k] @ (Wk|Wv)^T
// fp32 inputs converted to bf16 at staging / fragment load.
// -------------------------------------------------------------------------
__global__ __launch_bounds__(256) void conv_mfma_kernel(
    const float* __restrict__ img, const float* __restrict__ Wk,
    const float* __restrict__ Wv, bf16* __restrict__ buf)
{
    __shared__ __attribute__((aligned(16))) unsigned short Bt[64][264]; // [px][k], +8 pad
    const int tid = threadIdx.x;
    const int p0 = blockIdx.x * 64;
    const int o0 = blockIdx.y * 64;

#pragma unroll
    for (int i = 0; i < 4; i++) {
        int chunk = i * 256 + tid;
        int kp  = chunk >> 3;              // k-pair index
        int pxg = (chunk & 7) * 8;         // 8-pixel group
        const float* r0 = img + (size_t)(2 * kp) * 4096 + p0 + pxg;
        const float* r1 = img + (size_t)(2 * kp + 1) * 4096 + p0 + pxg;
        float4 a0 = *(const float4*)r0, a1 = *(const float4*)(r0 + 4);
        float4 b0 = *(const float4*)r1, b1 = *(const float4*)(r1 + 4);
        unsigned lo[8], hi[8];
        lo[0] = f2bfu(a0.x); lo[1] = f2bfu(a0.y); lo[2] = f2bfu(a0.z); lo[3] = f2bfu(a0.w);
        lo[4] = f2bfu(a1.x); lo[5] = f2bfu(a1.y); lo[6] = f2bfu(a1.z); lo[7] = f2bfu(a1.w);
        hi[0] = f2bfu(b0.x); hi[1] = f2bfu(b0.y); hi[2] = f2bfu(b0.z); hi[3] = f2bfu(b0.w);
        hi[4] = f2bfu(b1.x); hi[5] = f2bfu(b1.y); hi[6] = f2bfu(b1.z); hi[7] = f2bfu(b1.w);
#pragma unroll
        for (int j = 0; j < 8; j++)
            *(unsigned*)&Bt[pxg + j][2 * kp] = lo[j] | (hi[j] << 16);
    }
    __syncthreads();

    const int w = tid >> 6, l = tid & 63;
    const int m = l & 15, quad = l >> 4;
    const int mrow = w * 16 + m;
    const float* Wsel = (o0 < 512) ? Wk : Wv;
    const int obase = (o0 < 512) ? o0 : (o0 - 512);

    float4v acc[4] = {{0,0,0,0},{0,0,0,0},{0,0,0,0},{0,0,0,0}};
#pragma unroll
    for (int kk = 0; kk < 8; kk++) {
        const int kofs = kk * 32 + quad * 8;
        short8 af = *(const short8*)&Bt[mrow][kofs];
#pragma unroll
        for (int nt = 0; nt < 4; nt++) {
            const int row = obase + nt * 16 + m;
            const float* wp = Wsel + (size_t)row * 256 + kofs;
            float4 w0 = *(const float4*)wp, w1 = *(const float4*)(wp + 4);
            short8 b8;
            b8[0] = (short)f2bfu(w0.x); b8[1] = (short)f2bfu(w0.y);
            b8[2] = (short)f2bfu(w0.z); b8[3] = (short)f2bfu(w0.w);
            b8[4] = (short)f2bfu(w1.x); b8[5] = (short)f2bfu(w1.y);
            b8[6] = (short)f2bfu(w1.z); b8[7] = (short)f2bfu(w1.w);
            acc[nt] = __builtin_amdgcn_mfma_f32_16x16x32_bf16(af, b8, acc[nt], 0, 0, 0);
        }
    }
#pragma unroll
    for (int nt = 0; nt < 4; nt++) {
#pragma unroll
        for (int r = 0; r < 4; r++) {
            size_t px = p0 + w * 16 + quad * 4 + r;
            buf[px * 1024 + o0 + nt * 16 + m] = __float2bfloat16(acc[nt][r]);
        }
    }
}

// -------------------------------------------------------------------------
// Kernel 2: qfull[24576,512](bf16) = features[24576,32](fp32) @ Wq[32,512](fp32)
// grid (384, 2); block 256 = 4 waves; wave = 16 rows x 256 cols.
// -------------------------------------------------------------------------
__global__ __launch_bounds__(256) void qgemm_kernel(
    const float* __restrict__ features, const float* __restrict__ Wq,
    bf16* __restrict__ qfull)
{
    __shared__ __attribute__((aligned(16))) unsigned short WqT[256][40]; // [n][k]
    const int tid = threadIdx.x;
    const int R0 = blockIdx.x * 64;
    const int n0 = blockIdx.y * 256;
#pragma unroll
    for (int k = 0; k < 32; k++)
        WqT[tid][k] = f2bfu(Wq[(size_t)k * 512 + n0 + tid]);
    __syncthreads();

    const int w = tid >> 6, l = tid & 63, m = l & 15, quad = l >> 4;
    const int row = R0 + w * 16 + m;
    const float* fp = features + (size_t)row * 32 + quad * 8;
    float4 f0 = *(const float4*)fp, f1 = *(const float4*)(fp + 4);
    short8 af;
    af[0] = (short)f2bfu(f0.x); af[1] = (short)f2bfu(f0.y);
    af[2] = (short)f2bfu(f0.z); af[3] = (short)f2bfu(f0.w);
    af[4] = (short)f2bfu(f1.x); af[5] = (short)f2bfu(f1.y);
    af[6] = (short)f2bfu(f1.z); af[7] = (short)f2bfu(f1.w);
    float4v acc[16];
#pragma unroll
    for (int t = 0; t < 16; t++) acc[t] = (float4v){0.f, 0.f, 0.f, 0.f};
#pragma unroll
    for (int t = 0; t < 16; t++) {
        short8 b8 = *(const short8*)&WqT[t * 16 + m][quad * 8];
        acc[t] = __builtin_amdgcn_mfma_f32_16x16x32_bf16(af, b8, acc[t], 0, 0, 0);
    }
    const int rb = R0 + w * 16 + quad * 4;
#pragma unroll
    for (int t = 0; t < 16; t++)
#pragma unroll
        for (int r = 0; r < 4; r++)
            qfull[(size_t)(rb + r) * 512 + n0 + t * 16 + m] = __float2bfloat16(acc[t][r]);
}

// -------------------------------------------------------------------------
// Kernel 3: per-gaussian sampling + attention core. 1 block = 1 gaussian.
// Reads qfull (bf16), writes out_attn IN PLACE into qfull (own rows only).
// -------------------------------------------------------------------------
__global__ __launch_bounds__(256, 7) void attn_core_kernel(
    const float* __restrict__ means, const float* __restrict__ scales,
    const float* __restrict__ rot,   const float* __restrict__ transforms,
    const float* __restrict__ projection, const float* __restrict__ W_off,
    const float* __restrict__ b_off, const bf16* __restrict__ buf,
    bf16* __restrict__ qfull)
{
    __shared__ __attribute__((aligned(16))) float qf[1536];           // q fp32 [t][512]
    __shared__ __attribute__((aligned(16))) unsigned short vsh[6144]; // v bf16 [p][64]
    __shared__ __attribute__((aligned(16))) float qm_u[512];          // qm | corner+att
    __shared__ float lrn[144];
    __shared__ float mw[3], sc3[3], Rt[9], pr[12];

    short4* corner = (short4*)qm_u;       // 96 x 8 B (live stage4+)
    float*  att    = qm_u + 192;          // 288 floats (live stage5+)

    const int g = blockIdx.x, tid = threadIdx.x;

    // ---- stage 0: geometry + q staging ----
    if (tid < 3) {
        sc3[tid] = scales[(size_t)g * 3 + tid];
    } else if (tid >= 4 && tid < 16) {
        pr[tid - 4] = projection[tid - 4];
    } else if (tid == 16) {
        float w = rot[(size_t)g * 4],     x = rot[(size_t)g * 4 + 1];
        float y = rot[(size_t)g * 4 + 2], z = rot[(size_t)g * 4 + 3];
        float n = rsqrtf(w * w + x * x + y * y + z * z);
        w *= n; x *= n; y *= n; z *= n;
        float R00 = 1 - 2 * (y * y + z * z), R01 = 2 * (x * y - w * z), R02 = 2 * (x * z + w * y);
        float R10 = 2 * (x * y + w * z), R11 = 1 - 2 * (x * x + z * z), R12 = 2 * (y * z - w * x);
        float R20 = 2 * (x * z - w * y), R21 = 2 * (y * z + w * x), R22 = 1 - 2 * (x * x + y * y);
        Rt[0] = R00; Rt[1] = R10; Rt[2] = R20;
        Rt[3] = R01; Rt[4] = R11; Rt[5] = R21;
        Rt[6] = R02; Rt[7] = R12; Rt[8] = R22;
    } else if (tid >= 20 && tid < 23) {
        int i = tid - 20;
        float m0 = means[(size_t)g * 3];
        float m1 = means[(size_t)g * 3 + 1];
        float m2 = means[(size_t)g * 3 + 2];
        const float* T = transforms + (size_t)g * 16 + i * 4;
        mw[i] = T[0] * m0 + T[1] * m1 + T[2] * m2 + T[3];
    }
    {
        const unsigned short* qsrc = (const unsigned short*)qfull + (size_t)g * 1536;
#pragma unroll
        for (int i = 0; i < 6; i++) {
            int e = tid + i * 256;
            qf[e] = __uint_as_float((unsigned)qsrc[e] << 16);
        }
    }
    __syncthreads();

    // ---- stage 2: q_mean ----
    qm_u[tid]       = (qf[tid]       + qf[tid + 512] + qf[tid + 1024]) * (1.f / 3.f);
    qm_u[tid + 256] = (qf[tid + 256] + qf[tid + 768] + qf[tid + 1280]) * (1.f / 3.f);
    __syncthreads();

    // ---- stage 3: OffsetNet ----
    if (tid < 144) {
        int h = tid / 18, l = tid % 18;
        float s = b_off[l];
#pragma unroll
        for (int i = 0; i < 3; i++) s += mw[i] * W_off[i * 18 + l];
        for (int d = 0; d < 64; d++) s += qm_u[h * 64 + d] * W_off[(size_t)(3 + d) * 18 + l];
        s = fminf(fmaxf(s, -9.21f), 9.21f);
        lrn[tid] = 1.f / (1.f + expf(-s)) - 0.5f;
    }
    __syncthreads();

    // ---- stage 4: sample coords -> corner short4 {x0, y0, wx1_u16, wy1_u16} ----
    if (tid < 96) {
        int h = tid / 12, k = tid % 12;
        float s0, s1, s2;
        if (k < 6) {
            const float FSx[6] = {0.f, 1.f, 0.f, 0.f, -1.f, 0.f};
            const float FSy[6] = {0.f, 0.f, 1.f, 0.f, 0.f, -1.f};
            const float FSz[6] = {0.f, 0.f, 0.f, 1.f, 0.f, 0.f};
            s0 = FSx[k]; s1 = FSy[k]; s2 = FSz[k];
        } else {
            int b = h * 18 + (k - 6) * 3;
            s0 = lrn[b]; s1 = lrn[b + 1]; s2 = lrn[b + 2];
        }
        float o0 = s0 * sc3[0], o1 = s1 * sc3[1], o2 = s2 * sc3[2];
        float wx = Rt[0] * o0 + Rt[1] * o1 + Rt[2] * o2 + mw[0];
        float wy = Rt[3] * o0 + Rt[4] * o1 + Rt[5] * o2 + mw[1];
        float wz = Rt[6] * o0 + Rt[7] * o1 + Rt[8] * o2 + mw[2];
        float px = pr[0] * wx + pr[1] * wy + pr[2]  * wz + pr[3];
        float py = pr[4] * wx + pr[5] * wy + pr[6]  * wz + pr[7];
        float pz = pr[8] * wx + pr[9] * wy + pr[10] * wz + pr[11];
        pz = fmaxf(pz, 1e-5f);
        float gx = fminf(fmaxf(px / pz * (1.f / 64.f), 0.f), 0.9999f);
        float gy = fminf(fmaxf(py / pz * (1.f / 64.f), 0.f), 0.9999f);
        float x = gx * 64.f - 0.5f, y = gy * 64.f - 0.5f;
        float fx = floorf(x), fy = floorf(y);
        short4 cn;
        cn.x = (short)(int)fx;
        cn.y = (short)(int)fy;
        cn.z = (short)(unsigned short)fminf((x - fx) * 65536.f, 65535.f);
        cn.w = (short)(unsigned short)fminf((y - fy) * 65536.f, 65535.f);
        corner[tid] = cn;
    }
    __syncthreads();

    // ---- stage 5: sample k/v + fused q.k scores ----
    {
        const int slice = tid & 7, d0 = slice * 8, grp = tid >> 3;
#pragma unroll
        for (int it = 0; it < 3; it++) {
            const int p = it * 32 + grp;
            const int h = p / 12, k = p - h * 12;
            short4 cn = corner[p];
            int x0 = cn.x, y0 = cn.y, x1 = x0 + 1, y1 = y0 + 1;
            float wx1 = (float)(unsigned short)cn.z * (1.f / 65536.f);
            float wy1 = (float)(unsigned short)cn.w * (1.f / 65536.f);
            float wx0 = 1.f - wx1, wy0 = 1.f - wy1;
            bool vx0 = (unsigned)x0 < 64u, vx1 = (unsigned)x1 < 64u;
            bool vy0 = (unsigned)y0 < 64u, vy1 = (unsigned)y1 < 64u;
            int xc0 = min(max(x0, 0), 63), xc1 = min(max(x1, 0), 63);
            int yc0 = min(max(y0, 0), 63), yc1 = min(max(y1, 0), 63);
            int   off[4];
            float wt[4];
            off[0] = (yc0 * 64 + xc0) * 1024; wt[0] = (vx0 & vy0) ? wx0 * wy0 : 0.f;
            off[1] = (yc0 * 64 + xc1) * 1024; wt[1] = (vx1 & vy0) ? wx1 * wy0 : 0.f;
            off[2] = (yc1 * 64 + xc0) * 1024; wt[2] = (vx0 & vy1) ? wx0 * wy1 : 0.f;
            off[3] = (yc1 * 64 + xc1) * 1024; wt[3] = (vx1 & vy1) ? wx1 * wy1 : 0.f;
            const int a = h * 64 + d0;
            const bf16* bp = buf + a;
            float ka[8] = {0,0,0,0,0,0,0,0}, va[8] = {0,0,0,0,0,0,0,0}, t8[8];
#pragma unroll
            for (int c = 0; c < 4; c++) {
                const float w = wt[c];
                ld8bf(bp + off[c], t8);
#pragma unroll
                for (int j = 0; j < 8; j++) ka[j] += w * t8[j];
                ld8bf(bp + off[c] + 512, t8);
#pragma unroll
                for (int j = 0; j < 8; j++) va[j] += w * t8[j];
            }
            uint4 pv;
            pv.x = packbf(va[0], va[1]); pv.y = packbf(va[2], va[3]);
            pv.z = packbf(va[4], va[5]); pv.w = packbf(va[6], va[7]);
            *(uint4*)(vsh + p * 64 + d0) = pv;
            float sp[3];
#pragma unroll
            for (int t = 0; t < 3; t++) {
                const float* qp = qf + t * 512 + a;
                float s = 0.f;
#pragma unroll
                for (int j = 0; j < 8; j++) s += qp[j] * ka[j];
                sp[t] = s;
            }
#pragma unroll
            for (int msk = 1; msk < 8; msk <<= 1) {
#pragma unroll
                for (int t = 0; t < 3; t++) sp[t] += __shfl_xor(sp[t], msk);
            }
            if (slice == 0) {
#pragma unroll
                for (int t = 0; t < 3; t++) att[(h * 3 + t) * 12 + k] = sp[t] * 0.125f;
            }
        }
    }
    __syncthreads();

    // ---- stage 7: softmax over K=12 ----
    if (tid < 24) {
        float* row = att + tid * 12;
        float m = row[0];
#pragma unroll
        for (int k = 1; k < 12; k++) m = fmaxf(m, row[k]);
        float e_[12]; float ssum = 0.f;
#pragma unroll
        for (int k = 0; k < 12; k++) { e_[k] = expf(row[k] - m); ssum += e_[k]; }
        float inv = 1.f / ssum;
#pragma unroll
        for (int k = 0; k < 12; k++) row[k] = e_[k] * inv;
    }
    __syncthreads();

    // ---- stage 8: out_attn = attn @ v_s -> in place into qfull rows ----
    {
        unsigned short* oa = (unsigned short*)qfull + (size_t)g * 1536;
#pragma unroll
        for (int i = 0; i < 6; i++) {
            int e = tid + i * 256;
            int t = e >> 9, a = e & 511, h = a >> 6, dd = a & 63;
            const float* ar = att + (h * 3 + t) * 12;
            const unsigned short* vp = vsh + (h * 12) * 64 + dd;
            float s = 0.f;
#pragma unroll
            for (int k = 0; k < 12; k++)
                s += ar[k] * __uint_as_float((unsigned)vp[k * 64] << 16);
            oa[e] = f2bfu(s);
        }
    }
}

// -------------------------------------------------------------------------
// Kernel 4: out[24576,32](fp32) = oa[24576,512](bf16) @ Wout[512,32](fp32)
//           + b_out + features
// -------------------------------------------------------------------------
__global__ __launch_bounds__(256) void outgemm_kernel(
    const bf16* __restrict__ oa, const float* __restrict__ Wout,
    const float* __restrict__ b_out, const float* __restrict__ features,
    float* __restrict__ out)
{
    __shared__ __attribute__((aligned(16))) unsigned short WT[32][520]; // [n][k]
    const int tid = threadIdx.x;
    const int R0 = blockIdx.x * 64;
#pragma unroll
    for (int j = 0; j < 64; j++) {
        int lin = j * 256 + tid;         // lin = k*32 + n
        WT[lin & 31][lin >> 5] = f2bfu(Wout[lin]);
    }
    __syncthreads();

    const int w = tid >> 6, l = tid & 63, m = l & 15, quad = l >> 4;
    const int row = R0 + w * 16 + m;
    float4v acc[2] = {{0,0,0,0},{0,0,0,0}};
#pragma unroll
    for (int kk = 0; kk < 16; kk++) {
        short8 af = *(const short8*)((const unsigned short*)oa + (size_t)row * 512 + kk * 32 + quad * 8);
#pragma unroll
        for (int t = 0; t < 2; t++) {
            short8 b8 = *(const short8*)&WT[t * 16 + m][kk * 32 + quad * 8];
            acc[t] = __builtin_amdgcn_mfma_f32_16x16x32_bf16(af, b8, acc[t], 0, 0, 0);
        }
    }
    const int rb = R0 + w * 16 + quad * 4;
#pragma unroll
    for (int t = 0; t < 2; t++) {
        int col = t * 16 + m;
        float bb = b_out[col];
#pragma unroll
        for (int r = 0; r < 4; r++) {
            int rr = rb + r;
            out[(size_t)rr * 32 + col] = acc[t][r] + bb + features[(size_t)rr * 32 + col];
        }
    }
}

// -------------------------------------------------------------------------
// Fallback (ws too small): round-4 fused attention kernel, fp32 inputs.
// -------------------------------------------------------------------------
__global__ __launch_bounds__(256, 6) void attn_fused_kernel(
    const float* __restrict__ means, const float* __restrict__ scales,
    const float* __restrict__ rot,   const float* __restrict__ features,
    const float* __restrict__ transforms, const float* __restrict__ projection,
    const float* __restrict__ Wq,    const float* __restrict__ W_off,
    const float* __restrict__ b_off, const float* __restrict__ Wout,
    const float* __restrict__ b_out, const bf16* __restrict__ buf,
    float* __restrict__ out)
{
    __shared__ float feat[96];
    __shared__ __attribute__((aligned(16))) float qf[1536];
    __shared__ float qm[512];
    __shared__ float mw[3], sc3[3], Rt[9], pr[12];
    __shared__ float lrn[144];
    __shared__ int   coff[96][4];
    __shared__ float cwt[96][4];
    __shared__ __attribute__((aligned(16))) char pool[12288];
    __shared__ float att[288];

    unsigned short* vsh = (unsigned short*)pool;
    const int g = blockIdx.x, tid = threadIdx.x;

    if (tid < 96) {
        feat[tid] = features[(size_t)g * 96 + tid];
    } else if (tid < 99) {
        sc3[tid - 96] = scales[(size_t)g * 3 + (tid - 96)];
    } else if (tid >= 100 && tid < 112) {
        pr[tid - 100] = projection[tid - 100];
    } else if (tid == 112) {
        float w = rot[(size_t)g * 4],     x = rot[(size_t)g * 4 + 1];
        float y = rot[(size_t)g * 4 + 2], z = rot[(size_t)g * 4 + 3];
        float n = rsqrtf(w * w + x * x + y * y + z * z);
        w *= n; x *= n; y *= n; z *= n;
        float R00 = 1 - 2 * (y * y + z * z), R01 = 2 * (x * y - w * z), R02 = 2 * (x * z + w * y);
        float R10 = 2 * (x * y + w * z), R11 = 1 - 2 * (x * x + z * z), R12 = 2 * (y * z - w * x);
        float R20 = 2 * (x * z - w * y), R21 = 2 * (y * z + w * x), R22 = 1 - 2 * (x * x + y * y);
        Rt[0] = R00; Rt[1] = R10; Rt[2] = R20;
        Rt[3] = R01; Rt[4] = R11; Rt[5] = R21;
        Rt[6] = R02; Rt[7] = R12; Rt[8] = R22;
    } else if (tid >= 116 && tid < 119) {
        int i = tid - 116;
        float m0 = means[(size_t)g * 3];
        float m1 = means[(size_t)g * 3 + 1];
        float m2 = means[(size_t)g * 3 + 2];
        const float* T = transforms + (size_t)g * 16 + i * 4;
        mw[i] = T[0] * m0 + T[1] * m1 + T[2] * m2 + T[3];
    }
    __syncthreads();

    {
        const int a0 = tid * 2;
        float s00 = 0.f, s01 = 0.f, s10 = 0.f, s11 = 0.f, s20 = 0.f, s21 = 0.f;
#pragma unroll
        for (int f = 0; f < 32; f++) {
            float2 w2 = *(const float2*)(Wq + (size_t)f * 512 + a0);
            float f0 = feat[f], f1 = feat[32 + f], f2 = feat[64 + f];
            s00 += f0 * w2.x; s01 += f0 * w2.y;
            s10 += f1 * w2.x; s11 += f1 * w2.y;
            s20 += f2 * w2.x; s21 += f2 * w2.y;
        }
        *(float2*)(qf + a0)        = make_float2(s00, s01);
        *(float2*)(qf + 512 + a0)  = make_float2(s10, s11);
        *(float2*)(qf + 1024 + a0) = make_float2(s20, s21);
    }
    __syncthreads();

    qm[tid]       = (qf[tid]       + qf[tid + 512] + qf[tid + 1024]) * (1.f / 3.f);
    qm[tid + 256] = (qf[tid + 256] + qf[tid + 768] + qf[tid + 1280]) * (1.f / 3.f);
    __syncthreads();

    if (tid < 144) {
        int h = tid / 18, l = tid % 18;
        float s = b_off[l];
#pragma unroll
        for (int i = 0; i < 3; i++) s += mw[i] * W_off[i * 18 + l];
        for (int d = 0; d < 64; d++) s += qm[h * 64 + d] * W_off[(size_t)(3 + d) * 18 + l];
        s = fminf(fmaxf(s, -9.21f), 9.21f);
        lrn[tid] = 1.f / (1.f + expf(-s)) - 0.5f;
    }
    __syncthreads();

    if (tid < 96) {
        int h = tid / 12, k = tid % 12;
        float s0, s1, s2;
        if (k < 6) {
            const float FSx[6] = {0.f, 1.f, 0.f, 0.f, -1.f, 0.f};
            const float FSy[6] = {0.f, 0.f, 1.f, 0.f, 0.f, -1.f};
            const float FSz[6] = {0.f, 0.f, 0.f, 1.f, 0.f, 0.f};
            s0 = FSx[k]; s1 = FSy[k]; s2 = FSz[k];
        } else {
            int b = h * 18 + (k - 6) * 3;
            s0 = lrn[b]; s1 = lrn[b + 1]; s2 = lrn[b + 2];
        }
        float o0 = s0 * sc3[0], o1 = s1 * sc3[1], o2 = s2 * sc3[2];
        float wx = Rt[0] * o0 + Rt[1] * o1 + Rt[2] * o2 + mw[0];
        float wy = Rt[3] * o0 + Rt[4] * o1 + Rt[5] * o2 + mw[1];
        float wz = Rt[6] * o0 + Rt[7] * o1 + Rt[8] * o2 + mw[2];
        float px = pr[0] * wx + pr[1] * wy + pr[2]  * wz + pr[3];
        float py = pr[4] * wx + pr[5] * wy + pr[6]  * wz + pr[7];
        float pz = pr[8] * wx + pr[9] * wy + pr[10] * wz + pr[11];
        pz = fmaxf(pz, 1e-5f);
        float gx = fminf(fmaxf(px / pz * (1.f / 64.f), 0.f), 0.9999f);
        float gy = fminf(fmaxf(py / pz * (1.f / 64.f), 0.f), 0.9999f);
        float x = gx * 64.f - 0.5f, y = gy * 64.f - 0.5f;
        float fx = floorf(x), fy = floorf(y);
        int x0 = (int)fx, y0 = (int)fy;
        float wx1 = x - fx, wx0c = 1.f - wx1;
        float wy1 = y - fy, wy0c = 1.f - wy1;
        int xs[2] = {x0, x0 + 1}, ys[2] = {y0, y0 + 1};
        float wxs[2] = {wx0c, wx1}, wys[2] = {wy0c, wy1};
#pragma unroll
        for (int c = 0; c < 4; c++) {
            int dx = c & 1, dy = c >> 1;
            int xi = xs[dx], yi = ys[dy];
            bool v = (xi >= 0) & (xi < 64) & (yi >= 0) & (yi < 64);
            int xc = min(max(xi, 0), 63), yc = min(max(yi, 0), 63);
            coff[tid][c] = (yc * 64 + xc) * 1024;
            cwt[tid][c]  = v ? wxs[dx] * wys[dy] : 0.f;
        }
    }
    __syncthreads();

    {
        const int slice = tid & 7, d0 = slice * 8, grp = tid >> 3;
#pragma unroll
        for (int it = 0; it < 3; it++) {
            const int p = it * 32 + grp;
            const int h = p / 12, k = p - h * 12;
            const int a = h * 64 + d0;
            const bf16* bp = buf + a;
            float ka[8] = {0,0,0,0,0,0,0,0}, va[8] = {0,0,0,0,0,0,0,0}, t8[8];
#pragma unroll
            for (int c = 0; c < 4; c++) {
                const int   o = coff[p][c];
                const float w = cwt[p][c];
                ld8bf(bp + o, t8);
#pragma unroll
                for (int j = 0; j < 8; j++) ka[j] += w * t8[j];
                ld8bf(bp + o + 512, t8);
#pragma unroll
                for (int j = 0; j < 8; j++) va[j] += w * t8[j];
            }
            uint4 pv;
            pv.x = packbf(va[0], va[1]); pv.y = packbf(va[2], va[3]);
            pv.z = packbf(va[4], va[5]); pv.w = packbf(va[6], va[7]);
            *(uint4*)(vsh + p * 64 + d0) = pv;
            float sp[3];
#pragma unroll
            for (int t = 0; t < 3; t++) {
                const float* qp = qf + t * 512 + a;
                float s = 0.f;
#pragma unroll
                for (int j = 0; j < 8; j++) s += qp[j] * ka[j];
                sp[t] = s;
            }
#pragma unroll
            for (int msk = 1; msk < 8; msk <<= 1) {
#pragma unroll
                for (int t = 0; t < 3; t++) sp[t] += __shfl_xor(sp[t], msk);
            }
            if (slice == 0) {
#pragma unroll
                for (int t = 0; t < 3; t++) att[(h * 3 + t) * 12 + k] = sp[t] * 0.125f;
            }
        }
    }
    __syncthreads();

    if (tid < 24) {
        float* row = att + tid * 12;
        float m = row[0];
#pragma unroll
        for (int k = 1; k < 12; k++) m = fmaxf(m, row[k]);
        float e_[12]; float ssum = 0.f;
#pragma unroll
        for (int k = 0; k < 12; k++) { e_[k] = expf(row[k] - m); ssum += e_[k]; }
        float inv = 1.f / ssum;
#pragma unroll
        for (int k = 0; k < 12; k++) row[k] = e_[k] * inv;
    }
    __syncthreads();

#pragma unroll
    for (int i = 0; i < 6; i++) {
        int e = tid + i * 256;
        int t = e >> 9, a = e & 511, h = a >> 6, dd = a & 63;
        const float* ar = att + (h * 3 + t) * 12;
        const unsigned short* vp = vsh + (h * 12) * 64 + dd;
        float s = 0.f;
#pragma unroll
        for (int k = 0; k < 12; k++)
            s += ar[k] * __uint_as_float((unsigned)vp[k * 64] << 16);
        qf[e] = s;
    }
    __syncthreads();

    {
        float* red = (float*)pool;
        const int c0 = (tid & 15) * 2, slice = tid >> 4;
        const int abase = slice * 32;
        float a00 = 0.f, a01 = 0.f, a10 = 0.f, a11 = 0.f, a20 = 0.f, a21 = 0.f;
#pragma unroll
        for (int i = 0; i < 32; i++) {
            int a = abase + i;
            float2 w2 = *(const float2*)(Wout + (size_t)a * 32 + c0);
            float o0 = qf[a], o1 = qf[512 + a], o2 = qf[1024 + a];
            a00 += o0 * w2.x; a01 += o0 * w2.y;
            a10 += o1 * w2.x; a11 += o1 * w2.y;
            a20 += o2 * w2.x; a21 += o2 * w2.y;
        }
        __syncthreads();
        red[(slice * 3 + 0) * 32 + c0] = a00; red[(slice * 3 + 0) * 32 + c0 + 1] = a01;
        red[(slice * 3 + 1) * 32 + c0] = a10; red[(slice * 3 + 1) * 32 + c0 + 1] = a11;
        red[(slice * 3 + 2) * 32 + c0] = a20; red[(slice * 3 + 2) * 32 + c0 + 1] = a21;
        __syncthreads();
        if (tid < 96) {
            int t = tid >> 5, c = tid & 31;
            float acc = b_out[c] + feat[tid];
#pragma unroll
            for (int s = 0; s < 16; s++) acc += red[(s * 3 + t) * 32 + c];
            out[(size_t)g * 96 + tid] = acc;
        }
    }
}

extern "C" void kernel_launch(void* const* d_in, const int* in_sizes, int n_in,
                              void* d_out, int out_size, void* d_ws, size_t ws_size,
                              hipStream_t stream) {
    const float* means      = (const float*)d_in[0];
    const float* scales     = (const float*)d_in[1];
    const float* rot        = (const float*)d_in[2];
    const float* features   = (const float*)d_in[3];
    const float* transforms = (const float*)d_in[4];
    const float* projection = (const float*)d_in[5];
    const float* img        = (const float*)d_in[6];
    const float* Wq         = (const float*)d_in[7];
    const float* Wk         = (const float*)d_in[8];
    const float* Wv         = (const float*)d_in[9];
    const float* W_off      = (const float*)d_in[10];
    const float* b_off      = (const float*)d_in[11];
    const float* Wout       = (const float*)d_in[12];
    const float* b_out      = (const float*)d_in[13];
    float* out = (float*)d_out;

    char* w = (char*)d_ws;
    bf16* buf = (bf16*)(w + 64);                       // 4096 x 1024 bf16 = 8 MiB
    const size_t BUF_BYTES = (size_t)4096 * 1024 * 2;
    const size_t Q_BYTES   = (size_t)24576 * 512 * 2;  // 24 MiB
    const size_t need = 64 + BUF_BYTES + Q_BYTES;

    dim3 gridc(64, 16);
    conv_mfma_kernel<<<gridc, 256, 0, stream>>>(img, Wk, Wv, buf);

    if (ws_size >= need) {
        bf16* qfull = (bf16*)(w + 64 + BUF_BYTES);
        dim3 gridq(384, 2);
        qgemm_kernel<<<gridq, 256, 0, stream>>>(features, Wq, qfull);
        attn_core_kernel<<<8192, 256, 0, stream>>>(
            means, scales, rot, transforms, projection, W_off, b_off, buf, qfull);
        outgemm_kernel<<<384, 256, 0, stream>>>(qfull, Wout, b_out, features, out);
    } else {
        attn_fused_kernel<<<8192, 256, 0, stream>>>(
            means, scales, rot, features, transforms, projection,
            Wq, W_off, b_off, Wout, b_out, buf, out);
    }
}

// Round 7
// 183.800 us; speedup vs baseline: 4.2268x; 1.1504x over previous
//
#include <hip/hip_runtime.h>
#include <hip/hip_bf16.h>

typedef __hip_bfloat16 bf16;
typedef __attribute__((ext_vector_type(8))) short short8;
typedef __attribute__((ext_vector_type(4))) float float4v;

// ---- helpers: inputs are fp32; MFMA operands / intermediates are bf16 ----
__device__ __forceinline__ unsigned short f2bfu(float f) {
    bf16 b = __float2bfloat16(f);
    return *(unsigned short*)&b;
}
// unpack 8 bf16 (16B aligned) to 8 floats
__device__ __forceinline__ void ld8bf(const bf16* p, float* f) {
    uint4 u = *(const uint4*)p;
    f[0] = __uint_as_float(u.x << 16); f[1] = __uint_as_float(u.x & 0xffff0000u);
    f[2] = __uint_as_float(u.y << 16); f[3] = __uint_as_float(u.y & 0xffff0000u);
    f[4] = __uint_as_float(u.z << 16); f[5] = __uint_as_float(u.z & 0xffff0000u);
    f[6] = __uint_as_float(u.w << 16); f[7] = __uint_as_float(u.w & 0xffff0000u);
}
__device__ __forceinline__ unsigned packbf(float lo, float hi) {
    return (unsigned)f2bfu(lo) | ((unsigned)f2bfu(hi) << 16);
}

// -------------------------------------------------------------------------
// Kernel 0: preconvert img (1048576 el) + Wk|Wv (262144 el) fp32 -> bf16.
// 1280 blocks x 256 threads x 4 elems.
// -------------------------------------------------------------------------
__global__ __launch_bounds__(256) void preconvert_kernel(
    const float* __restrict__ img, const float* __restrict__ Wk,
    const float* __restrict__ Wv, unsigned short* __restrict__ imgbf,
    unsigned short* __restrict__ wkvbf)
{
    const size_t base = ((size_t)blockIdx.x * 256 + threadIdx.x) * 4;
    float4 v;
    unsigned short* dst;
    if (base < 1048576) {
        v = *(const float4*)(img + base);
        dst = imgbf + base;
    } else {
        size_t o = base - 1048576;
        v = *(const float4*)((o < 131072) ? (Wk + o) : (Wv + (o - 131072)));
        dst = wkvbf + o;
    }
    *(uint2*)dst = make_uint2(packbf(v.x, v.y), packbf(v.z, v.w));
}

// -------------------------------------------------------------------------
// Kernel 1: MFMA 1x1 conv on preconverted bf16.
// buf[px][1024] = img^T[px][256k] @ (Wk|Wv)^T
// -------------------------------------------------------------------------
__global__ __launch_bounds__(256) void conv_bf16_kernel(
    const unsigned short* __restrict__ imgbf, const unsigned short* __restrict__ wkvbf,
    bf16* __restrict__ buf)
{
    __shared__ __attribute__((aligned(16))) unsigned short Bt[64][264]; // [px][k], +8 pad
    const int tid = threadIdx.x;
    const int p0 = blockIdx.x * 64;
    const int o0 = blockIdx.y * 64;

#pragma unroll
    for (int i = 0; i < 4; i++) {
        int chunk = i * 256 + tid;
        int kp  = chunk >> 3;              // k-pair index
        int pxg = (chunk & 7) * 8;         // 8-pixel group
        uint4 r0 = *(const uint4*)(imgbf + (size_t)(2 * kp) * 4096 + p0 + pxg);
        uint4 r1 = *(const uint4*)(imgbf + (size_t)(2 * kp + 1) * 4096 + p0 + pxg);
        unsigned lo[8], hi[8];
        lo[0] = r0.x & 0xffffu; lo[1] = r0.x >> 16; lo[2] = r0.y & 0xffffu; lo[3] = r0.y >> 16;
        lo[4] = r0.z & 0xffffu; lo[5] = r0.z >> 16; lo[6] = r0.w & 0xffffu; lo[7] = r0.w >> 16;
        hi[0] = r1.x & 0xffffu; hi[1] = r1.x >> 16; hi[2] = r1.y & 0xffffu; hi[3] = r1.y >> 16;
        hi[4] = r1.z & 0xffffu; hi[5] = r1.z >> 16; hi[6] = r1.w & 0xffffu; hi[7] = r1.w >> 16;
#pragma unroll
        for (int j = 0; j < 8; j++)
            *(unsigned*)&Bt[pxg + j][2 * kp] = lo[j] | (hi[j] << 16);
    }
    __syncthreads();

    const int w = tid >> 6, l = tid & 63;
    const int m = l & 15, quad = l >> 4;
    const int mrow = w * 16 + m;
    const unsigned short* Wsel = wkvbf + ((o0 < 512) ? 0 : 131072);
    const int obase = (o0 < 512) ? o0 : (o0 - 512);

    float4v acc[4] = {{0,0,0,0},{0,0,0,0},{0,0,0,0},{0,0,0,0}};
#pragma unroll
    for (int kk = 0; kk < 8; kk++) {
        const int kofs = kk * 32 + quad * 8;
        short8 af = *(const short8*)&Bt[mrow][kofs];
#pragma unroll
        for (int nt = 0; nt < 4; nt++) {
            const int row = obase + nt * 16 + m;
            short8 b8 = *(const short8*)(Wsel + (size_t)row * 256 + kofs);
            acc[nt] = __builtin_amdgcn_mfma_f32_16x16x32_bf16(af, b8, acc[nt], 0, 0, 0);
        }
    }
#pragma unroll
    for (int nt = 0; nt < 4; nt++) {
#pragma unroll
        for (int r = 0; r < 4; r++) {
            size_t px = p0 + w * 16 + quad * 4 + r;
            buf[px * 1024 + o0 + nt * 16 + m] = __float2bfloat16(acc[nt][r]);
        }
    }
}

// -------------------------------------------------------------------------
// Kernel 1b (fallback, ws too small): conv directly from fp32.
// -------------------------------------------------------------------------
__global__ __launch_bounds__(256) void conv_mfma_kernel(
    const float* __restrict__ img, const float* __restrict__ Wk,
    const float* __restrict__ Wv, bf16* __restrict__ buf)
{
    __shared__ __attribute__((aligned(16))) unsigned short Bt[64][264];
    const int tid = threadIdx.x;
    const int p0 = blockIdx.x * 64;
    const int o0 = blockIdx.y * 64;

#pragma unroll
    for (int i = 0; i < 4; i++) {
        int chunk = i * 256 + tid;
        int kp  = chunk >> 3;
        int pxg = (chunk & 7) * 8;
        const float* r0 = img + (size_t)(2 * kp) * 4096 + p0 + pxg;
        const float* r1 = img + (size_t)(2 * kp + 1) * 4096 + p0 + pxg;
        float4 a0 = *(const float4*)r0, a1 = *(const float4*)(r0 + 4);
        float4 b0 = *(const float4*)r1, b1 = *(const float4*)(r1 + 4);
        unsigned lo[8], hi[8];
        lo[0] = f2bfu(a0.x); lo[1] = f2bfu(a0.y); lo[2] = f2bfu(a0.z); lo[3] = f2bfu(a0.w);
        lo[4] = f2bfu(a1.x); lo[5] = f2bfu(a1.y); lo[6] = f2bfu(a1.z); lo[7] = f2bfu(a1.w);
        hi[0] = f2bfu(b0.x); hi[1] = f2bfu(b0.y); hi[2] = f2bfu(b0.z); hi[3] = f2bfu(b0.w);
        hi[4] = f2bfu(b1.x); hi[5] = f2bfu(b1.y); hi[6] = f2bfu(b1.z); hi[7] = f2bfu(b1.w);
#pragma unroll
        for (int j = 0; j < 8; j++)
            *(unsigned*)&Bt[pxg + j][2 * kp] = lo[j] | (hi[j] << 16);
    }
    __syncthreads();

    const int w = tid >> 6, l = tid & 63;
    const int m = l & 15, quad = l >> 4;
    const int mrow = w * 16 + m;
    const float* Wsel = (o0 < 512) ? Wk : Wv;
    const int obase = (o0 < 512) ? o0 : (o0 - 512);

    float4v acc[4] = {{0,0,0,0},{0,0,0,0},{0,0,0,0},{0,0,0,0}};
#pragma unroll
    for (int kk = 0; kk < 8; kk++) {
        const int kofs = kk * 32 + quad * 8;
        short8 af = *(const short8*)&Bt[mrow][kofs];
#pragma unroll
        for (int nt = 0; nt < 4; nt++) {
            const int row = obase + nt * 16 + m;
            const float* wp = Wsel + (size_t)row * 256 + kofs;
            float4 w0 = *(const float4*)wp, w1 = *(const float4*)(wp + 4);
            short8 b8;
            b8[0] = (short)f2bfu(w0.x); b8[1] = (short)f2bfu(w0.y);
            b8[2] = (short)f2bfu(w0.z); b8[3] = (short)f2bfu(w0.w);
            b8[4] = (short)f2bfu(w1.x); b8[5] = (short)f2bfu(w1.y);
            b8[6] = (short)f2bfu(w1.z); b8[7] = (short)f2bfu(w1.w);
            acc[nt] = __builtin_amdgcn_mfma_f32_16x16x32_bf16(af, b8, acc[nt], 0, 0, 0);
        }
    }
#pragma unroll
    for (int nt = 0; nt < 4; nt++) {
#pragma unroll
        for (int r = 0; r < 4; r++) {
            size_t px = p0 + w * 16 + quad * 4 + r;
            buf[px * 1024 + o0 + nt * 16 + m] = __float2bfloat16(acc[nt][r]);
        }
    }
}

// -------------------------------------------------------------------------
// Kernel 2: qfull[24576,512](bf16) = features[24576,32](fp32) @ Wq[32,512](fp32)
// -------------------------------------------------------------------------
__global__ __launch_bounds__(256) void qgemm_kernel(
    const float* __restrict__ features, const float* __restrict__ Wq,
    bf16* __restrict__ qfull)
{
    __shared__ __attribute__((aligned(16))) unsigned short WqT[256][40]; // [n][k]
    const int tid = threadIdx.x;
    const int R0 = blockIdx.x * 64;
    const int n0 = blockIdx.y * 256;
#pragma unroll
    for (int k = 0; k < 32; k++)
        WqT[tid][k] = f2bfu(Wq[(size_t)k * 512 + n0 + tid]);
    __syncthreads();

    const int w = tid >> 6, l = tid & 63, m = l & 15, quad = l >> 4;
    const int row = R0 + w * 16 + m;
    const float* fp = features + (size_t)row * 32 + quad * 8;
    float4 f0 = *(const float4*)fp, f1 = *(const float4*)(fp + 4);
    short8 af;
    af[0] = (short)f2bfu(f0.x); af[1] = (short)f2bfu(f0.y);
    af[2] = (short)f2bfu(f0.z); af[3] = (short)f2bfu(f0.w);
    af[4] = (short)f2bfu(f1.x); af[5] = (short)f2bfu(f1.y);
    af[6] = (short)f2bfu(f1.z); af[7] = (short)f2bfu(f1.w);
    float4v acc[16];
#pragma unroll
    for (int t = 0; t < 16; t++) acc[t] = (float4v){0.f, 0.f, 0.f, 0.f};
#pragma unroll
    for (int t = 0; t < 16; t++) {
        short8 b8 = *(const short8*)&WqT[t * 16 + m][quad * 8];
        acc[t] = __builtin_amdgcn_mfma_f32_16x16x32_bf16(af, b8, acc[t], 0, 0, 0);
    }
    const int rb = R0 + w * 16 + quad * 4;
#pragma unroll
    for (int t = 0; t < 16; t++)
#pragma unroll
        for (int r = 0; r < 4; r++)
            qfull[(size_t)(rb + r) * 512 + n0 + t * 16 + m] = __float2bfloat16(acc[t][r]);
}

// -------------------------------------------------------------------------
// Kernel 3: per-gaussian sampling + attention core. 1 block = 1 gaussian.
// -------------------------------------------------------------------------
__global__ __launch_bounds__(256, 7) void attn_core_kernel(
    const float* __restrict__ means, const float* __restrict__ scales,
    const float* __restrict__ rot,   const float* __restrict__ transforms,
    const float* __restrict__ projection, const float* __restrict__ W_off,
    const float* __restrict__ b_off, const bf16* __restrict__ buf,
    bf16* __restrict__ qfull)
{
    __shared__ __attribute__((aligned(16))) float qf[1536];           // q fp32 [t][512]
    __shared__ __attribute__((aligned(16))) unsigned short vsh[6144]; // W_off stage | v bf16
    __shared__ __attribute__((aligned(16))) float qm_u[512];          // qm | corner+att
    __shared__ float lrn[144];
    __shared__ float mw[3], sc3[3], Rt[9], pr[12];

    short4* corner = (short4*)qm_u;       // 96 x 8 B (live stage4+)
    float*  att    = qm_u + 192;          // 288 floats (live stage5+)
    float*  wofl   = (float*)vsh;         // 1206 floats (live stages 0-3)
    float*  bofl   = wofl + 1206;         // 18 floats

    const int g = blockIdx.x, tid = threadIdx.x;

    // ---- stage 0: geometry + weight staging + q staging ----
    for (int i = tid; i < 1206; i += 256) wofl[i] = W_off[i];
    if (tid < 18) bofl[tid] = b_off[tid];
    if (tid >= 32 && tid < 35) {
        sc3[tid - 32] = scales[(size_t)g * 3 + (tid - 32)];
    } else if (tid >= 36 && tid < 48) {
        pr[tid - 36] = projection[tid - 36];
    } else if (tid == 48) {
        float w = rot[(size_t)g * 4],     x = rot[(size_t)g * 4 + 1];
        float y = rot[(size_t)g * 4 + 2], z = rot[(size_t)g * 4 + 3];
        float n = rsqrtf(w * w + x * x + y * y + z * z);
        w *= n; x *= n; y *= n; z *= n;
        float R00 = 1 - 2 * (y * y + z * z), R01 = 2 * (x * y - w * z), R02 = 2 * (x * z + w * y);
        float R10 = 2 * (x * y + w * z), R11 = 1 - 2 * (x * x + z * z), R12 = 2 * (y * z - w * x);
        float R20 = 2 * (x * z - w * y), R21 = 2 * (y * z + w * x), R22 = 1 - 2 * (x * x + y * y);
        Rt[0] = R00; Rt[1] = R10; Rt[2] = R20;
        Rt[3] = R01; Rt[4] = R11; Rt[5] = R21;
        Rt[6] = R02; Rt[7] = R12; Rt[8] = R22;
    } else if (tid >= 52 && tid < 55) {
        int i = tid - 52;
        float m0 = means[(size_t)g * 3];
        float m1 = means[(size_t)g * 3 + 1];
        float m2 = means[(size_t)g * 3 + 2];
        const float* T = transforms + (size_t)g * 16 + i * 4;
        mw[i] = T[0] * m0 + T[1] * m1 + T[2] * m2 + T[3];
    }
    {
        const unsigned* qsrc = (const unsigned*)((const unsigned short*)qfull + (size_t)g * 1536);
#pragma unroll
        for (int i = 0; i < 3; i++) {
            int e = tid + i * 256;
            unsigned u = qsrc[e];
            qf[e * 2]     = __uint_as_float(u << 16);
            qf[e * 2 + 1] = __uint_as_float(u & 0xffff0000u);
        }
    }
    __syncthreads();

    // ---- stage 2: q_mean ----
    qm_u[tid]       = (qf[tid]       + qf[tid + 512] + qf[tid + 1024]) * (1.f / 3.f);
    qm_u[tid + 256] = (qf[tid + 256] + qf[tid + 768] + qf[tid + 1280]) * (1.f / 3.f);
    __syncthreads();

    // ---- stage 3: OffsetNet (weights from LDS) ----
    if (tid < 144) {
        int h = tid / 18, l = tid % 18;
        float s = bofl[l];
#pragma unroll
        for (int i = 0; i < 3; i++) s += mw[i] * wofl[i * 18 + l];
        for (int d = 0; d < 64; d++) s += qm_u[h * 64 + d] * wofl[(3 + d) * 18 + l];
        s = fminf(fmaxf(s, -9.21f), 9.21f);
        lrn[tid] = 1.f / (1.f + expf(-s)) - 0.5f;
    }
    __syncthreads();

    // ---- stage 4: sample coords -> corner short4 {x0, y0, wx1_u16, wy1_u16} ----
    if (tid < 96) {
        int h = tid / 12, k = tid % 12;
        float s0, s1, s2;
        if (k < 6) {
            const float FSx[6] = {0.f, 1.f, 0.f, 0.f, -1.f, 0.f};
            const float FSy[6] = {0.f, 0.f, 1.f, 0.f, 0.f, -1.f};
            const float FSz[6] = {0.f, 0.f, 0.f, 1.f, 0.f, 0.f};
            s0 = FSx[k]; s1 = FSy[k]; s2 = FSz[k];
        } else {
            int b = h * 18 + (k - 6) * 3;
            s0 = lrn[b]; s1 = lrn[b + 1]; s2 = lrn[b + 2];
        }
        float o0 = s0 * sc3[0], o1 = s1 * sc3[1], o2 = s2 * sc3[2];
        float wx = Rt[0] * o0 + Rt[1] * o1 + Rt[2] * o2 + mw[0];
        float wy = Rt[3] * o0 + Rt[4] * o1 + Rt[5] * o2 + mw[1];
        float wz = Rt[6] * o0 + Rt[7] * o1 + Rt[8] * o2 + mw[2];
        float px = pr[0] * wx + pr[1] * wy + pr[2]  * wz + pr[3];
        float py = pr[4] * wx + pr[5] * wy + pr[6]  * wz + pr[7];
        float pz = pr[8] * wx + pr[9] * wy + pr[10] * wz + pr[11];
        pz = fmaxf(pz, 1e-5f);
        float gx = fminf(fmaxf(px / pz * (1.f / 64.f), 0.f), 0.9999f);
        float gy = fminf(fmaxf(py / pz * (1.f / 64.f), 0.f), 0.9999f);
        float x = gx * 64.f - 0.5f, y = gy * 64.f - 0.5f;
        float fx = floorf(x), fy = floorf(y);
        short4 cn;
        cn.x = (short)(int)fx;
        cn.y = (short)(int)fy;
        cn.z = (short)(unsigned short)fminf((x - fx) * 65536.f, 65535.f);
        cn.w = (short)(unsigned short)fminf((y - fy) * 65536.f, 65535.f);
        corner[tid] = cn;
    }
    __syncthreads();

    // ---- stage 5: sample k/v + fused q.k scores (vsh becomes v buffer) ----
    {
        const int slice = tid & 7, d0 = slice * 8, grp = tid >> 3;
#pragma unroll
        for (int it = 0; it < 3; it++) {
            const int p = it * 32 + grp;
            const int h = p / 12, k = p - h * 12;
            short4 cn = corner[p];
            int x0 = cn.x, y0 = cn.y, x1 = x0 + 1, y1 = y0 + 1;
            float wx1 = (float)(unsigned short)cn.z * (1.f / 65536.f);
            float wy1 = (float)(unsigned short)cn.w * (1.f / 65536.f);
            float wx0 = 1.f - wx1, wy0 = 1.f - wy1;
            bool vx0 = (unsigned)x0 < 64u, vx1 = (unsigned)x1 < 64u;
            bool vy0 = (unsigned)y0 < 64u, vy1 = (unsigned)y1 < 64u;
            int xc0 = min(max(x0, 0), 63), xc1 = min(max(x1, 0), 63);
            int yc0 = min(max(y0, 0), 63), yc1 = min(max(y1, 0), 63);
            int   off[4];
            float wt[4];
            off[0] = (yc0 * 64 + xc0) * 1024; wt[0] = (vx0 & vy0) ? wx0 * wy0 : 0.f;
            off[1] = (yc0 * 64 + xc1) * 1024; wt[1] = (vx1 & vy0) ? wx1 * wy0 : 0.f;
            off[2] = (yc1 * 64 + xc0) * 1024; wt[2] = (vx0 & vy1) ? wx0 * wy1 : 0.f;
            off[3] = (yc1 * 64 + xc1) * 1024; wt[3] = (vx1 & vy1) ? wx1 * wy1 : 0.f;
            const int a = h * 64 + d0;
            const bf16* bp = buf + a;
            float ka[8] = {0,0,0,0,0,0,0,0}, va[8] = {0,0,0,0,0,0,0,0}, t8[8];
#pragma unroll
            for (int c = 0; c < 4; c++) {
                const float w = wt[c];
                ld8bf(bp + off[c], t8);
#pragma unroll
                for (int j = 0; j < 8; j++) ka[j] += w * t8[j];
                ld8bf(bp + off[c] + 512, t8);
#pragma unroll
                for (int j = 0; j < 8; j++) va[j] += w * t8[j];
            }
            uint4 pv;
            pv.x = packbf(va[0], va[1]); pv.y = packbf(va[2], va[3]);
            pv.z = packbf(va[4], va[5]); pv.w = packbf(va[6], va[7]);
            *(uint4*)(vsh + p * 64 + d0) = pv;
            float sp[3];
#pragma unroll
            for (int t = 0; t < 3; t++) {
                const float* qp = qf + t * 512 + a;
                float s = 0.f;
#pragma unroll
                for (int j = 0; j < 8; j++) s += qp[j] * ka[j];
                sp[t] = s;
            }
#pragma unroll
            for (int msk = 1; msk < 8; msk <<= 1) {
#pragma unroll
                for (int t = 0; t < 3; t++) sp[t] += __shfl_xor(sp[t], msk);
            }
            if (slice == 0) {
#pragma unroll
                for (int t = 0; t < 3; t++) att[(h * 3 + t) * 12 + k] = sp[t] * 0.125f;
            }
        }
    }
    __syncthreads();

    // ---- stage 7: softmax over K=12 ----
    if (tid < 24) {
        float* row = att + tid * 12;
        float m = row[0];
#pragma unroll
        for (int k = 1; k < 12; k++) m = fmaxf(m, row[k]);
        float e_[12]; float ssum = 0.f;
#pragma unroll
        for (int k = 0; k < 12; k++) { e_[k] = expf(row[k] - m); ssum += e_[k]; }
        float inv = 1.f / ssum;
#pragma unroll
        for (int k = 0; k < 12; k++) row[k] = e_[k] * inv;
    }
    __syncthreads();

    // ---- stage 8: out_attn = attn @ v_s, channel pairs, packed u32 stores ----
    {
        unsigned* oa32 = (unsigned*)((unsigned short*)qfull + (size_t)g * 1536);
#pragma unroll
        for (int i = 0; i < 3; i++) {
            int e = tid + i * 256;            // pair index 0..767
            int t = e >> 8, a2 = (e & 255) * 2;
            int h = a2 >> 6, dd = a2 & 63;
            const float* ar = att + (h * 3 + t) * 12;
            const unsigned short* vp = vsh + (h * 12) * 64 + dd;
            float s0 = 0.f, s1 = 0.f;
#pragma unroll
            for (int k = 0; k < 12; k++) {
                unsigned u = *(const unsigned*)(vp + k * 64);
                s0 += ar[k] * __uint_as_float(u << 16);
                s1 += ar[k] * __uint_as_float(u & 0xffff0000u);
            }
            oa32[e] = packbf(s0, s1);
        }
    }
}

// -------------------------------------------------------------------------
// Kernel 4: out[24576,32](fp32) = oa[24576,512](bf16) @ Wout[512,32](fp32)
//           + b_out + features
// -------------------------------------------------------------------------
__global__ __launch_bounds__(256) void outgemm_kernel(
    const bf16* __restrict__ oa, const float* __restrict__ Wout,
    const float* __restrict__ b_out, const float* __restrict__ features,
    float* __restrict__ out)
{
    __shared__ __attribute__((aligned(16))) unsigned short WT[32][520]; // [n][k]
    const int tid = threadIdx.x;
    const int R0 = blockIdx.x * 64;
#pragma unroll
    for (int j = 0; j < 64; j++) {
        int lin = j * 256 + tid;         // lin = k*32 + n
        WT[lin & 31][lin >> 5] = f2bfu(Wout[lin]);
    }
    __syncthreads();

    const int w = tid >> 6, l = tid & 63, m = l & 15, quad = l >> 4;
    const int row = R0 + w * 16 + m;
    float4v acc[2] = {{0,0,0,0},{0,0,0,0}};
#pragma unroll
    for (int kk = 0; kk < 16; kk++) {
        short8 af = *(const short8*)((const unsigned short*)oa + (size_t)row * 512 + kk * 32 + quad * 8);
#pragma unroll
        for (int t = 0; t < 2; t++) {
            short8 b8 = *(const short8*)&WT[t * 16 + m][kk * 32 + quad * 8];
            acc[t] = __builtin_amdgcn_mfma_f32_16x16x32_bf16(af, b8, acc[t], 0, 0, 0);
        }
    }
    const int rb = R0 + w * 16 + quad * 4;
#pragma unroll
    for (int t = 0; t < 2; t++) {
        int col = t * 16 + m;
        float bb = b_out[col];
#pragma unroll
        for (int r = 0; r < 4; r++) {
            int rr = rb + r;
            out[(size_t)rr * 32 + col] = acc[t][r] + bb + features[(size_t)rr * 32 + col];
        }
    }
}

// -------------------------------------------------------------------------
// Fallback (ws too small): fused attention kernel, fp32 inputs.
// -------------------------------------------------------------------------
__global__ __launch_bounds__(256, 6) void attn_fused_kernel(
    const float* __restrict__ means, const float* __restrict__ scales,
    const float* __restrict__ rot,   const float* __restrict__ features,
    const float* __restrict__ transforms, const float* __restrict__ projection,
    const float* __restrict__ Wq,    const float* __restrict__ W_off,
    const float* __restrict__ b_off, const float* __restrict__ Wout,
    const float* __restrict__ b_out, const bf16* __restrict__ buf,
    float* __restrict__ out)
{
    __shared__ float feat[96];
    __shared__ __attribute__((aligned(16))) float qf[1536];
    __shared__ float qm[512];
    __shared__ float mw[3], sc3[3], Rt[9], pr[12];
    __shared__ float lrn[144];
    __shared__ int   coff[96][4];
    __shared__ float cwt[96][4];
    __shared__ __attribute__((aligned(16))) char pool[12288];
    __shared__ float att[288];

    unsigned short* vsh = (unsigned short*)pool;
    const int g = blockIdx.x, tid = threadIdx.x;

    if (tid < 96) {
        feat[tid] = features[(size_t)g * 96 + tid];
    } else if (tid < 99) {
        sc3[tid - 96] = scales[(size_t)g * 3 + (tid - 96)];
    } else if (tid >= 100 && tid < 112) {
        pr[tid - 100] = projection[tid - 100];
    } else if (tid == 112) {
        float w = rot[(size_t)g * 4],     x = rot[(size_t)g * 4 + 1];
        float y = rot[(size_t)g * 4 + 2], z = rot[(size_t)g * 4 + 3];
        float n = rsqrtf(w * w + x * x + y * y + z * z);
        w *= n; x *= n; y *= n; z *= n;
        float R00 = 1 - 2 * (y * y + z * z), R01 = 2 * (x * y - w * z), R02 = 2 * (x * z + w * y);
        float R10 = 2 * (x * y + w * z), R11 = 1 - 2 * (x * x + z * z), R12 = 2 * (y * z - w * x);
        float R20 = 2 * (x * z - w * y), R21 = 2 * (y * z + w * x), R22 = 1 - 2 * (x * x + y * y);
        Rt[0] = R00; Rt[1] = R10; Rt[2] = R20;
        Rt[3] = R01; Rt[4] = R11; Rt[5] = R21;
        Rt[6] = R02; Rt[7] = R12; Rt[8] = R22;
    } else if (tid >= 116 && tid < 119) {
        int i = tid - 116;
        float m0 = means[(size_t)g * 3];
        float m1 = means[(size_t)g * 3 + 1];
        float m2 = means[(size_t)g * 3 + 2];
        const float* T = transforms + (size_t)g * 16 + i * 4;
        mw[i] = T[0] * m0 + T[1] * m1 + T[2] * m2 + T[3];
    }
    __syncthreads();

    {
        const int a0 = tid * 2;
        float s00 = 0.f, s01 = 0.f, s10 = 0.f, s11 = 0.f, s20 = 0.f, s21 = 0.f;
#pragma unroll
        for (int f = 0; f < 32; f++) {
            float2 w2 = *(const float2*)(Wq + (size_t)f * 512 + a0);
            float f0 = feat[f], f1 = feat[32 + f], f2 = feat[64 + f];
            s00 += f0 * w2.x; s01 += f0 * w2.y;
            s10 += f1 * w2.x; s11 += f1 * w2.y;
            s20 += f2 * w2.x; s21 += f2 * w2.y;
        }
        *(float2*)(qf + a0)        = make_float2(s00, s01);
        *(float2*)(qf + 512 + a0)  = make_float2(s10, s11);
        *(float2*)(qf + 1024 + a0) = make_float2(s20, s21);
    }
    __syncthreads();

    qm[tid]       = (qf[tid]       + qf[tid + 512] + qf[tid + 1024]) * (1.f / 3.f);
    qm[tid + 256] = (qf[tid + 256] + qf[tid + 768] + qf[tid + 1280]) * (1.f / 3.f);
    __syncthreads();

    if (tid < 144) {
        int h = tid / 18, l = tid % 18;
        float s = b_off[l];
#pragma unroll
        for (int i = 0; i < 3; i++) s += mw[i] * W_off[i * 18 + l];
        for (int d = 0; d < 64; d++) s += qm[h * 64 + d] * W_off[(size_t)(3 + d) * 18 + l];
        s = fminf(fmaxf(s, -9.21f), 9.21f);
        lrn[tid] = 1.f / (1.f + expf(-s)) - 0.5f;
    }
    __syncthreads();

    if (tid < 96) {
        int h = tid / 12, k = tid % 12;
        float s0, s1, s2;
        if (k < 6) {
            const float FSx[6] = {0.f, 1.f, 0.f, 0.f, -1.f, 0.f};
            const float FSy[6] = {0.f, 0.f, 1.f, 0.f, 0.f, -1.f};
            const float FSz[6] = {0.f, 0.f, 0.f, 1.f, 0.f, 0.f};
            s0 = FSx[k]; s1 = FSy[k]; s2 = FSz[k];
        } else {
            int b = h * 18 + (k - 6) * 3;
            s0 = lrn[b]; s1 = lrn[b + 1]; s2 = lrn[b + 2];
        }
        float o0 = s0 * sc3[0], o1 = s1 * sc3[1], o2 = s2 * sc3[2];
        float wx = Rt[0] * o0 + Rt[1] * o1 + Rt[2] * o2 + mw[0];
        float wy = Rt[3] * o0 + Rt[4] * o1 + Rt[5] * o2 + mw[1];
        float wz = Rt[6] * o0 + Rt[7] * o1 + Rt[8] * o2 + mw[2];
        float px = pr[0] * wx + pr[1] * wy + pr[2]  * wz + pr[3];
        float py = pr[4] * wx + pr[5] * wy + pr[6]  * wz + pr[7];
        float pz = pr[8] * wx + pr[9] * wy + pr[10] * wz + pr[11];
        pz = fmaxf(pz, 1e-5f);
        float gx = fminf(fmaxf(px / pz * (1.f / 64.f), 0.f), 0.9999f);
        float gy = fminf(fmaxf(py / pz * (1.f / 64.f), 0.f), 0.9999f);
        float x = gx * 64.f - 0.5f, y = gy * 64.f - 0.5f;
        float fx = floorf(x), fy = floorf(y);
        int x0 = (int)fx, y0 = (int)fy;
        float wx1 = x - fx, wx0c = 1.f - wx1;
        float wy1 = y - fy, wy0c = 1.f - wy1;
        int xs[2] = {x0, x0 + 1}, ys[2] = {y0, y0 + 1};
        float wxs[2] = {wx0c, wx1}, wys[2] = {wy0c, wy1};
#pragma unroll
        for (int c = 0; c < 4; c++) {
            int dx = c & 1, dy = c >> 1;
            int xi = xs[dx], yi = ys[dy];
            bool v = (xi >= 0) & (xi < 64) & (yi >= 0) & (yi < 64);
            int xc = min(max(xi, 0), 63), yc = min(max(yi, 0), 63);
            coff[tid][c] = (yc * 64 + xc) * 1024;
            cwt[tid][c]  = v ? wxs[dx] * wys[dy] : 0.f;
        }
    }
    __syncthreads();

    {
        const int slice = tid & 7, d0 = slice * 8, grp = tid >> 3;
#pragma unroll
        for (int it = 0; it < 3; it++) {
            const int p = it * 32 + grp;
            const int h = p / 12, k = p - h * 12;
            const int a = h * 64 + d0;
            const bf16* bp = buf + a;
            float ka[8] = {0,0,0,0,0,0,0,0}, va[8] = {0,0,0,0,0,0,0,0}, t8[8];
#pragma unroll
            for (int c = 0; c < 4; c++) {
                const int   o = coff[p][c];
                const float w = cwt[p][c];
                ld8bf(bp + o, t8);
#pragma unroll
                for (int j = 0; j < 8; j++) ka[j] += w * t8[j];
                ld8bf(bp + o + 512, t8);
#pragma unroll
                for (int j = 0; j < 8; j++) va[j] += w * t8[j];
            }
            uint4 pv;
            pv.x = packbf(va[0], va[1]); pv.y = packbf(va[2], va[3]);
            pv.z = packbf(va[4], va[5]); pv.w = packbf(va[6], va[7]);
            *(uint4*)(vsh + p * 64 + d0) = pv;
            float sp[3];
#pragma unroll
            for (int t = 0; t < 3; t++) {
                const float* qp = qf + t * 512 + a;
                float s = 0.f;
#pragma unroll
                for (int j = 0; j < 8; j++) s += qp[j] * ka[j];
                sp[t] = s;
            }
#pragma unroll
            for (int msk = 1; msk < 8; msk <<= 1) {
#pragma unroll
                for (int t = 0; t < 3; t++) sp[t] += __shfl_xor(sp[t], msk);
            }
            if (slice == 0) {
#pragma unroll
                for (int t = 0; t < 3; t++) att[(h * 3 + t) * 12 + k] = sp[t] * 0.125f;
            }
        }
    }
    __syncthreads();

    if (tid < 24) {
        float* row = att + tid * 12;
        float m = row[0];
#pragma unroll
        for (int k = 1; k < 12; k++) m = fmaxf(m, row[k]);
        float e_[12]; float ssum = 0.f;
#pragma unroll
        for (int k = 0; k < 12; k++) { e_[k] = expf(row[k] - m); ssum += e_[k]; }
        float inv = 1.f / ssum;
#pragma unroll
        for (int k = 0; k < 12; k++) row[k] = e_[k] * inv;
    }
    __syncthreads();

#pragma unroll
    for (int i = 0; i < 6; i++) {
        int e = tid + i * 256;
        int t = e >> 9, a = e & 511, h = a >> 6, dd = a & 63;
        const float* ar = att + (h * 3 + t) * 12;
        const unsigned short* vp = vsh + (h * 12) * 64 + dd;
        float s = 0.f;
#pragma unroll
        for (int k = 0; k < 12; k++)
            s += ar[k] * __uint_as_float((unsigned)vp[k * 64] << 16);
        qf[e] = s;
    }
    __syncthreads();

    {
        float* red = (float*)pool;
        const int c0 = (tid & 15) * 2, slice = tid >> 4;
        const int abase = slice * 32;
        float a00 = 0.f, a01 = 0.f, a10 = 0.f, a11 = 0.f, a20 = 0.f, a21 = 0.f;
#pragma unroll
        for (int i = 0; i < 32; i++) {
            int a = abase + i;
            float2 w2 = *(const float2*)(Wout + (size_t)a * 32 + c0);
            float o0 = qf[a], o1 = qf[512 + a], o2 = qf[1024 + a];
            a00 += o0 * w2.x; a01 += o0 * w2.y;
            a10 += o1 * w2.x; a11 += o1 * w2.y;
            a20 += o2 * w2.x; a21 += o2 * w2.y;
        }
        __syncthreads();
        red[(slice * 3 + 0) * 32 + c0] = a00; red[(slice * 3 + 0) * 32 + c0 + 1] = a01;
        red[(slice * 3 + 1) * 32 + c0] = a10; red[(slice * 3 + 1) * 32 + c0 + 1] = a11;
        red[(slice * 3 + 2) * 32 + c0] = a20; red[(slice * 3 + 2) * 32 + c0 + 1] = a21;
        __syncthreads();
        if (tid < 96) {
            int t = tid >> 5, c = tid & 31;
            float acc = b_out[c] + feat[tid];
#pragma unroll
            for (int s = 0; s < 16; s++) acc += red[(s * 3 + t) * 32 + c];
            out[(size_t)g * 96 + tid] = acc;
        }
    }
}

extern "C" void kernel_launch(void* const* d_in, const int* in_sizes, int n_in,
                              void* d_out, int out_size, void* d_ws, size_t ws_size,
                              hipStream_t stream) {
    const float* means      = (const float*)d_in[0];
    const float* scales     = (const float*)d_in[1];
    const float* rot        = (const float*)d_in[2];
    const float* features   = (const float*)d_in[3];
    const float* transforms = (const float*)d_in[4];
    const float* projection = (const float*)d_in[5];
    const float* img        = (const float*)d_in[6];
    const float* Wq         = (const float*)d_in[7];
    const float* Wk         = (const float*)d_in[8];
    const float* Wv         = (const float*)d_in[9];
    const float* W_off      = (const float*)d_in[10];
    const float* b_off      = (const float*)d_in[11];
    const float* Wout       = (const float*)d_in[12];
    const float* b_out      = (const float*)d_in[13];
    float* out = (float*)d_out;

    char* w = (char*)d_ws;
    bf16* buf = (bf16*)(w + 64);                       // 4096 x 1024 bf16 = 8 MiB
    const size_t BUF_BYTES = (size_t)4096 * 1024 * 2;
    const size_t Q_BYTES   = (size_t)24576 * 512 * 2;  // 24 MiB
    const size_t need = 64 + BUF_BYTES + Q_BYTES;

    dim3 gridc(64, 16);
    if (ws_size >= need) {
        bf16* qfull = (bf16*)(w + 64 + BUF_BYTES);
        // overlay in the front of qfull (dead until qgemm runs, strictly after conv)
        unsigned short* imgbf = (unsigned short*)qfull;        // 1048576 el = 2 MiB
        unsigned short* wkvbf = imgbf + 1048576;               // 262144 el = 0.5 MiB
        preconvert_kernel<<<1280, 256, 0, stream>>>(img, Wk, Wv, imgbf, wkvbf);
        conv_bf16_kernel<<<gridc, 256, 0, stream>>>(imgbf, wkvbf, buf);
        dim3 gridq(384, 2);
        qgemm_kernel<<<gridq, 256, 0, stream>>>(features, Wq, qfull);
        attn_core_kernel<<<8192, 256, 0, stream>>>(
            means, scales, rot, transforms, projection, W_off, b_off, buf, qfull);
        outgemm_kernel<<<384, 256, 0, stream>>>(qfull, Wout, b_out, features, out);
    } else {
        conv_mfma_kernel<<<gridc, 256, 0, stream>>>(img, Wk, Wv, buf);
        attn_fused_kernel<<<8192, 256, 0, stream>>>(
            means, scales, rot, features, transforms, projection,
            Wq, W_off, b_off, Wout, b_out, buf, out);
    }
}

// Round 8
// 174.504 us; speedup vs baseline: 4.4519x; 1.0533x over previous
//
#include <hip/hip_runtime.h>
#include <hip/hip_bf16.h>
#include <hip/hip_fp16.h>

typedef _Float16 half2v __attribute__((ext_vector_type(2)));
typedef _Float16 half8v __attribute__((ext_vector_type(8)));
typedef __attribute__((ext_vector_type(4))) float float4v;

// ---- helpers: inputs are fp32; intermediates are f16 (packed-math friendly) ----
__device__ __forceinline__ half2v u2h(unsigned u) { return __builtin_bit_cast(half2v, u); }
__device__ __forceinline__ unsigned h2u(half2v h) { return __builtin_bit_cast(unsigned, h); }
__device__ __forceinline__ unsigned short f2hu(float f) {
    _Float16 h = (_Float16)f; return __builtin_bit_cast(unsigned short, h);
}
__device__ __forceinline__ unsigned packh(float lo, float hi) {
    half2v h; h[0] = (_Float16)lo; h[1] = (_Float16)hi; return h2u(h);
}
// unpack 8 f16 (16B aligned) to 8 floats (fallback path)
__device__ __forceinline__ void ld8h(const unsigned short* p, float* f) {
    uint4 u = *(const uint4*)p;
    half2v h0 = u2h(u.x), h1 = u2h(u.y), h2 = u2h(u.z), h3 = u2h(u.w);
    f[0] = (float)h0[0]; f[1] = (float)h0[1]; f[2] = (float)h1[0]; f[3] = (float)h1[1];
    f[4] = (float)h2[0]; f[5] = (float)h2[1]; f[6] = (float)h3[0]; f[7] = (float)h3[1];
}

// -------------------------------------------------------------------------
// Kernel 0: preconvert img (1048576 el) + Wk|Wv (262144 el) fp32 -> f16.
// -------------------------------------------------------------------------
__global__ __launch_bounds__(256) void preconvert_kernel(
    const float* __restrict__ img, const float* __restrict__ Wk,
    const float* __restrict__ Wv, unsigned short* __restrict__ imgh,
    unsigned short* __restrict__ wkvh)
{
    const size_t base = ((size_t)blockIdx.x * 256 + threadIdx.x) * 4;
    float4 v;
    unsigned short* dst;
    if (base < 1048576) {
        v = *(const float4*)(img + base);
        dst = imgh + base;
    } else {
        size_t o = base - 1048576;
        v = *(const float4*)((o < 131072) ? (Wk + o) : (Wv + (o - 131072)));
        dst = wkvh + o;
    }
    *(uint2*)dst = make_uint2(packh(v.x, v.y), packh(v.z, v.w));
}

// -------------------------------------------------------------------------
// Kernel 1: MFMA 1x1 conv on preconverted f16.
// buf[px][1024] = img^T[px][256k] @ (Wk|Wv)^T
// -------------------------------------------------------------------------
__global__ __launch_bounds__(256) void conv_f16_kernel(
    const unsigned short* __restrict__ imgh, const unsigned short* __restrict__ wkvh,
    unsigned short* __restrict__ buf)
{
    __shared__ __attribute__((aligned(16))) unsigned short Bt[64][264]; // [px][k], +8 pad
    const int tid = threadIdx.x;
    const int p0 = blockIdx.x * 64;
    const int o0 = blockIdx.y * 64;

#pragma unroll
    for (int i = 0; i < 4; i++) {
        int chunk = i * 256 + tid;
        int kp  = chunk >> 3;
        int pxg = (chunk & 7) * 8;
        uint4 r0 = *(const uint4*)(imgh + (size_t)(2 * kp) * 4096 + p0 + pxg);
        uint4 r1 = *(const uint4*)(imgh + (size_t)(2 * kp + 1) * 4096 + p0 + pxg);
        unsigned lo[8], hi[8];
        lo[0] = r0.x & 0xffffu; lo[1] = r0.x >> 16; lo[2] = r0.y & 0xffffu; lo[3] = r0.y >> 16;
        lo[4] = r0.z & 0xffffu; lo[5] = r0.z >> 16; lo[6] = r0.w & 0xffffu; lo[7] = r0.w >> 16;
        hi[0] = r1.x & 0xffffu; hi[1] = r1.x >> 16; hi[2] = r1.y & 0xffffu; hi[3] = r1.y >> 16;
        hi[4] = r1.z & 0xffffu; hi[5] = r1.z >> 16; hi[6] = r1.w & 0xffffu; hi[7] = r1.w >> 16;
#pragma unroll
        for (int j = 0; j < 8; j++)
            *(unsigned*)&Bt[pxg + j][2 * kp] = lo[j] | (hi[j] << 16);
    }
    __syncthreads();

    const int w = tid >> 6, l = tid & 63;
    const int m = l & 15, quad = l >> 4;
    const int mrow = w * 16 + m;
    const unsigned short* Wsel = wkvh + ((o0 < 512) ? 0 : 131072);
    const int obase = (o0 < 512) ? o0 : (o0 - 512);

    float4v acc[4] = {{0,0,0,0},{0,0,0,0},{0,0,0,0},{0,0,0,0}};
#pragma unroll
    for (int kk = 0; kk < 8; kk++) {
        const int kofs = kk * 32 + quad * 8;
        half8v af = *(const half8v*)&Bt[mrow][kofs];
#pragma unroll
        for (int nt = 0; nt < 4; nt++) {
            const int row = obase + nt * 16 + m;
            half8v b8 = *(const half8v*)(Wsel + (size_t)row * 256 + kofs);
            acc[nt] = __builtin_amdgcn_mfma_f32_16x16x32_f16(af, b8, acc[nt], 0, 0, 0);
        }
    }
#pragma unroll
    for (int nt = 0; nt < 4; nt++) {
#pragma unroll
        for (int r = 0; r < 4; r++) {
            size_t px = p0 + w * 16 + quad * 4 + r;
            buf[px * 1024 + o0 + nt * 16 + m] = f2hu(acc[nt][r]);
        }
    }
}

// -------------------------------------------------------------------------
// Kernel 1b (fallback, ws too small): conv directly from fp32 -> f16 buf.
// -------------------------------------------------------------------------
__global__ __launch_bounds__(256) void conv_mfma_kernel(
    const float* __restrict__ img, const float* __restrict__ Wk,
    const float* __restrict__ Wv, unsigned short* __restrict__ buf)
{
    __shared__ __attribute__((aligned(16))) unsigned short Bt[64][264];
    const int tid = threadIdx.x;
    const int p0 = blockIdx.x * 64;
    const int o0 = blockIdx.y * 64;

#pragma unroll
    for (int i = 0; i < 4; i++) {
        int chunk = i * 256 + tid;
        int kp  = chunk >> 3;
        int pxg = (chunk & 7) * 8;
        const float* r0 = img + (size_t)(2 * kp) * 4096 + p0 + pxg;
        const float* r1 = img + (size_t)(2 * kp + 1) * 4096 + p0 + pxg;
        float4 a0 = *(const float4*)r0, a1 = *(const float4*)(r0 + 4);
        float4 b0 = *(const float4*)r1, b1 = *(const float4*)(r1 + 4);
        unsigned lo[8], hi[8];
        lo[0] = f2hu(a0.x); lo[1] = f2hu(a0.y); lo[2] = f2hu(a0.z); lo[3] = f2hu(a0.w);
        lo[4] = f2hu(a1.x); lo[5] = f2hu(a1.y); lo[6] = f2hu(a1.z); lo[7] = f2hu(a1.w);
        hi[0] = f2hu(b0.x); hi[1] = f2hu(b0.y); hi[2] = f2hu(b0.z); hi[3] = f2hu(b0.w);
        hi[4] = f2hu(b1.x); hi[5] = f2hu(b1.y); hi[6] = f2hu(b1.z); hi[7] = f2hu(b1.w);
#pragma unroll
        for (int j = 0; j < 8; j++)
            *(unsigned*)&Bt[pxg + j][2 * kp] = lo[j] | (hi[j] << 16);
    }
    __syncthreads();

    const int w = tid >> 6, l = tid & 63;
    const int m = l & 15, quad = l >> 4;
    const int mrow = w * 16 + m;
    const float* Wsel = (o0 < 512) ? Wk : Wv;
    const int obase = (o0 < 512) ? o0 : (o0 - 512);

    float4v acc[4] = {{0,0,0,0},{0,0,0,0},{0,0,0,0},{0,0,0,0}};
#pragma unroll
    for (int kk = 0; kk < 8; kk++) {
        const int kofs = kk * 32 + quad * 8;
        half8v af = *(const half8v*)&Bt[mrow][kofs];
#pragma unroll
        for (int nt = 0; nt < 4; nt++) {
            const int row = obase + nt * 16 + m;
            const float* wp = Wsel + (size_t)row * 256 + kofs;
            float4 w0 = *(const float4*)wp, w1 = *(const float4*)(wp + 4);
            half8v b8;
            b8[0] = (_Float16)w0.x; b8[1] = (_Float16)w0.y;
            b8[2] = (_Float16)w0.z; b8[3] = (_Float16)w0.w;
            b8[4] = (_Float16)w1.x; b8[5] = (_Float16)w1.y;
            b8[6] = (_Float16)w1.z; b8[7] = (_Float16)w1.w;
            acc[nt] = __builtin_amdgcn_mfma_f32_16x16x32_f16(af, b8, acc[nt], 0, 0, 0);
        }
    }
#pragma unroll
    for (int nt = 0; nt < 4; nt++) {
#pragma unroll
        for (int r = 0; r < 4; r++) {
            size_t px = p0 + w * 16 + quad * 4 + r;
            buf[px * 1024 + o0 + nt * 16 + m] = f2hu(acc[nt][r]);
        }
    }
}

// -------------------------------------------------------------------------
// Kernel 2: qfull[24576,512](f16) = features[24576,32](fp32) @ Wq[32,512](fp32)
// -------------------------------------------------------------------------
__global__ __launch_bounds__(256) void qgemm_kernel(
    const float* __restrict__ features, const float* __restrict__ Wq,
    unsigned short* __restrict__ qfull)
{
    __shared__ __attribute__((aligned(16))) unsigned short WqT[256][40]; // [n][k]
    const int tid = threadIdx.x;
    const int R0 = blockIdx.x * 64;
    const int n0 = blockIdx.y * 256;
#pragma unroll
    for (int k = 0; k < 32; k++)
        WqT[tid][k] = f2hu(Wq[(size_t)k * 512 + n0 + tid]);
    __syncthreads();

    const int w = tid >> 6, l = tid & 63, m = l & 15, quad = l >> 4;
    const int row = R0 + w * 16 + m;
    const float* fp = features + (size_t)row * 32 + quad * 8;
    float4 f0 = *(const float4*)fp, f1 = *(const float4*)(fp + 4);
    half8v af;
    af[0] = (_Float16)f0.x; af[1] = (_Float16)f0.y;
    af[2] = (_Float16)f0.z; af[3] = (_Float16)f0.w;
    af[4] = (_Float16)f1.x; af[5] = (_Float16)f1.y;
    af[6] = (_Float16)f1.z; af[7] = (_Float16)f1.w;
    float4v acc[16];
#pragma unroll
    for (int t = 0; t < 16; t++) acc[t] = (float4v){0.f, 0.f, 0.f, 0.f};
#pragma unroll
    for (int t = 0; t < 16; t++) {
        half8v b8 = *(const half8v*)&WqT[t * 16 + m][quad * 8];
        acc[t] = __builtin_amdgcn_mfma_f32_16x16x32_f16(af, b8, acc[t], 0, 0, 0);
    }
    const int rb = R0 + w * 16 + quad * 4;
#pragma unroll
    for (int t = 0; t < 16; t++)
#pragma unroll
        for (int r = 0; r < 4; r++)
            qfull[(size_t)(rb + r) * 512 + n0 + t * 16 + m] = f2hu(acc[t][r]);
}

// -------------------------------------------------------------------------
// Kernel 3: per-gaussian sampling + attention core. 1 block = 1 gaussian.
// f16 packed math: v_pk_fma_f16 for bilinear, v_dot2_f32_f16 for scores.
// -------------------------------------------------------------------------
__global__ __launch_bounds__(256, 8) void attn_core_kernel(
    const float* __restrict__ means, const float* __restrict__ scales,
    const float* __restrict__ rot,   const float* __restrict__ transforms,
    const float* __restrict__ projection, const float* __restrict__ W_off,
    const float* __restrict__ b_off, const unsigned short* __restrict__ buf,
    unsigned short* __restrict__ qfull)
{
    __shared__ __attribute__((aligned(16))) unsigned qf2[768];   // q f16-pairs [t][256]
    __shared__ __attribute__((aligned(16))) unsigned vsh2[3072]; // W_off stage | v pairs [p][32]
    __shared__ __attribute__((aligned(16))) float qm_u[512];     // qm | corner+att
    __shared__ float lrn[144];
    __shared__ float mw[3], sc3[3], Rt[9], pr[12];

    short4* corner = (short4*)qm_u;       // 96 x 8 B (live stage4+)
    float*  att    = qm_u + 192;          // 288 floats (live stage5+)
    float*  wofl   = (float*)vsh2;        // 1206 floats (live stages 0-3)
    float*  bofl   = wofl + 1206;         // 18 floats

    const int g = blockIdx.x, tid = threadIdx.x;

    // ---- stage 0: geometry + weight staging + q staging (packed) ----
    for (int i = tid; i < 1206; i += 256) wofl[i] = W_off[i];
    if (tid < 18) bofl[tid] = b_off[tid];
    if (tid >= 32 && tid < 35) {
        sc3[tid - 32] = scales[(size_t)g * 3 + (tid - 32)];
    } else if (tid >= 36 && tid < 48) {
        pr[tid - 36] = projection[tid - 36];
    } else if (tid == 48) {
        float w = rot[(size_t)g * 4],     x = rot[(size_t)g * 4 + 1];
        float y = rot[(size_t)g * 4 + 2], z = rot[(size_t)g * 4 + 3];
        float n = rsqrtf(w * w + x * x + y * y + z * z);
        w *= n; x *= n; y *= n; z *= n;
        float R00 = 1 - 2 * (y * y + z * z), R01 = 2 * (x * y - w * z), R02 = 2 * (x * z + w * y);
        float R10 = 2 * (x * y + w * z), R11 = 1 - 2 * (x * x + z * z), R12 = 2 * (y * z - w * x);
        float R20 = 2 * (x * z - w * y), R21 = 2 * (y * z + w * x), R22 = 1 - 2 * (x * x + y * y);
        Rt[0] = R00; Rt[1] = R10; Rt[2] = R20;
        Rt[3] = R01; Rt[4] = R11; Rt[5] = R21;
        Rt[6] = R02; Rt[7] = R12; Rt[8] = R22;
    } else if (tid >= 52 && tid < 55) {
        int i = tid - 52;
        float m0 = means[(size_t)g * 3];
        float m1 = means[(size_t)g * 3 + 1];
        float m2 = means[(size_t)g * 3 + 2];
        const float* T = transforms + (size_t)g * 16 + i * 4;
        mw[i] = T[0] * m0 + T[1] * m1 + T[2] * m2 + T[3];
    }
    {
        const unsigned* qsrc = (const unsigned*)(qfull + (size_t)g * 1536);
#pragma unroll
        for (int i = 0; i < 3; i++) {
            int e = tid + i * 256;
            qf2[e] = qsrc[e];
        }
    }
    __syncthreads();

    // ---- stage 2: q_mean (one pair per thread) ----
    {
        half2v a = u2h(qf2[tid]), b = u2h(qf2[256 + tid]), c = u2h(qf2[512 + tid]);
        qm_u[tid * 2]     = ((float)a[0] + (float)b[0] + (float)c[0]) * (1.f / 3.f);
        qm_u[tid * 2 + 1] = ((float)a[1] + (float)b[1] + (float)c[1]) * (1.f / 3.f);
    }
    __syncthreads();

    // ---- stage 3: OffsetNet (weights from LDS) ----
    if (tid < 144) {
        int h = tid / 18, l = tid % 18;
        float s = bofl[l];
#pragma unroll
        for (int i = 0; i < 3; i++) s += mw[i] * wofl[i * 18 + l];
        for (int d = 0; d < 64; d++) s += qm_u[h * 64 + d] * wofl[(3 + d) * 18 + l];
        s = fminf(fmaxf(s, -9.21f), 9.21f);
        lrn[tid] = 1.f / (1.f + expf(-s)) - 0.5f;
    }
    __syncthreads();

    // ---- stage 4: sample coords -> corner short4 {x0, y0, wx1_u16, wy1_u16} ----
    if (tid < 96) {
        int h = tid / 12, k = tid % 12;
        float s0, s1, s2;
        if (k < 6) {
            const float FSx[6] = {0.f, 1.f, 0.f, 0.f, -1.f, 0.f};
            const float FSy[6] = {0.f, 0.f, 1.f, 0.f, 0.f, -1.f};
            const float FSz[6] = {0.f, 0.f, 0.f, 1.f, 0.f, 0.f};
            s0 = FSx[k]; s1 = FSy[k]; s2 = FSz[k];
        } else {
            int b = h * 18 + (k - 6) * 3;
            s0 = lrn[b]; s1 = lrn[b + 1]; s2 = lrn[b + 2];
        }
        float o0 = s0 * sc3[0], o1 = s1 * sc3[1], o2 = s2 * sc3[2];
        float wx = Rt[0] * o0 + Rt[1] * o1 + Rt[2] * o2 + mw[0];
        float wy = Rt[3] * o0 + Rt[4] * o1 + Rt[5] * o2 + mw[1];
        float wz = Rt[6] * o0 + Rt[7] * o1 + Rt[8] * o2 + mw[2];
        float px = pr[0] * wx + pr[1] * wy + pr[2]  * wz + pr[3];
        float py = pr[4] * wx + pr[5] * wy + pr[6]  * wz + pr[7];
        float pz = pr[8] * wx + pr[9] * wy + pr[10] * wz + pr[11];
        pz = fmaxf(pz, 1e-5f);
        float gx = fminf(fmaxf(px / pz * (1.f / 64.f), 0.f), 0.9999f);
        float gy = fminf(fmaxf(py / pz * (1.f / 64.f), 0.f), 0.9999f);
        float x = gx * 64.f - 0.5f, y = gy * 64.f - 0.5f;
        float fx = floorf(x), fy = floorf(y);
        short4 cn;
        cn.x = (short)(int)fx;
        cn.y = (short)(int)fy;
        cn.z = (short)(unsigned short)fminf((x - fx) * 65536.f, 65535.f);
        cn.w = (short)(unsigned short)fminf((y - fy) * 65536.f, 65535.f);
        corner[tid] = cn;
    }
    __syncthreads();

    // ---- stage 5: packed-f16 bilinear sample k/v + fdot2 q.k scores ----
    {
        const int slice = tid & 7, grp = tid >> 3;
#pragma unroll
        for (int it = 0; it < 3; it++) {
            const int p = it * 32 + grp;
            const int h = p / 12, k = p - h * 12;
            short4 cn = corner[p];
            int x0 = cn.x, y0 = cn.y, x1 = x0 + 1, y1 = y0 + 1;
            float wx1 = (float)(unsigned short)cn.z * (1.f / 65536.f);
            float wy1 = (float)(unsigned short)cn.w * (1.f / 65536.f);
            float wx0 = 1.f - wx1, wy0 = 1.f - wy1;
            bool vx0 = (unsigned)x0 < 64u, vx1 = (unsigned)x1 < 64u;
            bool vy0 = (unsigned)y0 < 64u, vy1 = (unsigned)y1 < 64u;
            int xc0 = min(max(x0, 0), 63), xc1 = min(max(x1, 0), 63);
            int yc0 = min(max(y0, 0), 63), yc1 = min(max(y1, 0), 63);
            int   off[4];
            float wt[4];
            off[0] = (yc0 * 64 + xc0) * 1024; wt[0] = (vx0 & vy0) ? wx0 * wy0 : 0.f;
            off[1] = (yc0 * 64 + xc1) * 1024; wt[1] = (vx1 & vy0) ? wx1 * wy0 : 0.f;
            off[2] = (yc1 * 64 + xc0) * 1024; wt[2] = (vx0 & vy1) ? wx0 * wy1 : 0.f;
            off[3] = (yc1 * 64 + xc1) * 1024; wt[3] = (vx1 & vy1) ? wx1 * wy1 : 0.f;
            const int a = h * 64 + slice * 8;          // channel base
            const unsigned short* bp = buf + a;
            half2v ka2[4] = {{0,0},{0,0},{0,0},{0,0}};
            half2v va2[4] = {{0,0},{0,0},{0,0},{0,0}};
#pragma unroll
            for (int c = 0; c < 4; c++) {
                _Float16 wh = (_Float16)wt[c];
                half2v w2; w2[0] = wh; w2[1] = wh;
                uint4 uk = *(const uint4*)(bp + off[c]);
                uint4 uv = *(const uint4*)(bp + off[c] + 512);
                ka2[0] += w2 * u2h(uk.x); ka2[1] += w2 * u2h(uk.y);
                ka2[2] += w2 * u2h(uk.z); ka2[3] += w2 * u2h(uk.w);
                va2[0] += w2 * u2h(uv.x); va2[1] += w2 * u2h(uv.y);
                va2[2] += w2 * u2h(uv.z); va2[3] += w2 * u2h(uv.w);
            }
            const int pa = h * 32 + slice * 4;         // pair base
            *(uint4*)&vsh2[p * 32 + slice * 4] =
                make_uint4(h2u(va2[0]), h2u(va2[1]), h2u(va2[2]), h2u(va2[3]));
            float sp[3];
#pragma unroll
            for (int t = 0; t < 3; t++) {
                uint4 q4 = *(const uint4*)&qf2[t * 256 + pa];
                float s = __builtin_amdgcn_fdot2(u2h(q4.x), ka2[0], 0.f, false);
                s = __builtin_amdgcn_fdot2(u2h(q4.y), ka2[1], s, false);
                s = __builtin_amdgcn_fdot2(u2h(q4.z), ka2[2], s, false);
                s = __builtin_amdgcn_fdot2(u2h(q4.w), ka2[3], s, false);
                sp[t] = s;
            }
#pragma unroll
            for (int msk = 1; msk < 8; msk <<= 1) {
#pragma unroll
                for (int t = 0; t < 3; t++) sp[t] += __shfl_xor(sp[t], msk);
            }
            if (slice == 0) {
#pragma unroll
                for (int t = 0; t < 3; t++) att[(h * 3 + t) * 12 + k] = sp[t] * 0.125f;
            }
        }
    }
    __syncthreads();

    // ---- stage 7: softmax over K=12 ----
    if (tid < 24) {
        float* row = att + tid * 12;
        float m = row[0];
#pragma unroll
        for (int k = 1; k < 12; k++) m = fmaxf(m, row[k]);
        float e_[12]; float ssum = 0.f;
#pragma unroll
        for (int k = 0; k < 12; k++) { e_[k] = expf(row[k] - m); ssum += e_[k]; }
        float inv = 1.f / ssum;
#pragma unroll
        for (int k = 0; k < 12; k++) row[k] = e_[k] * inv;
    }
    __syncthreads();

    // ---- stage 8: out_attn = attn @ v_s via pk_fma on packed pairs ----
    {
        unsigned* oa32 = (unsigned*)(qfull + (size_t)g * 1536);
#pragma unroll
        for (int i = 0; i < 3; i++) {
            int e = tid + i * 256;            // pair index 0..767
            int t = e >> 8, a2p = e & 255;
            int h = a2p >> 5, ddp = a2p & 31;
            const float* ar = att + (h * 3 + t) * 12;
            const unsigned* vp = vsh2 + h * 12 * 32 + ddp;
            half2v acc = {0, 0};
#pragma unroll
            for (int k = 0; k < 12; k++) {
                _Float16 ah = (_Float16)ar[k];
                half2v a2; a2[0] = ah; a2[1] = ah;
                acc += a2 * u2h(vp[k * 32]);
            }
            oa32[e] = h2u(acc);
        }
    }
}

// -------------------------------------------------------------------------
// Kernel 4: out[24576,32](fp32) = oa[24576,512](f16) @ Wout[512,32](fp32)
//           + b_out + features
// -------------------------------------------------------------------------
__global__ __launch_bounds__(256) void outgemm_kernel(
    const unsigned short* __restrict__ oa, const float* __restrict__ Wout,
    const float* __restrict__ b_out, const float* __restrict__ features,
    float* __restrict__ out)
{
    __shared__ __attribute__((aligned(16))) unsigned short WT[32][520]; // [n][k]
    const int tid = threadIdx.x;
    const int R0 = blockIdx.x * 64;
#pragma unroll
    for (int j = 0; j < 64; j++) {
        int lin = j * 256 + tid;         // lin = k*32 + n
        WT[lin & 31][lin >> 5] = f2hu(Wout[lin]);
    }
    __syncthreads();

    const int w = tid >> 6, l = tid & 63, m = l & 15, quad = l >> 4;
    const int row = R0 + w * 16 + m;
    float4v acc[2] = {{0,0,0,0},{0,0,0,0}};
#pragma unroll
    for (int kk = 0; kk < 16; kk++) {
        half8v af = *(const half8v*)(oa + (size_t)row * 512 + kk * 32 + quad * 8);
#pragma unroll
        for (int t = 0; t < 2; t++) {
            half8v b8 = *(const half8v*)&WT[t * 16 + m][kk * 32 + quad * 8];
            acc[t] = __builtin_amdgcn_mfma_f32_16x16x32_f16(af, b8, acc[t], 0, 0, 0);
        }
    }
    const int rb = R0 + w * 16 + quad * 4;
#pragma unroll
    for (int t = 0; t < 2; t++) {
        int col = t * 16 + m;
        float bb = b_out[col];
#pragma unroll
        for (int r = 0; r < 4; r++) {
            int rr = rb + r;
            out[(size_t)rr * 32 + col] = acc[t][r] + bb + features[(size_t)rr * 32 + col];
        }
    }
}

// -------------------------------------------------------------------------
// Fallback (ws too small): fused attention kernel, fp32 inputs, f16 buf.
// -------------------------------------------------------------------------
__global__ __launch_bounds__(256, 6) void attn_fused_kernel(
    const float* __restrict__ means, const float* __restrict__ scales,
    const float* __restrict__ rot,   const float* __restrict__ features,
    const float* __restrict__ transforms, const float* __restrict__ projection,
    const float* __restrict__ Wq,    const float* __restrict__ W_off,
    const float* __restrict__ b_off, const float* __restrict__ Wout,
    const float* __restrict__ b_out, const unsigned short* __restrict__ buf,
    float* __restrict__ out)
{
    __shared__ float feat[96];
    __shared__ __attribute__((aligned(16))) float qf[1536];
    __shared__ float qm[512];
    __shared__ float mw[3], sc3[3], Rt[9], pr[12];
    __shared__ float lrn[144];
    __shared__ int   coff[96][4];
    __shared__ float cwt[96][4];
    __shared__ __attribute__((aligned(16))) char pool[12288];
    __shared__ float att[288];

    unsigned short* vsh = (unsigned short*)pool;
    const int g = blockIdx.x, tid = threadIdx.x;

    if (tid < 96) {
        feat[tid] = features[(size_t)g * 96 + tid];
    } else if (tid < 99) {
        sc3[tid - 96] = scales[(size_t)g * 3 + (tid - 96)];
    } else if (tid >= 100 && tid < 112) {
        pr[tid - 100] = projection[tid - 100];
    } else if (tid == 112) {
        float w = rot[(size_t)g * 4],     x = rot[(size_t)g * 4 + 1];
        float y = rot[(size_t)g * 4 + 2], z = rot[(size_t)g * 4 + 3];
        float n = rsqrtf(w * w + x * x + y * y + z * z);
        w *= n; x *= n; y *= n; z *= n;
        float R00 = 1 - 2 * (y * y + z * z), R01 = 2 * (x * y - w * z), R02 = 2 * (x * z + w * y);
        float R10 = 2 * (x * y + w * z), R11 = 1 - 2 * (x * x + z * z), R12 = 2 * (y * z - w * x);
        float R20 = 2 * (x * z - w * y), R21 = 2 * (y * z + w * x), R22 = 1 - 2 * (x * x + y * y);
        Rt[0] = R00; Rt[1] = R10; Rt[2] = R20;
        Rt[3] = R01; Rt[4] = R11; Rt[5] = R21;
        Rt[6] = R02; Rt[7] = R12; Rt[8] = R22;
    } else if (tid >= 116 && tid < 119) {
        int i = tid - 116;
        float m0 = means[(size_t)g * 3];
        float m1 = means[(size_t)g * 3 + 1];
        float m2 = means[(size_t)g * 3 + 2];
        const float* T = transforms + (size_t)g * 16 + i * 4;
        mw[i] = T[0] * m0 + T[1] * m1 + T[2] * m2 + T[3];
    }
    __syncthreads();

    {
        const int a0 = tid * 2;
        float s00 = 0.f, s01 = 0.f, s10 = 0.f, s11 = 0.f, s20 = 0.f, s21 = 0.f;
#pragma unroll
        for (int f = 0; f < 32; f++) {
            float2 w2 = *(const float2*)(Wq + (size_t)f * 512 + a0);
            float f0 = feat[f], f1 = feat[32 + f], f2 = feat[64 + f];
            s00 += f0 * w2.x; s01 += f0 * w2.y;
            s10 += f1 * w2.x; s11 += f1 * w2.y;
            s20 += f2 * w2.x; s21 += f2 * w2.y;
        }
        *(float2*)(qf + a0)        = make_float2(s00, s01);
        *(float2*)(qf + 512 + a0)  = make_float2(s10, s11);
        *(float2*)(qf + 1024 + a0) = make_float2(s20, s21);
    }
    __syncthreads();

    qm[tid]       = (qf[tid]       + qf[tid + 512] + qf[tid + 1024]) * (1.f / 3.f);
    qm[tid + 256] = (qf[tid + 256] + qf[tid + 768] + qf[tid + 1280]) * (1.f / 3.f);
    __syncthreads();

    if (tid < 144) {
        int h = tid / 18, l = tid % 18;
        float s = b_off[l];
#pragma unroll
        for (int i = 0; i < 3; i++) s += mw[i] * W_off[i * 18 + l];
        for (int d = 0; d < 64; d++) s += qm[h * 64 + d] * W_off[(size_t)(3 + d) * 18 + l];
        s = fminf(fmaxf(s, -9.21f), 9.21f);
        lrn[tid] = 1.f / (1.f + expf(-s)) - 0.5f;
    }
    __syncthreads();

    if (tid < 96) {
        int h = tid / 12, k = tid % 12;
        float s0, s1, s2;
        if (k < 6) {
            const float FSx[6] = {0.f, 1.f, 0.f, 0.f, -1.f, 0.f};
            const float FSy[6] = {0.f, 0.f, 1.f, 0.f, 0.f, -1.f};
            const float FSz[6] = {0.f, 0.f, 0.f, 1.f, 0.f, 0.f};
            s0 = FSx[k]; s1 = FSy[k]; s2 = FSz[k];
        } else {
            int b = h * 18 + (k - 6) * 3;
            s0 = lrn[b]; s1 = lrn[b + 1]; s2 = lrn[b + 2];
        }
        float o0 = s0 * sc3[0], o1 = s1 * sc3[1], o2 = s2 * sc3[2];
        float wx = Rt[0] * o0 + Rt[1] * o1 + Rt[2] * o2 + mw[0];
        float wy = Rt[3] * o0 + Rt[4] * o1 + Rt[5] * o2 + mw[1];
        float wz = Rt[6] * o0 + Rt[7] * o1 + Rt[8] * o2 + mw[2];
        float px = pr[0] * wx + pr[1] * wy + pr[2]  * wz + pr[3];
        float py = pr[4] * wx + pr[5] * wy + pr[6]  * wz + pr[7];
        float pz = pr[8] * wx + pr[9] * wy + pr[10] * wz + pr[11];
        pz = fmaxf(pz, 1e-5f);
        float gx = fminf(fmaxf(px / pz * (1.f / 64.f), 0.f), 0.9999f);
        float gy = fminf(fmaxf(py / pz * (1.f / 64.f), 0.f), 0.9999f);
        float x = gx * 64.f - 0.5f, y = gy * 64.f - 0.5f;
        float fx = floorf(x), fy = floorf(y);
        int x0 = (int)fx, y0 = (int)fy;
        float wx1 = x - fx, wx0c = 1.f - wx1;
        float wy1 = y - fy, wy0c = 1.f - wy1;
        int xs[2] = {x0, x0 + 1}, ys[2] = {y0, y0 + 1};
        float wxs[2] = {wx0c, wx1}, wys[2] = {wy0c, wy1};
#pragma unroll
        for (int c = 0; c < 4; c++) {
            int dx = c & 1, dy = c >> 1;
            int xi = xs[dx], yi = ys[dy];
            bool v = (xi >= 0) & (xi < 64) & (yi >= 0) & (yi < 64);
            int xc = min(max(xi, 0), 63), yc = min(max(yi, 0), 63);
            coff[tid][c] = (yc * 64 + xc) * 1024;
            cwt[tid][c]  = v ? wxs[dx] * wys[dy] : 0.f;
        }
    }
    __syncthreads();

    {
        const int slice = tid & 7, d0 = slice * 8, grp = tid >> 3;
#pragma unroll
        for (int it = 0; it < 3; it++) {
            const int p = it * 32 + grp;
            const int h = p / 12, k = p - h * 12;
            const int a = h * 64 + d0;
            const unsigned short* bp = buf + a;
            float ka[8] = {0,0,0,0,0,0,0,0}, va[8] = {0,0,0,0,0,0,0,0}, t8[8];
#pragma unroll
            for (int c = 0; c < 4; c++) {
                const int   o = coff[p][c];
                const float w = cwt[p][c];
                ld8h(bp + o, t8);
#pragma unroll
                for (int j = 0; j < 8; j++) ka[j] += w * t8[j];
                ld8h(bp + o + 512, t8);
#pragma unroll
                for (int j = 0; j < 8; j++) va[j] += w * t8[j];
            }
            uint4 pv;
            pv.x = packh(va[0], va[1]); pv.y = packh(va[2], va[3]);
            pv.z = packh(va[4], va[5]); pv.w = packh(va[6], va[7]);
            *(uint4*)(vsh + p * 64 + d0) = pv;
            float sp[3];
#pragma unroll
            for (int t = 0; t < 3; t++) {
                const float* qp = qf + t * 512 + a;
                float s = 0.f;
#pragma unroll
                for (int j = 0; j < 8; j++) s += qp[j] * ka[j];
                sp[t] = s;
            }
#pragma unroll
            for (int msk = 1; msk < 8; msk <<= 1) {
#pragma unroll
                for (int t = 0; t < 3; t++) sp[t] += __shfl_xor(sp[t], msk);
            }
            if (slice == 0) {
#pragma unroll
                for (int t = 0; t < 3; t++) att[(h * 3 + t) * 12 + k] = sp[t] * 0.125f;
            }
        }
    }
    __syncthreads();

    if (tid < 24) {
        float* row = att + tid * 12;
        float m = row[0];
#pragma unroll
        for (int k = 1; k < 12; k++) m = fmaxf(m, row[k]);
        float e_[12]; float ssum = 0.f;
#pragma unroll
        for (int k = 0; k < 12; k++) { e_[k] = expf(row[k] - m); ssum += e_[k]; }
        float inv = 1.f / ssum;
#pragma unroll
        for (int k = 0; k < 12; k++) row[k] = e_[k] * inv;
    }
    __syncthreads();

#pragma unroll
    for (int i = 0; i < 6; i++) {
        int e = tid + i * 256;
        int t = e >> 9, a = e & 511, h = a >> 6, dd = a & 63;
        const float* ar = att + (h * 3 + t) * 12;
        const unsigned short* vp = vsh + (h * 12) * 64 + dd;
        float s = 0.f;
#pragma unroll
        for (int k = 0; k < 12; k++) {
            _Float16 hh = __builtin_bit_cast(_Float16, vp[k * 64]);
            s += ar[k] * (float)hh;
        }
        qf[e] = s;
    }
    __syncthreads();

    {
        float* red = (float*)pool;
        const int c0 = (tid & 15) * 2, slice = tid >> 4;
        const int abase = slice * 32;
        float a00 = 0.f, a01 = 0.f, a10 = 0.f, a11 = 0.f, a20 = 0.f, a21 = 0.f;
#pragma unroll
        for (int i = 0; i < 32; i++) {
            int a = abase + i;
            float2 w2 = *(const float2*)(Wout + (size_t)a * 32 + c0);
            float o0 = qf[a], o1 = qf[512 + a], o2 = qf[1024 + a];
            a00 += o0 * w2.x; a01 += o0 * w2.y;
            a10 += o1 * w2.x; a11 += o1 * w2.y;
            a20 += o2 * w2.x; a21 += o2 * w2.y;
        }
        __syncthreads();
        red[(slice * 3 + 0) * 32 + c0] = a00; red[(slice * 3 + 0) * 32 + c0 + 1] = a01;
        red[(slice * 3 + 1) * 32 + c0] = a10; red[(slice * 3 + 1) * 32 + c0 + 1] = a11;
        red[(slice * 3 + 2) * 32 + c0] = a20; red[(slice * 3 + 2) * 32 + c0 + 1] = a21;
        __syncthreads();
        if (tid < 96) {
            int t = tid >> 5, c = tid & 31;
            float acc = b_out[c] + feat[tid];
#pragma unroll
            for (int s = 0; s < 16; s++) acc += red[(s * 3 + t) * 32 + c];
            out[(size_t)g * 96 + tid] = acc;
        }
    }
}

extern "C" void kernel_launch(void* const* d_in, const int* in_sizes, int n_in,
                              void* d_out, int out_size, void* d_ws, size_t ws_size,
                              hipStream_t stream) {
    const float* means      = (const float*)d_in[0];
    const float* scales     = (const float*)d_in[1];
    const float* rot        = (const float*)d_in[2];
    const float* features   = (const float*)d_in[3];
    const float* transforms = (const float*)d_in[4];
    const float* projection = (const float*)d_in[5];
    const float* img        = (const float*)d_in[6];
    const float* Wq         = (const float*)d_in[7];
    const float* Wk         = (const float*)d_in[8];
    const float* Wv         = (const float*)d_in[9];
    const float* W_off      = (const float*)d_in[10];
    const float* b_off      = (const float*)d_in[11];
    const float* Wout       = (const float*)d_in[12];
    const float* b_out      = (const float*)d_in[13];
    float* out = (float*)d_out;

    char* w = (char*)d_ws;
    unsigned short* buf = (unsigned short*)(w + 64);   // 4096 x 1024 f16 = 8 MiB
    const size_t BUF_BYTES = (size_t)4096 * 1024 * 2;
    const size_t Q_BYTES   = (size_t)24576 * 512 * 2;  // 24 MiB
    const size_t need = 64 + BUF_BYTES + Q_BYTES;

    dim3 gridc(64, 16);
    if (ws_size >= need) {
        unsigned short* qfull = (unsigned short*)(w + 64 + BUF_BYTES);
        // overlay in the front of qfull (dead until qgemm runs, strictly after conv)
        unsigned short* imgh = qfull;                  // 1048576 el = 2 MiB
        unsigned short* wkvh = imgh + 1048576;         // 262144 el = 0.5 MiB
        preconvert_kernel<<<1280, 256, 0, stream>>>(img, Wk, Wv, imgh, wkvh);
        conv_f16_kernel<<<gridc, 256, 0, stream>>>(imgh, wkvh, buf);
        dim3 gridq(384, 2);
        qgemm_kernel<<<gridq, 256, 0, stream>>>(features, Wq, qfull);
        attn_core_kernel<<<8192, 256, 0, stream>>>(
            means, scales, rot, transforms, projection, W_off, b_off, buf, qfull);
        outgemm_kernel<<<384, 256, 0, stream>>>(qfull, Wout, b_out, features, out);
    } else {
        conv_mfma_kernel<<<gridc, 256, 0, stream>>>(img, Wk, Wv, buf);
        attn_fused_kernel<<<8192, 256, 0, stream>>>(
            means, scales, rot, features, transforms, projection,
            Wq, W_off, b_off, Wout, b_out, buf, out);
    }
}

// Round 9
// 165.866 us; speedup vs baseline: 4.6838x; 1.0521x over previous
//
#include <hip/hip_runtime.h>
#include <hip/hip_bf16.h>
#include <hip/hip_fp16.h>

typedef _Float16 half2v __attribute__((ext_vector_type(2)));
typedef _Float16 half8v __attribute__((ext_vector_type(8)));
typedef __attribute__((ext_vector_type(4))) float float4v;

// ---- helpers: inputs are fp32; intermediates are f16 (packed-math friendly) ----
__device__ __forceinline__ half2v u2h(unsigned u) { return __builtin_bit_cast(half2v, u); }
__device__ __forceinline__ unsigned h2u(half2v h) { return __builtin_bit_cast(unsigned, h); }
__device__ __forceinline__ unsigned short f2hu(float f) {
    _Float16 h = (_Float16)f; return __builtin_bit_cast(unsigned short, h);
}
__device__ __forceinline__ unsigned packh(float lo, float hi) {
    half2v h; h[0] = (_Float16)lo; h[1] = (_Float16)hi; return h2u(h);
}
// unpack 8 f16 (16B aligned) to 8 floats (fallback path)
__device__ __forceinline__ void ld8h(const unsigned short* p, float* f) {
    uint4 u = *(const uint4*)p;
    half2v h0 = u2h(u.x), h1 = u2h(u.y), h2 = u2h(u.z), h3 = u2h(u.w);
    f[0] = (float)h0[0]; f[1] = (float)h0[1]; f[2] = (float)h1[0]; f[3] = (float)h1[1];
    f[4] = (float)h2[0]; f[5] = (float)h2[1]; f[6] = (float)h3[0]; f[7] = (float)h3[1];
}

// -------------------------------------------------------------------------
// Kernel 1: fused MFMA 1x1 conv from fp32. Both img tile and W tile staged
// into LDS with inline fp32->f16 conversion (once per block).
// buf[px][1024](f16) = img^T[px][256k] @ (Wk|Wv)^T
// -------------------------------------------------------------------------
__global__ __launch_bounds__(256) void conv_fused_kernel(
    const float* __restrict__ img, const float* __restrict__ Wk,
    const float* __restrict__ Wv, unsigned short* __restrict__ buf)
{
    __shared__ __attribute__((aligned(16))) unsigned short Bt[64][264]; // img [px][k]
    __shared__ __attribute__((aligned(16))) unsigned short Wt[64][264]; // W   [row][k]
    const int tid = threadIdx.x;
    const int p0 = blockIdx.x * 64;
    const int o0 = blockIdx.y * 64;
    const float* Wsel = (o0 < 512) ? Wk : Wv;
    const int obase = (o0 < 512) ? o0 : (o0 - 512);

    // ---- stage img tile transposed (fp32 -> f16) ----
#pragma unroll
    for (int i = 0; i < 4; i++) {
        int chunk = i * 256 + tid;
        int kp  = chunk >> 3;              // k-pair index
        int pxg = (chunk & 7) * 8;         // 8-pixel group
        const float* r0 = img + (size_t)(2 * kp) * 4096 + p0 + pxg;
        const float* r1 = img + (size_t)(2 * kp + 1) * 4096 + p0 + pxg;
        float4 a0 = *(const float4*)r0, a1 = *(const float4*)(r0 + 4);
        float4 b0 = *(const float4*)r1, b1 = *(const float4*)(r1 + 4);
        unsigned lo[8], hi[8];
        lo[0] = f2hu(a0.x); lo[1] = f2hu(a0.y); lo[2] = f2hu(a0.z); lo[3] = f2hu(a0.w);
        lo[4] = f2hu(a1.x); lo[5] = f2hu(a1.y); lo[6] = f2hu(a1.z); lo[7] = f2hu(a1.w);
        hi[0] = f2hu(b0.x); hi[1] = f2hu(b0.y); hi[2] = f2hu(b0.z); hi[3] = f2hu(b0.w);
        hi[4] = f2hu(b1.x); hi[5] = f2hu(b1.y); hi[6] = f2hu(b1.z); hi[7] = f2hu(b1.w);
#pragma unroll
        for (int j = 0; j < 8; j++)
            *(unsigned*)&Bt[pxg + j][2 * kp] = lo[j] | (hi[j] << 16);
    }
    // ---- stage W tile (fp32 -> f16): row = tid>>2, 64 k per quarter ----
    {
        const int row = tid >> 2, q = tid & 3;
        const float* wp = Wsel + (size_t)(obase + row) * 256 + q * 64;
#pragma unroll
        for (int j = 0; j < 8; j++) {
            float4 w0 = *(const float4*)(wp + j * 8);
            float4 w1 = *(const float4*)(wp + j * 8 + 4);
            uint4 pk;
            pk.x = packh(w0.x, w0.y); pk.y = packh(w0.z, w0.w);
            pk.z = packh(w1.x, w1.y); pk.w = packh(w1.z, w1.w);
            *(uint4*)&Wt[row][q * 64 + j * 8] = pk;
        }
    }
    __syncthreads();

    const int w = tid >> 6, l = tid & 63;
    const int m = l & 15, quad = l >> 4;
    const int mrow = w * 16 + m;

    float4v acc[4] = {{0,0,0,0},{0,0,0,0},{0,0,0,0},{0,0,0,0}};
#pragma unroll
    for (int kk = 0; kk < 8; kk++) {
        const int kofs = kk * 32 + quad * 8;
        half8v af = *(const half8v*)&Bt[mrow][kofs];
#pragma unroll
        for (int nt = 0; nt < 4; nt++) {
            half8v b8 = *(const half8v*)&Wt[nt * 16 + m][kofs];
            acc[nt] = __builtin_amdgcn_mfma_f32_16x16x32_f16(af, b8, acc[nt], 0, 0, 0);
        }
    }
#pragma unroll
    for (int nt = 0; nt < 4; nt++) {
#pragma unroll
        for (int r = 0; r < 4; r++) {
            size_t px = p0 + w * 16 + quad * 4 + r;
            buf[px * 1024 + o0 + nt * 16 + m] = f2hu(acc[nt][r]);
        }
    }
}

// -------------------------------------------------------------------------
// Kernel 2: qfull[24576,512](f16) = features[24576,32](fp32) @ Wq[32,512](fp32)
// -------------------------------------------------------------------------
__global__ __launch_bounds__(256) void qgemm_kernel(
    const float* __restrict__ features, const float* __restrict__ Wq,
    unsigned short* __restrict__ qfull)
{
    __shared__ __attribute__((aligned(16))) unsigned short WqT[256][40]; // [n][k]
    const int tid = threadIdx.x;
    const int R0 = blockIdx.x * 64;
    const int n0 = blockIdx.y * 256;
#pragma unroll
    for (int k = 0; k < 32; k++)
        WqT[tid][k] = f2hu(Wq[(size_t)k * 512 + n0 + tid]);
    __syncthreads();

    const int w = tid >> 6, l = tid & 63, m = l & 15, quad = l >> 4;
    const int row = R0 + w * 16 + m;
    const float* fp = features + (size_t)row * 32 + quad * 8;
    float4 f0 = *(const float4*)fp, f1 = *(const float4*)(fp + 4);
    half8v af;
    af[0] = (_Float16)f0.x; af[1] = (_Float16)f0.y;
    af[2] = (_Float16)f0.z; af[3] = (_Float16)f0.w;
    af[4] = (_Float16)f1.x; af[5] = (_Float16)f1.y;
    af[6] = (_Float16)f1.z; af[7] = (_Float16)f1.w;
    float4v acc[16];
#pragma unroll
    for (int t = 0; t < 16; t++) acc[t] = (float4v){0.f, 0.f, 0.f, 0.f};
#pragma unroll
    for (int t = 0; t < 16; t++) {
        half8v b8 = *(const half8v*)&WqT[t * 16 + m][quad * 8];
        acc[t] = __builtin_amdgcn_mfma_f32_16x16x32_f16(af, b8, acc[t], 0, 0, 0);
    }
    const int rb = R0 + w * 16 + quad * 4;
#pragma unroll
    for (int t = 0; t < 16; t++)
#pragma unroll
        for (int r = 0; r < 4; r++)
            qfull[(size_t)(rb + r) * 512 + n0 + t * 16 + m] = f2hu(acc[t][r]);
}

// -------------------------------------------------------------------------
// Kernel 3: per-gaussian sampling + attention core. 1 block = 1 gaussian.
// launch_bounds(256,6): ~80 VGPR cap so stage-5's 8 corner loads stay in flight.
// -------------------------------------------------------------------------
__global__ __launch_bounds__(256, 6) void attn_core_kernel(
    const float* __restrict__ means, const float* __restrict__ scales,
    const float* __restrict__ rot,   const float* __restrict__ transforms,
    const float* __restrict__ projection, const float* __restrict__ W_off,
    const float* __restrict__ b_off, const unsigned short* __restrict__ buf,
    unsigned short* __restrict__ qfull)
{
    __shared__ __attribute__((aligned(16))) unsigned qf2[768];   // q f16-pairs [t][256]
    __shared__ __attribute__((aligned(16))) unsigned vsh2[3072]; // W_off stage | v pairs [p][32]
    __shared__ __attribute__((aligned(16))) float qm_u[512];     // qm | corner+att
    __shared__ float lrn[144];
    __shared__ float mw[3], sc3[3], Rt[9], pr[12];

    short4* corner = (short4*)qm_u;       // 96 x 8 B (live stage4+)
    float*  att    = qm_u + 192;          // 288 floats (live stage5+)
    float*  wofl   = (float*)vsh2;        // 1206 floats (live stages 0-3)
    float*  bofl   = wofl + 1206;         // 18 floats

    const int g = blockIdx.x, tid = threadIdx.x;

    // ---- stage 0: geometry + weight staging + q staging (packed) ----
    for (int i = tid; i < 1206; i += 256) wofl[i] = W_off[i];
    if (tid < 18) bofl[tid] = b_off[tid];
    if (tid >= 32 && tid < 35) {
        sc3[tid - 32] = scales[(size_t)g * 3 + (tid - 32)];
    } else if (tid >= 36 && tid < 48) {
        pr[tid - 36] = projection[tid - 36];
    } else if (tid == 48) {
        float w = rot[(size_t)g * 4],     x = rot[(size_t)g * 4 + 1];
        float y = rot[(size_t)g * 4 + 2], z = rot[(size_t)g * 4 + 3];
        float n = rsqrtf(w * w + x * x + y * y + z * z);
        w *= n; x *= n; y *= n; z *= n;
        float R00 = 1 - 2 * (y * y + z * z), R01 = 2 * (x * y - w * z), R02 = 2 * (x * z + w * y);
        float R10 = 2 * (x * y + w * z), R11 = 1 - 2 * (x * x + z * z), R12 = 2 * (y * z - w * x);
        float R20 = 2 * (x * z - w * y), R21 = 2 * (y * z + w * x), R22 = 1 - 2 * (x * x + y * y);
        Rt[0] = R00; Rt[1] = R10; Rt[2] = R20;
        Rt[3] = R01; Rt[4] = R11; Rt[5] = R21;
        Rt[6] = R02; Rt[7] = R12; Rt[8] = R22;
    } else if (tid >= 52 && tid < 55) {
        int i = tid - 52;
        float m0 = means[(size_t)g * 3];
        float m1 = means[(size_t)g * 3 + 1];
        float m2 = means[(size_t)g * 3 + 2];
        const float* T = transforms + (size_t)g * 16 + i * 4;
        mw[i] = T[0] * m0 + T[1] * m1 + T[2] * m2 + T[3];
    }
    {
        const unsigned* qsrc = (const unsigned*)(qfull + (size_t)g * 1536);
#pragma unroll
        for (int i = 0; i < 3; i++) {
            int e = tid + i * 256;
            qf2[e] = qsrc[e];
        }
    }
    __syncthreads();

    // ---- stage 2: q_mean (one pair per thread) ----
    {
        half2v a = u2h(qf2[tid]), b = u2h(qf2[256 + tid]), c = u2h(qf2[512 + tid]);
        qm_u[tid * 2]     = ((float)a[0] + (float)b[0] + (float)c[0]) * (1.f / 3.f);
        qm_u[tid * 2 + 1] = ((float)a[1] + (float)b[1] + (float)c[1]) * (1.f / 3.f);
    }
    __syncthreads();

    // ---- stage 3: OffsetNet (weights from LDS) ----
    if (tid < 144) {
        int h = tid / 18, l = tid % 18;
        float s = bofl[l];
#pragma unroll
        for (int i = 0; i < 3; i++) s += mw[i] * wofl[i * 18 + l];
        for (int d = 0; d < 64; d++) s += qm_u[h * 64 + d] * wofl[(3 + d) * 18 + l];
        s = fminf(fmaxf(s, -9.21f), 9.21f);
        lrn[tid] = 1.f / (1.f + expf(-s)) - 0.5f;
    }
    __syncthreads();

    // ---- stage 4: sample coords -> corner short4 {x0, y0, wx1_u16, wy1_u16} ----
    if (tid < 96) {
        int h = tid / 12, k = tid % 12;
        float s0, s1, s2;
        if (k < 6) {
            const float FSx[6] = {0.f, 1.f, 0.f, 0.f, -1.f, 0.f};
            const float FSy[6] = {0.f, 0.f, 1.f, 0.f, 0.f, -1.f};
            const float FSz[6] = {0.f, 0.f, 0.f, 1.f, 0.f, 0.f};
            s0 = FSx[k]; s1 = FSy[k]; s2 = FSz[k];
        } else {
            int b = h * 18 + (k - 6) * 3;
            s0 = lrn[b]; s1 = lrn[b + 1]; s2 = lrn[b + 2];
        }
        float o0 = s0 * sc3[0], o1 = s1 * sc3[1], o2 = s2 * sc3[2];
        float wx = Rt[0] * o0 + Rt[1] * o1 + Rt[2] * o2 + mw[0];
        float wy = Rt[3] * o0 + Rt[4] * o1 + Rt[5] * o2 + mw[1];
        float wz = Rt[6] * o0 + Rt[7] * o1 + Rt[8] * o2 + mw[2];
        float px = pr[0] * wx + pr[1] * wy + pr[2]  * wz + pr[3];
        float py = pr[4] * wx + pr[5] * wy + pr[6]  * wz + pr[7];
        float pz = pr[8] * wx + pr[9] * wy + pr[10] * wz + pr[11];
        pz = fmaxf(pz, 1e-5f);
        float gx = fminf(fmaxf(px / pz * (1.f / 64.f), 0.f), 0.9999f);
        float gy = fminf(fmaxf(py / pz * (1.f / 64.f), 0.f), 0.9999f);
        float x = gx * 64.f - 0.5f, y = gy * 64.f - 0.5f;
        float fx = floorf(x), fy = floorf(y);
        short4 cn;
        cn.x = (short)(int)fx;
        cn.y = (short)(int)fy;
        cn.z = (short)(unsigned short)fminf((x - fx) * 65536.f, 65535.f);
        cn.w = (short)(unsigned short)fminf((y - fy) * 65536.f, 65535.f);
        corner[tid] = cn;
    }
    __syncthreads();

    // ---- stage 5: batched 8-load gather + packed-f16 bilinear + fdot2 scores ----
    {
        const int slice = tid & 7, grp = tid >> 3;
#pragma unroll
        for (int it = 0; it < 3; it++) {
            const int p = it * 32 + grp;
            const int h = p / 12, k = p - h * 12;
            short4 cn = corner[p];
            int x0 = cn.x, y0 = cn.y, x1 = x0 + 1, y1 = y0 + 1;
            float wx1 = (float)(unsigned short)cn.z * (1.f / 65536.f);
            float wy1 = (float)(unsigned short)cn.w * (1.f / 65536.f);
            float wx0 = 1.f - wx1, wy0 = 1.f - wy1;
            bool vx0 = (unsigned)x0 < 64u, vx1 = (unsigned)x1 < 64u;
            bool vy0 = (unsigned)y0 < 64u, vy1 = (unsigned)y1 < 64u;
            int xc0 = min(max(x0, 0), 63), xc1 = min(max(x1, 0), 63);
            int yc0 = min(max(y0, 0), 63), yc1 = min(max(y1, 0), 63);
            int   off[4];
            float wt[4];
            off[0] = (yc0 * 64 + xc0) * 1024; wt[0] = (vx0 & vy0) ? wx0 * wy0 : 0.f;
            off[1] = (yc0 * 64 + xc1) * 1024; wt[1] = (vx1 & vy0) ? wx1 * wy0 : 0.f;
            off[2] = (yc1 * 64 + xc0) * 1024; wt[2] = (vx0 & vy1) ? wx0 * wy1 : 0.f;
            off[3] = (yc1 * 64 + xc1) * 1024; wt[3] = (vx1 & vy1) ? wx1 * wy1 : 0.f;
            const int a = h * 64 + slice * 8;          // channel base
            const unsigned short* bp = buf + a;
            // issue ALL 8 loads before any math (needs the 6-waves VGPR budget)
            uint4 uk[4], uv[4];
#pragma unroll
            for (int c = 0; c < 4; c++) {
                uk[c] = *(const uint4*)(bp + off[c]);
                uv[c] = *(const uint4*)(bp + off[c] + 512);
            }
            half2v ka2[4] = {{0,0},{0,0},{0,0},{0,0}};
            half2v va2[4] = {{0,0},{0,0},{0,0},{0,0}};
#pragma unroll
            for (int c = 0; c < 4; c++) {
                _Float16 wh = (_Float16)wt[c];
                half2v w2; w2[0] = wh; w2[1] = wh;
                ka2[0] += w2 * u2h(uk[c].x); ka2[1] += w2 * u2h(uk[c].y);
                ka2[2] += w2 * u2h(uk[c].z); ka2[3] += w2 * u2h(uk[c].w);
                va2[0] += w2 * u2h(uv[c].x); va2[1] += w2 * u2h(uv[c].y);
                va2[2] += w2 * u2h(uv[c].z); va2[3] += w2 * u2h(uv[c].w);
            }
            const int pa = h * 32 + slice * 4;         // pair base
            *(uint4*)&vsh2[p * 32 + slice * 4] =
                make_uint4(h2u(va2[0]), h2u(va2[1]), h2u(va2[2]), h2u(va2[3]));
            float sp[3];
#pragma unroll
            for (int t = 0; t < 3; t++) {
                uint4 q4 = *(const uint4*)&qf2[t * 256 + pa];
                float s = __builtin_amdgcn_fdot2(u2h(q4.x), ka2[0], 0.f, false);
                s = __builtin_amdgcn_fdot2(u2h(q4.y), ka2[1], s, false);
                s = __builtin_amdgcn_fdot2(u2h(q4.z), ka2[2], s, false);
                s = __builtin_amdgcn_fdot2(u2h(q4.w), ka2[3], s, false);
                sp[t] = s;
            }
#pragma unroll
            for (int msk = 1; msk < 8; msk <<= 1) {
#pragma unroll
                for (int t = 0; t < 3; t++) sp[t] += __shfl_xor(sp[t], msk);
            }
            if (slice == 0) {
#pragma unroll
                for (int t = 0; t < 3; t++) att[(h * 3 + t) * 12 + k] = sp[t] * 0.125f;
            }
        }
    }
    __syncthreads();

    // ---- stage 7: softmax over K=12 ----
    if (tid < 24) {
        float* row = att + tid * 12;
        float m = row[0];
#pragma unroll
        for (int k = 1; k < 12; k++) m = fmaxf(m, row[k]);
        float e_[12]; float ssum = 0.f;
#pragma unroll
        for (int k = 0; k < 12; k++) { e_[k] = expf(row[k] - m); ssum += e_[k]; }
        float inv = 1.f / ssum;
#pragma unroll
        for (int k = 0; k < 12; k++) row[k] = e_[k] * inv;
    }
    __syncthreads();

    // ---- stage 8: out_attn = attn @ v_s via pk_fma on packed pairs ----
    {
        unsigned* oa32 = (unsigned*)(qfull + (size_t)g * 1536);
#pragma unroll
        for (int i = 0; i < 3; i++) {
            int e = tid + i * 256;            // pair index 0..767
            int t = e >> 8, a2p = e & 255;
            int h = a2p >> 5, ddp = a2p & 31;
            const float* ar = att + (h * 3 + t) * 12;
            const unsigned* vp = vsh2 + h * 12 * 32 + ddp;
            half2v acc = {0, 0};
#pragma unroll
            for (int k = 0; k < 12; k++) {
                _Float16 ah = (_Float16)ar[k];
                half2v a2; a2[0] = ah; a2[1] = ah;
                acc += a2 * u2h(vp[k * 32]);
            }
            oa32[e] = h2u(acc);
        }
    }
}

// -------------------------------------------------------------------------
// Kernel 4: out[24576,32](fp32) = oa[24576,512](f16) @ Wout[512,32](fp32)
//           + b_out + features
// -------------------------------------------------------------------------
__global__ __launch_bounds__(256) void outgemm_kernel(
    const unsigned short* __restrict__ oa, const float* __restrict__ Wout,
    const float* __restrict__ b_out, const float* __restrict__ features,
    float* __restrict__ out)
{
    __shared__ __attribute__((aligned(16))) unsigned short WT[32][520]; // [n][k]
    const int tid = threadIdx.x;
    const int R0 = blockIdx.x * 64;
#pragma unroll
    for (int j = 0; j < 64; j++) {
        int lin = j * 256 + tid;         // lin = k*32 + n
        WT[lin & 31][lin >> 5] = f2hu(Wout[lin]);
    }
    __syncthreads();

    const int w = tid >> 6, l = tid & 63, m = l & 15, quad = l >> 4;
    const int row = R0 + w * 16 + m;
    float4v acc[2] = {{0,0,0,0},{0,0,0,0}};
#pragma unroll
    for (int kk = 0; kk < 16; kk++) {
        half8v af = *(const half8v*)(oa + (size_t)row * 512 + kk * 32 + quad * 8);
#pragma unroll
        for (int t = 0; t < 2; t++) {
            half8v b8 = *(const half8v*)&WT[t * 16 + m][kk * 32 + quad * 8];
            acc[t] = __builtin_amdgcn_mfma_f32_16x16x32_f16(af, b8, acc[t], 0, 0, 0);
        }
    }
    const int rb = R0 + w * 16 + quad * 4;
#pragma unroll
    for (int t = 0; t < 2; t++) {
        int col = t * 16 + m;
        float bb = b_out[col];
#pragma unroll
        for (int r = 0; r < 4; r++) {
            int rr = rb + r;
            out[(size_t)rr * 32 + col] = acc[t][r] + bb + features[(size_t)rr * 32 + col];
        }
    }
}

// -------------------------------------------------------------------------
// Fallback (ws too small): fused attention kernel, fp32 inputs, f16 buf.
// -------------------------------------------------------------------------
__global__ __launch_bounds__(256, 6) void attn_fused_kernel(
    const float* __restrict__ means, const float* __restrict__ scales,
    const float* __restrict__ rot,   const float* __restrict__ features,
    const float* __restrict__ transforms, const float* __restrict__ projection,
    const float* __restrict__ Wq,    const float* __restrict__ W_off,
    const float* __restrict__ b_off, const float* __restrict__ Wout,
    const float* __restrict__ b_out, const unsigned short* __restrict__ buf,
    float* __restrict__ out)
{
    __shared__ float feat[96];
    __shared__ __attribute__((aligned(16))) float qf[1536];
    __shared__ float qm[512];
    __shared__ float mw[3], sc3[3], Rt[9], pr[12];
    __shared__ float lrn[144];
    __shared__ int   coff[96][4];
    __shared__ float cwt[96][4];
    __shared__ __attribute__((aligned(16))) char pool[12288];
    __shared__ float att[288];

    unsigned short* vsh = (unsigned short*)pool;
    const int g = blockIdx.x, tid = threadIdx.x;

    if (tid < 96) {
        feat[tid] = features[(size_t)g * 96 + tid];
    } else if (tid < 99) {
        sc3[tid - 96] = scales[(size_t)g * 3 + (tid - 96)];
    } else if (tid >= 100 && tid < 112) {
        pr[tid - 100] = projection[tid - 100];
    } else if (tid == 112) {
        float w = rot[(size_t)g * 4],     x = rot[(size_t)g * 4 + 1];
        float y = rot[(size_t)g * 4 + 2], z = rot[(size_t)g * 4 + 3];
        float n = rsqrtf(w * w + x * x + y * y + z * z);
        w *= n; x *= n; y *= n; z *= n;
        float R00 = 1 - 2 * (y * y + z * z), R01 = 2 * (x * y - w * z), R02 = 2 * (x * z + w * y);
        float R10 = 2 * (x * y + w * z), R11 = 1 - 2 * (x * x + z * z), R12 = 2 * (y * z - w * x);
        float R20 = 2 * (x * z - w * y), R21 = 2 * (y * z + w * x), R22 = 1 - 2 * (x * x + y * y);
        Rt[0] = R00; Rt[1] = R10; Rt[2] = R20;
        Rt[3] = R01; Rt[4] = R11; Rt[5] = R21;
        Rt[6] = R02; Rt[7] = R12; Rt[8] = R22;
    } else if (tid >= 116 && tid < 119) {
        int i = tid - 116;
        float m0 = means[(size_t)g * 3];
        float m1 = means[(size_t)g * 3 + 1];
        float m2 = means[(size_t)g * 3 + 2];
        const float* T = transforms + (size_t)g * 16 + i * 4;
        mw[i] = T[0] * m0 + T[1] * m1 + T[2] * m2 + T[3];
    }
    __syncthreads();

    {
        const int a0 = tid * 2;
        float s00 = 0.f, s01 = 0.f, s10 = 0.f, s11 = 0.f, s20 = 0.f, s21 = 0.f;
#pragma unroll
        for (int f = 0; f < 32; f++) {
            float2 w2 = *(const float2*)(Wq + (size_t)f * 512 + a0);
            float f0 = feat[f], f1 = feat[32 + f], f2 = feat[64 + f];
            s00 += f0 * w2.x; s01 += f0 * w2.y;
            s10 += f1 * w2.x; s11 += f1 * w2.y;
            s20 += f2 * w2.x; s21 += f2 * w2.y;
        }
        *(float2*)(qf + a0)        = make_float2(s00, s01);
        *(float2*)(qf + 512 + a0)  = make_float2(s10, s11);
        *(float2*)(qf + 1024 + a0) = make_float2(s20, s21);
    }
    __syncthreads();

    qm[tid]       = (qf[tid]       + qf[tid + 512] + qf[tid + 1024]) * (1.f / 3.f);
    qm[tid + 256] = (qf[tid + 256] + qf[tid + 768] + qf[tid + 1280]) * (1.f / 3.f);
    __syncthreads();

    if (tid < 144) {
        int h = tid / 18, l = tid % 18;
        float s = b_off[l];
#pragma unroll
        for (int i = 0; i < 3; i++) s += mw[i] * W_off[i * 18 + l];
        for (int d = 0; d < 64; d++) s += qm[h * 64 + d] * W_off[(size_t)(3 + d) * 18 + l];
        s = fminf(fmaxf(s, -9.21f), 9.21f);
        lrn[tid] = 1.f / (1.f + expf(-s)) - 0.5f;
    }
    __syncthreads();

    if (tid < 96) {
        int h = tid / 12, k = tid % 12;
        float s0, s1, s2;
        if (k < 6) {
            const float FSx[6] = {0.f, 1.f, 0.f, 0.f, -1.f, 0.f};
            const float FSy[6] = {0.f, 0.f, 1.f, 0.f, 0.f, -1.f};
            const float FSz[6] = {0.f, 0.f, 0.f, 1.f, 0.f, 0.f};
            s0 = FSx[k]; s1 = FSy[k]; s2 = FSz[k];
        } else {
            int b = h * 18 + (k - 6) * 3;
            s0 = lrn[b]; s1 = lrn[b + 1]; s2 = lrn[b + 2];
        }
        float o0 = s0 * sc3[0], o1 = s1 * sc3[1], o2 = s2 * sc3[2];
        float wx = Rt[0] * o0 + Rt[1] * o1 + Rt[2] * o2 + mw[0];
        float wy = Rt[3] * o0 + Rt[4] * o1 + Rt[5] * o2 + mw[1];
        float wz = Rt[6] * o0 + Rt[7] * o1 + Rt[8] * o2 + mw[2];
        float px = pr[0] * wx + pr[1] * wy + pr[2]  * wz + pr[3];
        float py = pr[4] * wx + pr[5] * wy + pr[6]  * wz + pr[7];
        float pz = pr[8] * wx + pr[9] * wy + pr[10] * wz + pr[11];
        pz = fmaxf(pz, 1e-5f);
        float gx = fminf(fmaxf(px / pz * (1.f / 64.f), 0.f), 0.9999f);
        float gy = fminf(fmaxf(py / pz * (1.f / 64.f), 0.f), 0.9999f);
        float x = gx * 64.f - 0.5f, y = gy * 64.f - 0.5f;
        float fx = floorf(x), fy = floorf(y);
        int x0 = (int)fx, y0 = (int)fy;
        float wx1 = x - fx, wx0c = 1.f - wx1;
        float wy1 = y - fy, wy0c = 1.f - wy1;
        int xs[2] = {x0, x0 + 1}, ys[2] = {y0, y0 + 1};
        float wxs[2] = {wx0c, wx1}, wys[2] = {wy0c, wy1};
#pragma unroll
        for (int c = 0; c < 4; c++) {
            int dx = c & 1, dy = c >> 1;
            int xi = xs[dx], yi = ys[dy];
            bool v = (xi >= 0) & (xi < 64) & (yi >= 0) & (yi < 64);
            int xc = min(max(xi, 0), 63), yc = min(max(yi, 0), 63);
            coff[tid][c] = (yc * 64 + xc) * 1024;
            cwt[tid][c]  = v ? wxs[dx] * wys[dy] : 0.f;
        }
    }
    __syncthreads();

    {
        const int slice = tid & 7, d0 = slice * 8, grp = tid >> 3;
#pragma unroll
        for (int it = 0; it < 3; it++) {
            const int p = it * 32 + grp;
            const int h = p / 12, k = p - h * 12;
            const int a = h * 64 + d0;
            const unsigned short* bp = buf + a;
            float ka[8] = {0,0,0,0,0,0,0,0}, va[8] = {0,0,0,0,0,0,0,0}, t8[8];
#pragma unroll
            for (int c = 0; c < 4; c++) {
                const int   o = coff[p][c];
                const float w = cwt[p][c];
                ld8h(bp + o, t8);
#pragma unroll
                for (int j = 0; j < 8; j++) ka[j] += w * t8[j];
                ld8h(bp + o + 512, t8);
#pragma unroll
                for (int j = 0; j < 8; j++) va[j] += w * t8[j];
            }
            uint4 pv;
            pv.x = packh(va[0], va[1]); pv.y = packh(va[2], va[3]);
            pv.z = packh(va[4], va[5]); pv.w = packh(va[6], va[7]);
            *(uint4*)(vsh + p * 64 + d0) = pv;
            float sp[3];
#pragma unroll
            for (int t = 0; t < 3; t++) {
                const float* qp = qf + t * 512 + a;
                float s = 0.f;
#pragma unroll
                for (int j = 0; j < 8; j++) s += qp[j] * ka[j];
                sp[t] = s;
            }
#pragma unroll
            for (int msk = 1; msk < 8; msk <<= 1) {
#pragma unroll
                for (int t = 0; t < 3; t++) sp[t] += __shfl_xor(sp[t], msk);
            }
            if (slice == 0) {
#pragma unroll
                for (int t = 0; t < 3; t++) att[(h * 3 + t) * 12 + k] = sp[t] * 0.125f;
            }
        }
    }
    __syncthreads();

    if (tid < 24) {
        float* row = att + tid * 12;
        float m = row[0];
#pragma unroll
        for (int k = 1; k < 12; k++) m = fmaxf(m, row[k]);
        float e_[12]; float ssum = 0.f;
#pragma unroll
        for (int k = 0; k < 12; k++) { e_[k] = expf(row[k] - m); ssum += e_[k]; }
        float inv = 1.f / ssum;
#pragma unroll
        for (int k = 0; k < 12; k++) row[k] = e_[k] * inv;
    }
    __syncthreads();

#pragma unroll
    for (int i = 0; i < 6; i++) {
        int e = tid + i * 256;
        int t = e >> 9, a = e & 511, h = a >> 6, dd = a & 63;
        const float* ar = att + (h * 3 + t) * 12;
        const unsigned short* vp = vsh + (h * 12) * 64 + dd;
        float s = 0.f;
#pragma unroll
        for (int k = 0; k < 12; k++) {
            _Float16 hh = __builtin_bit_cast(_Float16, vp[k * 64]);
            s += ar[k] * (float)hh;
        }
        qf[e] = s;
    }
    __syncthreads();

    {
        float* red = (float*)pool;
        const int c0 = (tid & 15) * 2, slice = tid >> 4;
        const int abase = slice * 32;
        float a00 = 0.f, a01 = 0.f, a10 = 0.f, a11 = 0.f, a20 = 0.f, a21 = 0.f;
#pragma unroll
        for (int i = 0; i < 32; i++) {
            int a = abase + i;
            float2 w2 = *(const float2*)(Wout + (size_t)a * 32 + c0);
            float o0 = qf[a], o1 = qf[512 + a], o2 = qf[1024 + a];
            a00 += o0 * w2.x; a01 += o0 * w2.y;
            a10 += o1 * w2.x; a11 += o1 * w2.y;
            a20 += o2 * w2.x; a21 += o2 * w2.y;
        }
        __syncthreads();
        red[(slice * 3 + 0) * 32 + c0] = a00; red[(slice * 3 + 0) * 32 + c0 + 1] = a01;
        red[(slice * 3 + 1) * 32 + c0] = a10; red[(slice * 3 + 1) * 32 + c0 + 1] = a11;
        red[(slice * 3 + 2) * 32 + c0] = a20; red[(slice * 3 + 2) * 32 + c0 + 1] = a21;
        __syncthreads();
        if (tid < 96) {
            int t = tid >> 5, c = tid & 31;
            float acc = b_out[c] + feat[tid];
#pragma unroll
            for (int s = 0; s < 16; s++) acc += red[(s * 3 + t) * 32 + c];
            out[(size_t)g * 96 + tid] = acc;
        }
    }
}

extern "C" void kernel_launch(void* const* d_in, const int* in_sizes, int n_in,
                              void* d_out, int out_size, void* d_ws, size_t ws_size,
                              hipStream_t stream) {
    const float* means      = (const float*)d_in[0];
    const float* scales     = (const float*)d_in[1];
    const float* rot        = (const float*)d_in[2];
    const float* features   = (const float*)d_in[3];
    const float* transforms = (const float*)d_in[4];
    const float* projection = (const float*)d_in[5];
    const float* img        = (const float*)d_in[6];
    const float* Wq         = (const float*)d_in[7];
    const float* Wk         = (const float*)d_in[8];
    const float* Wv         = (const float*)d_in[9];
    const float* W_off      = (const float*)d_in[10];
    const float* b_off      = (const float*)d_in[11];
    const float* Wout       = (const float*)d_in[12];
    const float* b_out      = (const float*)d_in[13];
    float* out = (float*)d_out;

    char* w = (char*)d_ws;
    unsigned short* buf = (unsigned short*)(w + 64);   // 4096 x 1024 f16 = 8 MiB
    const size_t BUF_BYTES = (size_t)4096 * 1024 * 2;
    const size_t Q_BYTES   = (size_t)24576 * 512 * 2;  // 24 MiB
    const size_t need = 64 + BUF_BYTES + Q_BYTES;

    dim3 gridc(64, 16);
    conv_fused_kernel<<<gridc, 256, 0, stream>>>(img, Wk, Wv, buf);

    if (ws_size >= need) {
        unsigned short* qfull = (unsigned short*)(w + 64 + BUF_BYTES);
        dim3 gridq(384, 2);
        qgemm_kernel<<<gridq, 256, 0, stream>>>(features, Wq, qfull);
        attn_core_kernel<<<8192, 256, 0, stream>>>(
            means, scales, rot, transforms, projection, W_off, b_off, buf, qfull);
        outgemm_kernel<<<384, 256, 0, stream>>>(qfull, Wout, b_out, features, out);
    } else {
        attn_fused_kernel<<<8192, 256, 0, stream>>>(
            means, scales, rot, features, transforms, projection,
            Wq, W_off, b_off, Wout, b_out, buf, out);
    }
}

// Round 11
// 164.779 us; speedup vs baseline: 4.7147x; 1.0066x over previous
//
#include <hip/hip_runtime.h>
#include <hip/hip_bf16.h>
#include <hip/hip_fp16.h>

typedef _Float16 half2v __attribute__((ext_vector_type(2)));
typedef _Float16 half8v __attribute__((ext_vector_type(8)));
typedef __attribute__((ext_vector_type(4))) float float4v;

// ---- helpers: inputs are fp32; intermediates are f16 (packed-math friendly) ----
__device__ __forceinline__ half2v u2h(unsigned u) { return __builtin_bit_cast(half2v, u); }
__device__ __forceinline__ unsigned h2u(half2v h) { return __builtin_bit_cast(unsigned, h); }
__device__ __forceinline__ unsigned short f2hu(float f) {
    _Float16 h = (_Float16)f; return __builtin_bit_cast(unsigned short, h);
}
__device__ __forceinline__ unsigned packh(float lo, float hi) {
    half2v h; h[0] = (_Float16)lo; h[1] = (_Float16)hi; return h2u(h);
}
// unpack 8 f16 (16B aligned) to 8 floats (fallback path)
__device__ __forceinline__ void ld8h(const unsigned short* p, float* f) {
    uint4 u = *(const uint4*)p;
    half2v h0 = u2h(u.x), h1 = u2h(u.y), h2 = u2h(u.z), h3 = u2h(u.w);
    f[0] = (float)h0[0]; f[1] = (float)h0[1]; f[2] = (float)h1[0]; f[3] = (float)h1[1];
    f[4] = (float)h2[0]; f[5] = (float)h2[1]; f[6] = (float)h3[0]; f[7] = (float)h3[1];
}

// -------------------------------------------------------------------------
// Kernel 1: fused MFMA 1x1 conv from fp32. Both img tile and W tile staged
// into LDS with inline fp32->f16 conversion (once per block).
// buf[px][1024](f16) = img^T[px][256k] @ (Wk|Wv)^T
// -------------------------------------------------------------------------
__global__ __launch_bounds__(256) void conv_fused_kernel(
    const float* __restrict__ img, const float* __restrict__ Wk,
    const float* __restrict__ Wv, unsigned short* __restrict__ buf)
{
    __shared__ __attribute__((aligned(16))) unsigned short Bt[64][264]; // img [px][k]
    __shared__ __attribute__((aligned(16))) unsigned short Wt[64][264]; // W   [row][k]
    const int tid = threadIdx.x;
    const int p0 = blockIdx.x * 64;
    const int o0 = blockIdx.y * 64;
    const float* Wsel = (o0 < 512) ? Wk : Wv;
    const int obase = (o0 < 512) ? o0 : (o0 - 512);

    // ---- stage img tile transposed (fp32 -> f16) ----
#pragma unroll
    for (int i = 0; i < 4; i++) {
        int chunk = i * 256 + tid;
        int kp  = chunk >> 3;              // k-pair index
        int pxg = (chunk & 7) * 8;         // 8-pixel group
        const float* r0 = img + (size_t)(2 * kp) * 4096 + p0 + pxg;
        const float* r1 = img + (size_t)(2 * kp + 1) * 4096 + p0 + pxg;
        float4 a0 = *(const float4*)r0, a1 = *(const float4*)(r0 + 4);
        float4 b0 = *(const float4*)r1, b1 = *(const float4*)(r1 + 4);
        unsigned lo[8], hi[8];
        lo[0] = f2hu(a0.x); lo[1] = f2hu(a0.y); lo[2] = f2hu(a0.z); lo[3] = f2hu(a0.w);
        lo[4] = f2hu(a1.x); lo[5] = f2hu(a1.y); lo[6] = f2hu(a1.z); lo[7] = f2hu(a1.w);
        hi[0] = f2hu(b0.x); hi[1] = f2hu(b0.y); hi[2] = f2hu(b0.z); hi[3] = f2hu(b0.w);
        hi[4] = f2hu(b1.x); hi[5] = f2hu(b1.y); hi[6] = f2hu(b1.z); hi[7] = f2hu(b1.w);
#pragma unroll
        for (int j = 0; j < 8; j++)
            *(unsigned*)&Bt[pxg + j][2 * kp] = lo[j] | (hi[j] << 16);
    }
    // ---- stage W tile (fp32 -> f16): row = tid>>2, 64 k per quarter ----
    {
        const int row = tid >> 2, q = tid & 3;
        const float* wp = Wsel + (size_t)(obase + row) * 256 + q * 64;
#pragma unroll
        for (int j = 0; j < 8; j++) {
            float4 w0 = *(const float4*)(wp + j * 8);
            float4 w1 = *(const float4*)(wp + j * 8 + 4);
            uint4 pk;
            pk.x = packh(w0.x, w0.y); pk.y = packh(w0.z, w0.w);
            pk.z = packh(w1.x, w1.y); pk.w = packh(w1.z, w1.w);
            *(uint4*)&Wt[row][q * 64 + j * 8] = pk;
        }
    }
    __syncthreads();

    const int w = tid >> 6, l = tid & 63;
    const int m = l & 15, quad = l >> 4;
    const int mrow = w * 16 + m;

    float4v acc[4] = {{0,0,0,0},{0,0,0,0},{0,0,0,0},{0,0,0,0}};
#pragma unroll
    for (int kk = 0; kk < 8; kk++) {
        const int kofs = kk * 32 + quad * 8;
        half8v af = *(const half8v*)&Bt[mrow][kofs];
#pragma unroll
        for (int nt = 0; nt < 4; nt++) {
            half8v b8 = *(const half8v*)&Wt[nt * 16 + m][kofs];
            acc[nt] = __builtin_amdgcn_mfma_f32_16x16x32_f16(af, b8, acc[nt], 0, 0, 0);
        }
    }
#pragma unroll
    for (int nt = 0; nt < 4; nt++) {
#pragma unroll
        for (int r = 0; r < 4; r++) {
            size_t px = p0 + w * 16 + quad * 4 + r;
            buf[px * 1024 + o0 + nt * 16 + m] = f2hu(acc[nt][r]);
        }
    }
}

// -------------------------------------------------------------------------
// Kernel 2: qfull[24576,512](f16) = features[24576,32](fp32) @ Wq[32,512](fp32)
// -------------------------------------------------------------------------
__global__ __launch_bounds__(256) void qgemm_kernel(
    const float* __restrict__ features, const float* __restrict__ Wq,
    unsigned short* __restrict__ qfull)
{
    __shared__ __attribute__((aligned(16))) unsigned short WqT[256][40]; // [n][k]
    const int tid = threadIdx.x;
    const int R0 = blockIdx.x * 64;
    const int n0 = blockIdx.y * 256;
#pragma unroll
    for (int k = 0; k < 32; k++)
        WqT[tid][k] = f2hu(Wq[(size_t)k * 512 + n0 + tid]);
    __syncthreads();

    const int w = tid >> 6, l = tid & 63, m = l & 15, quad = l >> 4;
    const int row = R0 + w * 16 + m;
    const float* fp = features + (size_t)row * 32 + quad * 8;
    float4 f0 = *(const float4*)fp, f1 = *(const float4*)(fp + 4);
    half8v af;
    af[0] = (_Float16)f0.x; af[1] = (_Float16)f0.y;
    af[2] = (_Float16)f0.z; af[3] = (_Float16)f0.w;
    af[4] = (_Float16)f1.x; af[5] = (_Float16)f1.y;
    af[6] = (_Float16)f1.z; af[7] = (_Float16)f1.w;
    float4v acc[16];
#pragma unroll
    for (int t = 0; t < 16; t++) acc[t] = (float4v){0.f, 0.f, 0.f, 0.f};
#pragma unroll
    for (int t = 0; t < 16; t++) {
        half8v b8 = *(const half8v*)&WqT[t * 16 + m][quad * 8];
        acc[t] = __builtin_amdgcn_mfma_f32_16x16x32_f16(af, b8, acc[t], 0, 0, 0);
    }
    const int rb = R0 + w * 16 + quad * 4;
#pragma unroll
    for (int t = 0; t < 16; t++)
#pragma unroll
        for (int r = 0; r < 4; r++)
            qfull[(size_t)(rb + r) * 512 + n0 + t * 16 + m] = f2hu(acc[t][r]);
}

// -------------------------------------------------------------------------
// Kernel 3: per-gaussian sampling + attention core. 1 block = 1 gaussian.
// launch_bounds(256,6): ~80 VGPR cap so stage-5's 8 corner loads stay in flight.
// -------------------------------------------------------------------------
__global__ __launch_bounds__(256, 6) void attn_core_kernel(
    const float* __restrict__ means, const float* __restrict__ scales,
    const float* __restrict__ rot,   const float* __restrict__ transforms,
    const float* __restrict__ projection, const float* __restrict__ W_off,
    const float* __restrict__ b_off, const unsigned short* __restrict__ buf,
    unsigned short* __restrict__ qfull)
{
    __shared__ __attribute__((aligned(16))) unsigned qf2[768];   // q f16-pairs [t][256]
    __shared__ __attribute__((aligned(16))) unsigned vsh2[3072]; // W_off stage | v pairs [p][32]
    __shared__ __attribute__((aligned(16))) float qm_u[512];     // qm | corner+att
    __shared__ float lrn[144];
    __shared__ float mw[3], sc3[3], Rt[9], pr[12];

    short4* corner = (short4*)qm_u;       // 96 x 8 B (live stage4+)
    float*  att    = qm_u + 192;          // 288 floats (live stage5+)
    float*  wofl   = (float*)vsh2;        // 1206 floats (live stages 0-3)
    float*  bofl   = wofl + 1206;         // 18 floats

    const int g = blockIdx.x, tid = threadIdx.x;

    // ---- stage 0: geometry + weight staging + q staging (packed) ----
    for (int i = tid; i < 1206; i += 256) wofl[i] = W_off[i];
    if (tid < 18) bofl[tid] = b_off[tid];
    if (tid >= 32 && tid < 35) {
        sc3[tid - 32] = scales[(size_t)g * 3 + (tid - 32)];
    } else if (tid >= 36 && tid < 48) {
        pr[tid - 36] = projection[tid - 36];
    } else if (tid == 48) {
        float w = rot[(size_t)g * 4],     x = rot[(size_t)g * 4 + 1];
        float y = rot[(size_t)g * 4 + 2], z = rot[(size_t)g * 4 + 3];
        float n = rsqrtf(w * w + x * x + y * y + z * z);
        w *= n; x *= n; y *= n; z *= n;
        float R00 = 1 - 2 * (y * y + z * z), R01 = 2 * (x * y - w * z), R02 = 2 * (x * z + w * y);
        float R10 = 2 * (x * y + w * z), R11 = 1 - 2 * (x * x + z * z), R12 = 2 * (y * z - w * x);
        float R20 = 2 * (x * z - w * y), R21 = 2 * (y * z + w * x), R22 = 1 - 2 * (x * x + y * y);
        Rt[0] = R00; Rt[1] = R10; Rt[2] = R20;
        Rt[3] = R01; Rt[4] = R11; Rt[5] = R21;
        Rt[6] = R02; Rt[7] = R12; Rt[8] = R22;
    } else if (tid >= 52 && tid < 55) {
        int i = tid - 52;
        float m0 = means[(size_t)g * 3];
        float m1 = means[(size_t)g * 3 + 1];
        float m2 = means[(size_t)g * 3 + 2];
        const float* T = transforms + (size_t)g * 16 + i * 4;
        mw[i] = T[0] * m0 + T[1] * m1 + T[2] * m2 + T[3];
    }
    {
        const unsigned* qsrc = (const unsigned*)(qfull + (size_t)g * 1536);
#pragma unroll
        for (int i = 0; i < 3; i++) {
            int e = tid + i * 256;
            qf2[e] = qsrc[e];
        }
    }
    __syncthreads();

    // ---- stage 2: q_mean (one pair per thread) ----
    {
        half2v a = u2h(qf2[tid]), b = u2h(qf2[256 + tid]), c = u2h(qf2[512 + tid]);
        qm_u[tid * 2]     = ((float)a[0] + (float)b[0] + (float)c[0]) * (1.f / 3.f);
        qm_u[tid * 2 + 1] = ((float)a[1] + (float)b[1] + (float)c[1]) * (1.f / 3.f);
    }
    __syncthreads();

    // ---- stage 3: OffsetNet (weights from LDS) ----
    if (tid < 144) {
        int h = tid / 18, l = tid % 18;
        float s = bofl[l];
#pragma unroll
        for (int i = 0; i < 3; i++) s += mw[i] * wofl[i * 18 + l];
        for (int d = 0; d < 64; d++) s += qm_u[h * 64 + d] * wofl[(3 + d) * 18 + l];
        s = fminf(fmaxf(s, -9.21f), 9.21f);
        lrn[tid] = 1.f / (1.f + expf(-s)) - 0.5f;
    }
    __syncthreads();

    // ---- stage 4: sample coords -> corner short4 {x0, y0, wx1_u16, wy1_u16} ----
    if (tid < 96) {
        int h = tid / 12, k = tid % 12;
        float s0, s1, s2;
        if (k < 6) {
            const float FSx[6] = {0.f, 1.f, 0.f, 0.f, -1.f, 0.f};
            const float FSy[6] = {0.f, 0.f, 1.f, 0.f, 0.f, -1.f};
            const float FSz[6] = {0.f, 0.f, 0.f, 1.f, 0.f, 0.f};
            s0 = FSx[k]; s1 = FSy[k]; s2 = FSz[k];
        } else {
            int b = h * 18 + (k - 6) * 3;
            s0 = lrn[b]; s1 = lrn[b + 1]; s2 = lrn[b + 2];
        }
        float o0 = s0 * sc3[0], o1 = s1 * sc3[1], o2 = s2 * sc3[2];
        float wx = Rt[0] * o0 + Rt[1] * o1 + Rt[2] * o2 + mw[0];
        float wy = Rt[3] * o0 + Rt[4] * o1 + Rt[5] * o2 + mw[1];
        float wz = Rt[6] * o0 + Rt[7] * o1 + Rt[8] * o2 + mw[2];
        float px = pr[0] * wx + pr[1] * wy + pr[2]  * wz + pr[3];
        float py = pr[4] * wx + pr[5] * wy + pr[6]  * wz + pr[7];
        float pz = pr[8] * wx + pr[9] * wy + pr[10] * wz + pr[11];
        pz = fmaxf(pz, 1e-5f);
        float gx = fminf(fmaxf(px / pz * (1.f / 64.f), 0.f), 0.9999f);
        float gy = fminf(fmaxf(py / pz * (1.f / 64.f), 0.f), 0.9999f);
        float x = gx * 64.f - 0.5f, y = gy * 64.f - 0.5f;
        float fx = floorf(x), fy = floorf(y);
        short4 cn;
        cn.x = (short)(int)fx;
        cn.y = (short)(int)fy;
        cn.z = (short)(unsigned short)fminf((x - fx) * 65536.f, 65535.f);
        cn.w = (short)(unsigned short)fminf((y - fy) * 65536.f, 65535.f);
        corner[tid] = cn;
    }
    __syncthreads();

    // ---- stage 5: batched 8-load gather + packed-f16 bilinear + fdot2 scores ----
    {
        const int slice = tid & 7, grp = tid >> 3;
#pragma unroll
        for (int it = 0; it < 3; it++) {
            const int p = it * 32 + grp;
            const int h = p / 12, k = p - h * 12;
            short4 cn = corner[p];
            int x0 = cn.x, y0 = cn.y, x1 = x0 + 1, y1 = y0 + 1;
            float wx1 = (float)(unsigned short)cn.z * (1.f / 65536.f);
            float wy1 = (float)(unsigned short)cn.w * (1.f / 65536.f);
            float wx0 = 1.f - wx1, wy0 = 1.f - wy1;
            bool vx0 = (unsigned)x0 < 64u, vx1 = (unsigned)x1 < 64u;
            bool vy0 = (unsigned)y0 < 64u, vy1 = (unsigned)y1 < 64u;
            int xc0 = min(max(x0, 0), 63), xc1 = min(max(x1, 0), 63);
            int yc0 = min(max(y0, 0), 63), yc1 = min(max(y1, 0), 63);
            int   off[4];
            float wt[4];
            off[0] = (yc0 * 64 + xc0) * 1024; wt[0] = (vx0 & vy0) ? wx0 * wy0 : 0.f;
            off[1] = (yc0 * 64 + xc1) * 1024; wt[1] = (vx1 & vy0) ? wx1 * wy0 : 0.f;
            off[2] = (yc1 * 64 + xc0) * 1024; wt[2] = (vx0 & vy1) ? wx0 * wy1 : 0.f;
            off[3] = (yc1 * 64 + xc1) * 1024; wt[3] = (vx1 & vy1) ? wx1 * wy1 : 0.f;
            const int a = h * 64 + slice * 8;          // channel base
            const unsigned short* bp = buf + a;
            // issue ALL 8 loads before any math (needs the 6-waves VGPR budget)
            uint4 uk[4], uv[4];
#pragma unroll
            for (int c = 0; c < 4; c++) {
                uk[c] = *(const uint4*)(bp + off[c]);
                uv[c] = *(const uint4*)(bp + off[c] + 512);
            }
            half2v ka2[4] = {{0,0},{0,0},{0,0},{0,0}};
            half2v va2[4] = {{0,0},{0,0},{0,0},{0,0}};
#pragma unroll
            for (int c = 0; c < 4; c++) {
                _Float16 wh = (_Float16)wt[c];
                half2v w2; w2[0] = wh; w2[1] = wh;
                ka2[0] += w2 * u2h(uk[c].x); ka2[1] += w2 * u2h(uk[c].y);
                ka2[2] += w2 * u2h(uk[c].z); ka2[3] += w2 * u2h(uk[c].w);
                va2[0] += w2 * u2h(uv[c].x); va2[1] += w2 * u2h(uv[c].y);
                va2[2] += w2 * u2h(uv[c].z); va2[3] += w2 * u2h(uv[c].w);
            }
            const int pa = h * 32 + slice * 4;         // pair base
            *(uint4*)&vsh2[p * 32 + slice * 4] =
                make_uint4(h2u(va2[0]), h2u(va2[1]), h2u(va2[2]), h2u(va2[3]));
            float sp[3];
#pragma unroll
            for (int t = 0; t < 3; t++) {
                uint4 q4 = *(const uint4*)&qf2[t * 256 + pa];
                float s = __builtin_amdgcn_fdot2(u2h(q4.x), ka2[0], 0.f, false);
                s = __builtin_amdgcn_fdot2(u2h(q4.y), ka2[1], s, false);
                s = __builtin_amdgcn_fdot2(u2h(q4.z), ka2[2], s, false);
                s = __builtin_amdgcn_fdot2(u2h(q4.w), ka2[3], s, false);
                sp[t] = s;
            }
#pragma unroll
            for (int msk = 1; msk < 8; msk <<= 1) {
#pragma unroll
                for (int t = 0; t < 3; t++) sp[t] += __shfl_xor(sp[t], msk);
            }
            if (slice == 0) {
#pragma unroll
                for (int t = 0; t < 3; t++) att[(h * 3 + t) * 12 + k] = sp[t] * 0.125f;
            }
        }
    }
    __syncthreads();

    // ---- stage 7: softmax over K=12 ----
    if (tid < 24) {
        float* row = att + tid * 12;
        float m = row[0];
#pragma unroll
        for (int k = 1; k < 12; k++) m = fmaxf(m, row[k]);
        float e_[12]; float ssum = 0.f;
#pragma unroll
        for (int k = 0; k < 12; k++) { e_[k] = expf(row[k] - m); ssum += e_[k]; }
        float inv = 1.f / ssum;
#pragma unroll
        for (int k = 0; k < 12; k++) row[k] = e_[k] * inv;
    }
    __syncthreads();

    // ---- stage 8: out_attn = attn @ v_s via pk_fma on packed pairs ----
    {
        unsigned* oa32 = (unsigned*)(qfull + (size_t)g * 1536);
#pragma unroll
        for (int i = 0; i < 3; i++) {
            int e = tid + i * 256;            // pair index 0..767
            int t = e >> 8, a2p = e & 255;
            int h = a2p >> 5, ddp = a2p & 31;
            const float* ar = att + (h * 3 + t) * 12;
            const unsigned* vp = vsh2 + h * 12 * 32 + ddp;
            half2v acc = {0, 0};
#pragma unroll
            for (int k = 0; k < 12; k++) {
                _Float16 ah = (_Float16)ar[k];
                half2v a2; a2[0] = ah; a2[1] = ah;
                acc += a2 * u2h(vp[k * 32]);
            }
            oa32[e] = h2u(acc);
        }
    }
}

// -------------------------------------------------------------------------
// Kernel 4: out[24576,32](fp32) = oa[24576,512](f16) @ Wout[512,32](fp32)
//           + b_out + features
// -------------------------------------------------------------------------
__global__ __launch_bounds__(256) void outgemm_kernel(
    const unsigned short* __restrict__ oa, const float* __restrict__ Wout,
    const float* __restrict__ b_out, const float* __restrict__ features,
    float* __restrict__ out)
{
    __shared__ __attribute__((aligned(16))) unsigned short WT[32][520]; // [n][k]
    const int tid = threadIdx.x;
    const int R0 = blockIdx.x * 64;
#pragma unroll
    for (int j = 0; j < 64; j++) {
        int lin = j * 256 + tid;         // lin = k*32 + n
        WT[lin & 31][lin >> 5] = f2hu(Wout[lin]);
    }
    __syncthreads();

    const int w = tid >> 6, l = tid & 63, m = l & 15, quad = l >> 4;
    const int row = R0 + w * 16 + m;
    float4v acc[2] = {{0,0,0,0},{0,0,0,0}};
#pragma unroll
    for (int kk = 0; kk < 16; kk++) {
        half8v af = *(const half8v*)(oa + (size_t)row * 512 + kk * 32 + quad * 8);
#pragma unroll
        for (int t = 0; t < 2; t++) {
            half8v b8 = *(const half8v*)&WT[t * 16 + m][kk * 32 + quad * 8];
            acc[t] = __builtin_amdgcn_mfma_f32_16x16x32_f16(af, b8, acc[t], 0, 0, 0);
        }
    }
    const int rb = R0 + w * 16 + quad * 4;
#pragma unroll
    for (int t = 0; t < 2; t++) {
        int col = t * 16 + m;
        float bb = b_out[col];
#pragma unroll
        for (int r = 0; r < 4; r++) {
            int rr = rb + r;
            out[(size_t)rr * 32 + col] = acc[t][r] + bb + features[(size_t)rr * 32 + col];
        }
    }
}

// -------------------------------------------------------------------------
// Fallback (ws too small): fused attention kernel, fp32 inputs, f16 buf.
// -------------------------------------------------------------------------
__global__ __launch_bounds__(256, 6) void attn_fused_kernel(
    const float* __restrict__ means, const float* __restrict__ scales,
    const float* __restrict__ rot,   const float* __restrict__ features,
    const float* __restrict__ transforms, const float* __restrict__ projection,
    const float* __restrict__ Wq,    const float* __restrict__ W_off,
    const float* __restrict__ b_off, const float* __restrict__ Wout,
    const float* __restrict__ b_out, const unsigned short* __restrict__ buf,
    float* __restrict__ out)
{
    __shared__ float feat[96];
    __shared__ __attribute__((aligned(16))) float qf[1536];
    __shared__ float qm[512];
    __shared__ float mw[3], sc3[3], Rt[9], pr[12];
    __shared__ float lrn[144];
    __shared__ int   coff[96][4];
    __shared__ float cwt[96][4];
    __shared__ __attribute__((aligned(16))) char pool[12288];
    __shared__ float att[288];

    unsigned short* vsh = (unsigned short*)pool;
    const int g = blockIdx.x, tid = threadIdx.x;

    if (tid < 96) {
        feat[tid] = features[(size_t)g * 96 + tid];
    } else if (tid < 99) {
        sc3[tid - 96] = scales[(size_t)g * 3 + (tid - 96)];
    } else if (tid >= 100 && tid < 112) {
        pr[tid - 100] = projection[tid - 100];
    } else if (tid == 112) {
        float w = rot[(size_t)g * 4],     x = rot[(size_t)g * 4 + 1];
        float y = rot[(size_t)g * 4 + 2], z = rot[(size_t)g * 4 + 3];
        float n = rsqrtf(w * w + x * x + y * y + z * z);
        w *= n; x *= n; y *= n; z *= n;
        float R00 = 1 - 2 * (y * y + z * z), R01 = 2 * (x * y - w * z), R02 = 2 * (x * z + w * y);
        float R10 = 2 * (x * y + w * z), R11 = 1 - 2 * (x * x + z * z), R12 = 2 * (y * z - w * x);
        float R20 = 2 * (x * z - w * y), R21 = 2 * (y * z + w * x), R22 = 1 - 2 * (x * x + y * y);
        Rt[0] = R00; Rt[1] = R10; Rt[2] = R20;
        Rt[3] = R01; Rt[4] = R11; Rt[5] = R21;
        Rt[6] = R02; Rt[7] = R12; Rt[8] = R22;
    } else if (tid >= 116 && tid < 119) {
        int i = tid - 116;
        float m0 = means[(size_t)g * 3];
        float m1 = means[(size_t)g * 3 + 1];
        float m2 = means[(size_t)g * 3 + 2];
        const float* T = transforms + (size_t)g * 16 + i * 4;
        mw[i] = T[0] * m0 + T[1] * m1 + T[2] * m2 + T[3];
    }
    __syncthreads();

    {
        const int a0 = tid * 2;
        float s00 = 0.f, s01 = 0.f, s10 = 0.f, s11 = 0.f, s20 = 0.f, s21 = 0.f;
#pragma unroll
        for (int f = 0; f < 32; f++) {
            float2 w2 = *(const float2*)(Wq + (size_t)f * 512 + a0);
            float f0 = feat[f], f1 = feat[32 + f], f2 = feat[64 + f];
            s00 += f0 * w2.x; s01 += f0 * w2.y;
            s10 += f1 * w2.x; s11 += f1 * w2.y;
            s20 += f2 * w2.x; s21 += f2 * w2.y;
        }
        *(float2*)(qf + a0)        = make_float2(s00, s01);
        *(float2*)(qf + 512 + a0)  = make_float2(s10, s11);
        *(float2*)(qf + 1024 + a0) = make_float2(s20, s21);
    }
    __syncthreads();

    qm[tid]       = (qf[tid]       + qf[tid + 512] + qf[tid + 1024]) * (1.f / 3.f);
    qm[tid + 256] = (qf[tid + 256] + qf[tid + 768] + qf[tid + 1280]) * (1.f / 3.f);
    __syncthreads();

    if (tid < 144) {
        int h = tid / 18, l = tid % 18;
        float s = b_off[l];
#pragma unroll
        for (int i = 0; i < 3; i++) s += mw[i] * W_off[i * 18 + l];
        for (int d = 0; d < 64; d++) s += qm[h * 64 + d] * W_off[(size_t)(3 + d) * 18 + l];
        s = fminf(fmaxf(s, -9.21f), 9.21f);
        lrn[tid] = 1.f / (1.f + expf(-s)) - 0.5f;
    }
    __syncthreads();

    if (tid < 96) {
        int h = tid / 12, k = tid % 12;
        float s0, s1, s2;
        if (k < 6) {
            const float FSx[6] = {0.f, 1.f, 0.f, 0.f, -1.f, 0.f};
            const float FSy[6] = {0.f, 0.f, 1.f, 0.f, 0.f, -1.f};
            const float FSz[6] = {0.f, 0.f, 0.f, 1.f, 0.f, 0.f};
            s0 = FSx[k]; s1 = FSy[k]; s2 = FSz[k];
        } else {
            int b = h * 18 + (k - 6) * 3;
            s0 = lrn[b]; s1 = lrn[b + 1]; s2 = lrn[b + 2];
        }
        float o0 = s0 * sc3[0], o1 = s1 * sc3[1], o2 = s2 * sc3[2];
        float wx = Rt[0] * o0 + Rt[1] * o1 + Rt[2] * o2 + mw[0];
        float wy = Rt[3] * o0 + Rt[4] * o1 + Rt[5] * o2 + mw[1];
        float wz = Rt[6] * o0 + Rt[7] * o1 + Rt[8] * o2 + mw[2];
        float px = pr[0] * wx + pr[1] * wy + pr[2]  * wz + pr[3];
        float py = pr[4] * wx + pr[5] * wy + pr[6]  * wz + pr[7];
        float pz = pr[8] * wx + pr[9] * wy + pr[10] * wz + pr[11];
        pz = fmaxf(pz, 1e-5f);
        float gx = fminf(fmaxf(px / pz * (1.f / 64.f), 0.f), 0.9999f);
        float gy = fminf(fmaxf(py / pz * (1.f / 64.f), 0.f), 0.9999f);
        float x = gx * 64.f - 0.5f, y = gy * 64.f - 0.5f;
        float fx = floorf(x), fy = floorf(y);
        int x0 = (int)fx, y0 = (int)fy;
        float wx1 = x - fx, wx0c = 1.f - wx1;
        float wy1 = y - fy, wy0c = 1.f - wy1;
        int xs[2] = {x0, x0 + 1}, ys[2] = {y0, y0 + 1};
        float wxs[2] = {wx0c, wx1}, wys[2] = {wy0c, wy1};
#pragma unroll
        for (int c = 0; c < 4; c++) {
            int dx = c & 1, dy = c >> 1;
            int xi = xs[dx], yi = ys[dy];
            bool v = (xi >= 0) & (xi < 64) & (yi >= 0) & (yi < 64);
            int xc = min(max(xi, 0), 63), yc = min(max(yi, 0), 63);
            coff[tid][c] = (yc * 64 + xc) * 1024;
            cwt[tid][c]  = v ? wxs[dx] * wys[dy] : 0.f;
        }
    }
    __syncthreads();

    {
        const int slice = tid & 7, d0 = slice * 8, grp = tid >> 3;
#pragma unroll
        for (int it = 0; it < 3; it++) {
            const int p = it * 32 + grp;
            const int h = p / 12, k = p - h * 12;
            const int a = h * 64 + d0;
            const unsigned short* bp = buf + a;
            float ka[8] = {0,0,0,0,0,0,0,0}, va[8] = {0,0,0,0,0,0,0,0}, t8[8];
#pragma unroll
            for (int c = 0; c < 4; c++) {
                const int   o = coff[p][c];
                const float w = cwt[p][c];
                ld8h(bp + o, t8);
#pragma unroll
                for (int j = 0; j < 8; j++) ka[j] += w * t8[j];
                ld8h(bp + o + 512, t8);
#pragma unroll
                for (int j = 0; j < 8; j++) va[j] += w * t8[j];
            }
            uint4 pv;
            pv.x = packh(va[0], va[1]); pv.y = packh(va[2], va[3]);
            pv.z = packh(va[4], va[5]); pv.w = packh(va[6], va[7]);
            *(uint4*)(vsh + p * 64 + d0) = pv;
            float sp[3];
#pragma unroll
            for (int t = 0; t < 3; t++) {
                const float* qp = qf + t * 512 + a;
                float s = 0.f;
#pragma unroll
                for (int j = 0; j < 8; j++) s += qp[j] * ka[j];
                sp[t] = s;
            }
#pragma unroll
            for (int msk = 1; msk < 8; msk <<= 1) {
#pragma unroll
                for (int t = 0; t < 3; t++) sp[t] += __shfl_xor(sp[t], msk);
            }
            if (slice == 0) {
#pragma unroll
                for (int t = 0; t < 3; t++) att[(h * 3 + t) * 12 + k] = sp[t] * 0.125f;
            }
        }
    }
    __syncthreads();

    if (tid < 24) {
        float* row = att + tid * 12;
        float m = row[0];
#pragma unroll
        for (int k = 1; k < 12; k++) m = fmaxf(m, row[k]);
        float e_[12]; float ssum = 0.f;
#pragma unroll
        for (int k = 0; k < 12; k++) { e_[k] = expf(row[k] - m); ssum += e_[k]; }
        float inv = 1.f / ssum;
#pragma unroll
        for (int k = 0; k < 12; k++) row[k] = e_[k] * inv;
    }
    __syncthreads();

#pragma unroll
    for (int i = 0; i < 6; i++) {
        int e = tid + i * 256;
        int t = e >> 9, a = e & 511, h = a >> 6, dd = a & 63;
        const float* ar = att + (h * 3 + t) * 12;
        const unsigned short* vp = vsh + (h * 12) * 64 + dd;
        float s = 0.f;
#pragma unroll
        for (int k = 0; k < 12; k++) {
            _Float16 hh = __builtin_bit_cast(_Float16, vp[k * 64]);
            s += ar[k] * (float)hh;
        }
        qf[e] = s;
    }
    __syncthreads();

    {
        float* red = (float*)pool;
        const int c0 = (tid & 15) * 2, slice = tid >> 4;
        const int abase = slice * 32;
        float a00 = 0.f, a01 = 0.f, a10 = 0.f, a11 = 0.f, a20 = 0.f, a21 = 0.f;
#pragma unroll
        for (int i = 0; i < 32; i++) {
            int a = abase + i;
            float2 w2 = *(const float2*)(Wout + (size_t)a * 32 + c0);
            float o0 = qf[a], o1 = qf[512 + a], o2 = qf[1024 + a];
            a00 += o0 * w2.x; a01 += o0 * w2.y;
            a10 += o1 * w2.x; a11 += o1 * w2.y;
            a20 += o2 * w2.x; a21 += o2 * w2.y;
        }
        __syncthreads();
        red[(slice * 3 + 0) * 32 + c0] = a00; red[(slice * 3 + 0) * 32 + c0 + 1] = a01;
        red[(slice * 3 + 1) * 32 + c0] = a10; red[(slice * 3 + 1) * 32 + c0 + 1] = a11;
        red[(slice * 3 + 2) * 32 + c0] = a20; red[(slice * 3 + 2) * 32 + c0 + 1] = a21;
        __syncthreads();
        if (tid < 96) {
            int t = tid >> 5, c = tid & 31;
            float acc = b_out[c] + feat[tid];
#pragma unroll
            for (int s = 0; s < 16; s++) acc += red[(s * 3 + t) * 32 + c];
            out[(size_t)g * 96 + tid] = acc;
        }
    }
}

extern "C" void kernel_launch(void* const* d_in, const int* in_sizes, int n_in,
                              void* d_out, int out_size, void* d_ws, size_t ws_size,
                              hipStream_t stream) {
    const float* means      = (const float*)d_in[0];
    const float* scales     = (const float*)d_in[1];
    const float* rot        = (const float*)d_in[2];
    const float* features   = (const float*)d_in[3];
    const float* transforms = (const float*)d_in[4];
    const float* projection = (const float*)d_in[5];
    const float* img        = (const float*)d_in[6];
    const float* Wq         = (const float*)d_in[7];
    const float* Wk         = (const float*)d_in[8];
    const float* Wv         = (const float*)d_in[9];
    const float* W_off      = (const float*)d_in[10];
    const float* b_off      = (const float*)d_in[11];
    const float* Wout       = (const float*)d_in[12];
    const float* b_out      = (const float*)d_in[13];
    float* out = (float*)d_out;

    char* w = (char*)d_ws;
    unsigned short* buf = (unsigned short*)(w + 64);   // 4096 x 1024 f16 = 8 MiB
    const size_t BUF_BYTES = (size_t)4096 * 1024 * 2;
    const size_t Q_BYTES   = (size_t)24576 * 512 * 2;  // 24 MiB
    const size_t need = 64 + BUF_BYTES + Q_BYTES;

    dim3 gridc(64, 16);
    conv_fused_kernel<<<gridc, 256, 0, stream>>>(img, Wk, Wv, buf);

    if (ws_size >= need) {
        unsigned short* qfull = (unsigned short*)(w + 64 + BUF_BYTES);
        dim3 gridq(384, 2);
        qgemm_kernel<<<gridq, 256, 0, stream>>>(features, Wq, qfull);
        attn_core_kernel<<<8192, 256, 0, stream>>>(
            means, scales, rot, transforms, projection, W_off, b_off, buf, qfull);
        outgemm_kernel<<<384, 256, 0, stream>>>(qfull, Wout, b_out, features, out);
    } else {
        attn_fused_kernel<<<8192, 256, 0, stream>>>(
            means, scales, rot, features, transforms, projection,
            Wq, W_off, b_off, Wout, b_out, buf, out);
    }
}